// Round 7
// baseline (1116.011 us; speedup 1.0000x reference)
//
#include <hip/hip_runtime.h>
#include <hip/hip_bf16.h>

#define NN 10000
#define NE 160000
#define NZ 10
#define NC 64
#define NBES 8
#define NG 16
#define NT 2

static constexpr float PI_F  = 3.14159265358979323846f;
static constexpr float KBES  = 0.63245553203367587f;  // sqrt(2/5)
static constexpr float S3    = 1.73205080756887729f;
static constexpr float S5    = 2.23606797749978969f;
static constexpr float S15   = 3.87298334620741688f;

// ---- workspace layout (float offsets); node tensors stride 256 (planes 0..3) ----
static constexpr size_t OFF_SH   = 0;
static constexpr size_t OFF_EF   = OFF_SH  + (size_t)NE*9;
static constexpr size_t OFF_RL   = OFF_EF  + (size_t)NE*8;
static constexpr size_t OFF_UV   = OFF_RL  + (size_t)NE;
static constexpr size_t OFF_PIN  = OFF_UV  + (size_t)NE*3;
static constexpr size_t OFF_ATT  = OFF_PIN + (size_t)NN*3;
static constexpr size_t OFF_CHG  = OFF_ATT + (size_t)NN*NZ;
static constexpr size_t OFF_SHF  = OFF_CHG + (size_t)NN;
static constexpr size_t NFS      = (size_t)NN*256;
static constexpr size_t OFF_NF0  = OFF_SHF + (size_t)NE*3;
static constexpr size_t OFF_NF1  = OFF_NF0 + NFS;
static constexpr size_t OFF_NF2  = OFF_NF1 + NFS;
static constexpr size_t OFF_MSG0 = OFF_NF2 + NFS;
static constexpr size_t OFF_MSG1 = OFF_MSG0+ NFS;
static constexpr size_t OFF_AGG  = OFF_MSG1+ NFS;    // fwd agg; bwd compact GA0/GB0
static constexpr size_t OFF_W    = OFF_AGG + NFS;
static constexpr size_t O_WEMB   = OFF_W;
static constexpr size_t O_AE     = O_WEMB + 640;
static constexpr size_t O_R1     = O_AE   + 16;
static constexpr size_t O_R2     = O_R1   + 1024;
static constexpr size_t O_R2T    = O_R2   + 8192;   // kept in transpose (unused now)
static constexpr size_t O_WMIX   = O_R2T  + 8192;
static constexpr size_t O_WMIXT  = O_WMIX + 24576;
static constexpr size_t O_WSC    = O_WMIXT+ 24576;
static constexpr size_t O_WSCT   = O_WSC  + 24576;
static constexpr size_t O_WPROD  = O_WSCT + 24576;
static constexpr size_t O_WPRODT = O_WPROD+ 24576;
static constexpr size_t O_WPOLY  = O_WPRODT+24576;
static constexpr size_t O_WE     = O_WPOLY+ 384;
static constexpr size_t O_WD     = O_WE   + 128;
static constexpr size_t OFF_ACC  = O_WD   + 128;
static constexpr size_t O_E0G    = OFF_ACC;
static constexpr size_t O_ETG    = O_E0G + 16;
static constexpr size_t O_TD     = O_ETG + 32;
static constexpr size_t O_ADP    = O_TD  + 48;
static constexpr size_t O_GPOS   = O_ADP + (size_t)NN*3;
// per-node energy staging ALIASES gpos (k_reduce runs before k_gpos)
static constexpr size_t O_EN0    = O_GPOS;
static constexpr size_t O_EN1    = O_GPOS + NN;
static constexpr size_t O_E0N    = O_GPOS + 2*NN;
static constexpr size_t O_GVEC   = O_GPOS+ (size_t)NN*3;     // per-edge dE/dvec (NOT zeroed)
static constexpr size_t ACC_FLOATS = O_GVEC - OFF_ACC;
static constexpr size_t O_FLAG   = O_GVEC + (size_t)NE*3;
static constexpr size_t O_GVP    = O_FLAG + 4;
static constexpr size_t O_GNFC   = O_GVP + 64;
static constexpr size_t O_WBUF   = O_GNFC + 64;              // E*64 radial weights
static constexpr size_t O_QBUF   = O_WBUF + (size_t)NE*64;   // E*64 geometry-grad vectors
static constexpr size_t O_OFFR   = O_QBUF + (size_t)NE*64;   // ints from here
static constexpr size_t O_OFFS   = O_OFFR + (NN+1);
static constexpr size_t O_CURR   = O_OFFS + (NN+1);
static constexpr size_t O_CURS   = O_CURR + NN;
static constexpr size_t O_LISTR  = O_CURS + NN;
static constexpr size_t O_LISTS  = O_LISTR + (size_t)NE;
static constexpr size_t WS_FLOATS= O_LISTS + (size_t)NE;     // ~164 MB

__device__ __forceinline__ float rlane(float v, int l){
  return __int_as_float(__builtin_amdgcn_readlane(__float_as_int(v), l));
}

__device__ __forceinline__ void edge_defdr(float L, float* dd){
  float ur = L*0.2f;
  if (ur < 1.f){
    float u2=ur*ur, u4=u2*u2, u5=u4*ur;
    float fc = 1.f - 21.f*u5 + 35.f*u5*ur - 15.f*u5*u2;
    float omu = 1.f - ur;
    float dfc = -105.f*u4*omu*omu;
    float invr = 1.f/(L + 1e-9f);
    #pragma unroll
    for (int b = 0; b < 8; ++b){
      float nb = (float)(b+1);
      float arg = nb*PI_F*ur;
      float sn = sinf(arg), cs = cosf(arg);
      float bes = KBES*sn*invr;
      float dbes = KBES*(nb*PI_F*0.2f)*cs*invr - bes*invr;
      dd[b] = dbes*fc + bes*dfc*0.2f;
    }
  } else {
    #pragma unroll
    for (int b = 0; b < 8; ++b) dd[b] = 0.f;
  }
}

// ---------- dtype detection ----------
__global__ void k_detect(const unsigned* __restrict__ raw, int* __restrict__ flag){
  __shared__ int found;
  if (threadIdx.x == 0) found = 0;
  __syncthreads();
  for (int i = threadIdx.x; i < 4096; i += 256){
    unsigned w = raw[i];
    if (w == 0x00003F80u || w == 0x3F803F80u) found = 1;
  }
  __syncthreads();
  if (threadIdx.x == 0) flag[0] = found;
}

// ---------- fused loader ----------
static constexpr int LD_CNT[14] = {NN*3, NN*NZ, NN, NE*3, NZ*64, NZ, NT*NBES*64, NT*64*64,
                                   NT*3*64*64, NT*3*64*64, NT*64*3, NT*3*64*64, NT*64, NT*64};
static constexpr int LD_TOTAL = NN*3 + NN*NZ + NN + NE*3 + NZ*64 + NZ + NT*NBES*64 + NT*64*64
                              + 3*(NT*3*64*64) + NT*64*3 + 4*(NT*64) - NT*64*2;
__global__ __launch_bounds__(256) void k_load_all(
    const void* s0, const void* s1, const void* s2, const void* s3, const void* s4,
    const void* s5, const void* s6, const void* s7, const void* s8, const void* s9,
    const void* s10, const void* s11, const void* s12, const void* s13,
    float* __restrict__ ws, const int* __restrict__ flag){
  const void* srcs[14] = {s0,s1,s2,s3,s4,s5,s6,s7,s8,s9,s10,s11,s12,s13};
  const size_t dsts[14] = {OFF_PIN, OFF_ATT, OFF_CHG, OFF_SHF, O_WEMB, O_AE, O_R1, O_R2,
                           O_WMIX, O_WSC, O_WPOLY, O_WPROD, O_WE, O_WD};
  int i = blockIdx.x*256 + threadIdx.x;
  int seg = -1, off = i;
  #pragma unroll
  for (int j = 0; j < 14; ++j){
    if (seg < 0){
      if (off < LD_CNT[j]) seg = j;
      else off -= LD_CNT[j];
    }
  }
  if (seg < 0) return;
  float v = flag[0] ? __bfloat162float(((const __hip_bfloat16*)srcs[seg])[off])
                    : ((const float*)srcs[seg])[off];
  ws[dsts[seg] + off] = v;
}

// ---------- fused transposes ----------
__global__ void k_transpose_all(float* __restrict__ ws){
  const size_t srcs[4] = {O_R2, O_WMIX, O_WSC, O_WPROD};
  const size_t dsts[4] = {O_R2T, O_WMIXT, O_WSCT, O_WPRODT};
  const int cnts[4] = {2, 6, 6, 6};
  int i = blockIdx.x*256 + threadIdx.x;
  if (i >= 20*4096) return;
  int mm = i >> 12, r = (i >> 6) & 63, c = i & 63;
  int grp = 0, m = mm;
  #pragma unroll
  for (int j = 0; j < 4; ++j){ if (m >= cnts[j] && j < 3){ m -= cnts[j]; grp = j+1; } }
  ws[dsts[grp] + (size_t)m*4096 + (size_t)c*64 + r] =
      ws[srcs[grp] + (size_t)m*4096 + (size_t)r*64 + c];
}

// ---------- edge geometry ----------
__global__ void k_geom(const float* __restrict__ pos, const float* __restrict__ shifts,
                       const int* __restrict__ ei, float* __restrict__ sh, float* __restrict__ ef,
                       float* __restrict__ rl, float* __restrict__ uv){
  int e = blockIdx.x*256 + threadIdx.x;
  if (e >= NE) return;
  int s = ei[e], r = ei[NE + e];
  float vx = pos[s*3+0] - pos[r*3+0] + shifts[(size_t)e*3+0];
  float vy = pos[s*3+1] - pos[r*3+1] + shifts[(size_t)e*3+1];
  float vz = pos[s*3+2] - pos[r*3+2] + shifts[(size_t)e*3+2];
  float L = sqrtf(vx*vx + vy*vy + vz*vz + 1e-12f);
  float inv = 1.f / L;
  float x = vx*inv, y = vy*inv, z = vz*inv;
  float* shp = sh + (size_t)e*9;
  shp[0] = 1.f;     shp[1] = S3*x;    shp[2] = S3*y;   shp[3] = S3*z;
  shp[4] = S15*x*y; shp[5] = S15*y*z; shp[6] = 0.5f*S5*(3.f*z*z - 1.f);
  shp[7] = S15*x*z; shp[8] = 0.5f*S15*(x*x - y*y);
  rl[e] = L;
  uv[(size_t)e*3+0] = x; uv[(size_t)e*3+1] = y; uv[(size_t)e*3+2] = z;
  float ur = L * 0.2f;
  float fc = 0.f;
  if (ur < 1.f){
    float u2 = ur*ur, u4 = u2*u2, u5 = u4*ur;
    fc = 1.f - 21.f*u5 + 35.f*u5*ur - 15.f*u5*u2;
  }
  float invr = 1.f / (L + 1e-9f);
  float* efp = ef + (size_t)e*8;
  #pragma unroll
  for (int b = 0; b < 8; ++b){
    float arg = (float)(b+1) * PI_F * ur;
    efp[b] = KBES * sinf(arg) * invr * fc;
  }
}

// ---------- node init ----------
__global__ __launch_bounds__(256) void k_init_nodes(
    const float* __restrict__ attrs, const float* __restrict__ Wemb,
    const float* __restrict__ ae, float* __restrict__ nf0, float* __restrict__ e0n){
  int lane = threadIdx.x & 63;
  int n = blockIdx.x*4 + (threadIdx.x >> 6);
  if (n >= NN) return;
  float acc = 0.f;
  #pragma unroll
  for (int z = 0; z < NZ; ++z) acc = fmaf(attrs[(size_t)n*NZ+z], Wemb[z*64+lane], acc);
  size_t base = (size_t)n*256;
  nf0[base + lane] = acc;
  #pragma unroll
  for (int k = 1; k < 4; ++k) nf0[base + (size_t)k*64 + lane] = 0.f;
  if (lane == 0){
    float e = 0.f;
    #pragma unroll
    for (int z = 0; z < NZ; ++z) e = fmaf(attrs[(size_t)n*NZ+z], ae[z], e);
    e0n[n] = e;
  }
}

// ================= CSR construction =================
__global__ void k_csr_count(const int* __restrict__ ei, int* __restrict__ cntr, int* __restrict__ cnts){
  int e = blockIdx.x*256 + threadIdx.x;
  if (e >= NE) return;
  atomicAdd(&cntr[ei[NE+e]], 1);
  atomicAdd(&cnts[ei[e]], 1);
}

__global__ void k_csr_scan(int* __restrict__ cntr, int* __restrict__ cnts,
                           int* __restrict__ offr, int* __restrict__ offs_){
  __shared__ int part[256];
  for (int q = 0; q < 2; ++q){
    int* c   = q ? cnts  : cntr;
    int* off = q ? offs_ : offr;
    const int chunk = (NN + 255)/256;
    int lo = threadIdx.x*chunk, hi = lo+chunk; if (hi > NN) hi = NN; if (lo > NN) lo = NN;
    int s = 0;
    for (int i = lo; i < hi; ++i) s += c[i];
    part[threadIdx.x] = s;
    __syncthreads();
    for (int o = 1; o < 256; o <<= 1){
      int v = (threadIdx.x >= o) ? part[threadIdx.x-o] : 0;
      __syncthreads();
      part[threadIdx.x] += v;
      __syncthreads();
    }
    int run = (threadIdx.x == 0) ? 0 : part[threadIdx.x-1];
    for (int i = lo; i < hi; ++i){
      int ci = c[i];
      off[i] = run; c[i] = run;
      run += ci;
    }
    if (threadIdx.x == 255) off[NN] = run;
    __syncthreads();
  }
}

__global__ void k_csr_fill(const int* __restrict__ ei, int* __restrict__ curr, int* __restrict__ curs,
                           int* __restrict__ listr, int* __restrict__ lists){
  int e = blockIdx.x*256 + threadIdx.x;
  if (e >= NE) return;
  int pr = atomicAdd(&curr[ei[NE+e]], 1); listr[pr] = e;
  int ps = atomicAdd(&curs[ei[e]], 1);    lists[ps] = e;
}

// ================= radial MLP forward (VGPR-resident) =================
__global__ __launch_bounds__(256) void k_radial(
    const float* __restrict__ ef, const float* __restrict__ R1, const float* __restrict__ R2,
    float* __restrict__ wbuf){
  int lane = threadIdx.x & 63;
  int wid = blockIdx.x*4 + (threadIdx.x >> 6);
  int nw  = gridDim.x*4;
  float r1c[8], r2c[64];
  #pragma unroll
  for (int j = 0; j < 8; ++j)  r1c[j] = R1[j*64 + lane];
  #pragma unroll
  for (int j = 0; j < 64; ++j) r2c[j] = R2[j*64 + lane];
  for (int e = wid; e < NE; e += nw){
    float efv = ef[(size_t)e*8 + (lane & 7)];
    float a = 0.f;
    #pragma unroll
    for (int b = 0; b < 8; ++b) a = fmaf(rlane(efv, b), r1c[b], a);
    float sg = 1.f/(1.f + __expf(-a));
    float sl = a*sg;
    float w0 = 0.f, w1 = 0.f, w2 = 0.f, w3 = 0.f;
    #pragma unroll
    for (int j = 0; j < 64; j += 4){
      w0 = fmaf(rlane(sl, j  ), r2c[j  ], w0);
      w1 = fmaf(rlane(sl, j+1), r2c[j+1], w1);
      w2 = fmaf(rlane(sl, j+2), r2c[j+2], w2);
      w3 = fmaf(rlane(sl, j+3), r2c[j+3], w3);
    }
    wbuf[(size_t)e*64 + lane] = (w0+w1) + (w2+w3);
  }
}

// ================= per-edge geometry-gradient vector Q =================
// Q_e[d] = sum_j silu'(a_e[j]) * t_e[j] * R2[j][d],  t_e[j] = sum_b R1[b][j]*defdr_e[b]
// Then dE/dr for an edge = sum_d Q_e[d]*h_s[d]*gm_n[d]  (computed in k_edge_bwd_q).
__global__ __launch_bounds__(256) void k_radialQ(
    const float* __restrict__ ef, const float* __restrict__ rl,
    const float* __restrict__ R1, const float* __restrict__ R2,
    float* __restrict__ qbuf){
  int lane = threadIdx.x & 63;
  int wid = blockIdx.x*4 + (threadIdx.x >> 6);
  int nw  = gridDim.x*4;
  float r1c[8], r2c[64];
  #pragma unroll
  for (int j = 0; j < 8; ++j)  r1c[j] = R1[j*64 + lane];
  #pragma unroll
  for (int j = 0; j < 64; ++j) r2c[j] = R2[j*64 + lane];
  for (int e = wid; e < NE; e += nw){
    float efv = ef[(size_t)e*8 + (lane & 7)];
    float a = 0.f;
    #pragma unroll
    for (int b = 0; b < 8; ++b) a = fmaf(rlane(efv, b), r1c[b], a);
    float sg = 1.f/(1.f + __expf(-a));
    float dd[8];
    edge_defdr(rl[e], dd);
    float t = 0.f;
    #pragma unroll
    for (int b = 0; b < 8; ++b) t = fmaf(r1c[b], dd[b], t);
    float q = sg*fmaf(a, 1.f - sg, 1.f)*t;   // silu'(a) * t, per hidden unit = lane
    float w0 = 0.f, w1 = 0.f, w2 = 0.f, w3 = 0.f;
    #pragma unroll
    for (int j = 0; j < 64; j += 4){
      w0 = fmaf(rlane(q, j  ), r2c[j  ], w0);
      w1 = fmaf(rlane(q, j+1), r2c[j+1], w1);
      w2 = fmaf(rlane(q, j+2), r2c[j+2], w2);
      w3 = fmaf(rlane(q, j+3), r2c[j+3], w3);
    }
    qbuf[(size_t)e*64 + lane] = (w0+w1) + (w2+w3);
  }
}

// ================= aggregation via receiver CSR (planes 0..3) =================
__global__ __launch_bounds__(256) void k_agg(
    const float* __restrict__ wbuf, const float* __restrict__ sh, const float* __restrict__ nf,
    const int* __restrict__ ei, const int* __restrict__ offr, const int* __restrict__ listr,
    float* __restrict__ agg){
  int lane = threadIdx.x & 63;
  int wid = blockIdx.x*4 + (threadIdx.x >> 6);
  int nw  = gridDim.x*4;
  for (int n = wid; n < NN; n += nw){
    int lo = offr[n], hi = offr[n+1];
    float acc[4];
    #pragma unroll
    for (int k = 0; k < 4; ++k) acc[k] = 0.f;
    for (int i = lo; i < hi; ++i){
      int e = __builtin_amdgcn_readfirstlane(listr[i]);
      int s = __builtin_amdgcn_readfirstlane(ei[e]);
      float wh = wbuf[(size_t)e*64 + lane] * nf[(size_t)s*256 + lane];
      const float* shp = sh + (size_t)e*9;
      #pragma unroll
      for (int k = 0; k < 4; ++k) acc[k] = fmaf(wh, shp[k], acc[k]);
    }
    size_t ob = (size_t)n*256 + lane;
    #pragma unroll
    for (int k = 0; k < 4; ++k) agg[ob + (size_t)k*64] = acc[k]*(1.f/16.f);
  }
}

// ================= per-l linear, readlane matvec (gridDim.y = 4) =================
__global__ __launch_bounds__(256) void k_lin2(
    const float* __restrict__ in, const float* __restrict__ W3, const float* __restrict__ wp,
    float* __restrict__ out, int flags){
  int k = blockIdx.y;
  int l = (k==0) ? 0 : 1;
  const float* W = W3 + (size_t)l*4096;
  int lane = threadIdx.x & 63;
  float wcol[64];
  #pragma unroll
  for (int j = 0; j < 64; ++j) wcol[j] = W[j*64 + lane];
  float p0 = 0.f, p1 = 0.f, p2 = 0.f;
  if (flags & 2){ p0 = wp[lane*3]; p1 = wp[lane*3+1]; p2 = wp[lane*3+2]; }
  int wid = blockIdx.x*4 + (threadIdx.x >> 6);
  int nw  = gridDim.x*4;
  for (int n = wid; n < NN; n += nw){
    size_t base = (size_t)n*256;
    float x = in[base + (size_t)k*64 + lane];
    if (flags & 2){
      float s0 = in[base + lane];
      x *= fmaf(fmaf(p2, s0, p1), s0, p0);
    }
    float a0 = 0.f, a1 = 0.f, a2 = 0.f, a3 = 0.f;
    #pragma unroll
    for (int j = 0; j < 64; j += 4){
      a0 = fmaf(rlane(x, j  ), wcol[j  ], a0);
      a1 = fmaf(rlane(x, j+1), wcol[j+1], a1);
      a2 = fmaf(rlane(x, j+2), wcol[j+2], a2);
      a3 = fmaf(rlane(x, j+3), wcol[j+3], a3);
    }
    float acc = (a0+a1) + (a2+a3);
    float* o = out + base + (size_t)k*64 + lane;
    if (flags & 1) *o += acc; else *o = acc;
  }
}

// ================= compact 64-wide matvec =================
__global__ __launch_bounds__(256) void k_lin0(
    const float* __restrict__ in, const float* __restrict__ W, float* __restrict__ out){
  int lane = threadIdx.x & 63;
  float wcol[64];
  #pragma unroll
  for (int j = 0; j < 64; ++j) wcol[j] = W[j*64 + lane];
  int wid = blockIdx.x*4 + (threadIdx.x >> 6);
  int nw  = gridDim.x*4;
  for (int n = wid; n < NN; n += nw){
    float x = in[(size_t)n*64 + lane];
    float a0 = 0.f, a1 = 0.f, a2 = 0.f, a3 = 0.f;
    #pragma unroll
    for (int j = 0; j < 64; j += 4){
      a0 = fmaf(rlane(x, j  ), wcol[j  ], a0);
      a1 = fmaf(rlane(x, j+1), wcol[j+1], a1);
      a2 = fmaf(rlane(x, j+2), wcol[j+2], a2);
      a3 = fmaf(rlane(x, j+3), wcol[j+3], a3);
    }
    out[(size_t)n*64 + lane] = (a0+a1) + (a2+a3);
  }
}

// ================= energies & dipoles: per-node staging =================
__global__ __launch_bounds__(256) void k_edip(
    const float* __restrict__ nf, const float* __restrict__ we,
    const float* __restrict__ wd, float* __restrict__ en, float* __restrict__ adp){
  int lane = threadIdx.x & 63;
  int n = blockIdx.x*4 + (threadIdx.x >> 6);
  if (n >= NN) return;
  float v = nf[(size_t)n*256 + lane]*we[lane];
  #pragma unroll
  for (int o = 32; o; o >>= 1) v += __shfl_xor(v, o, 64);
  if (lane == 0) en[n] = v;
  #pragma unroll
  for (int j = 0; j < 3; ++j){
    float dv = nf[(size_t)n*256 + (size_t)(j+1)*64 + lane]*wd[lane];
    #pragma unroll
    for (int o = 32; o; o >>= 1) dv += __shfl_xor(dv, o, 64);
    if (lane == 0) adp[n*3+j] += dv;
  }
}

// ================= segmented final reduction =================
__global__ void k_reduce(const float* __restrict__ e0n, const float* __restrict__ en0,
                         const float* __restrict__ en1, const float* __restrict__ adp,
                         const float* __restrict__ q, const float* __restrict__ pos,
                         const int* __restrict__ batch, float* __restrict__ e0g,
                         float* __restrict__ Etg, float* __restrict__ td){
  int n = blockIdx.x*256 + threadIdx.x;
  int lane = threadIdx.x & 63;
  bool valid = (n < NN);
  int g = valid ? batch[n] : -1;
  float v0=0.f, v1=0.f, v2=0.f, tx=0.f, ty=0.f, tz=0.f;
  if (valid){
    v0 = e0n[n]; v1 = en0[n]; v2 = en1[n];
    float qq = q[n];
    tx = adp[n*3+0] + qq*pos[n*3+0];
    ty = adp[n*3+1] + qq*pos[n*3+1];
    tz = adp[n*3+2] + qq*pos[n*3+2];
  }
  int g0 = __shfl(g, 0, 64), g63 = __shfl(g, 63, 64);
  if (g0 == g63 && g0 >= 0){
    #pragma unroll
    for (int o = 32; o; o >>= 1){
      v0 += __shfl_xor(v0, o, 64); v1 += __shfl_xor(v1, o, 64); v2 += __shfl_xor(v2, o, 64);
      tx += __shfl_xor(tx, o, 64); ty += __shfl_xor(ty, o, 64); tz += __shfl_xor(tz, o, 64);
    }
    if (lane == 0){
      atomicAdd(&e0g[g0], v0); atomicAdd(&Etg[g0], v1); atomicAdd(&Etg[16+g0], v2);
      atomicAdd(&td[g0*3+0], tx); atomicAdd(&td[g0*3+1], ty); atomicAdd(&td[g0*3+2], tz);
    }
  } else if (valid){
    atomicAdd(&e0g[g], v0); atomicAdd(&Etg[g], v1); atomicAdd(&Etg[16+g], v2);
    atomicAdd(&td[g*3+0], tx); atomicAdd(&td[g*3+1], ty); atomicAdd(&td[g*3+2], tz);
  }
}

// ================= backward head =================
__global__ void k_bwd_head(const float* __restrict__ WPRODT1, const float* __restrict__ WSCT1,
                           const float* __restrict__ we1, const float* __restrict__ we0,
                           float* __restrict__ gvp, float* __restrict__ gnfc){
  int d = threadIdx.x;
  float a = 0.f, b = 0.f;
  #pragma unroll
  for (int c = 0; c < 64; ++c){
    float w = we1[c];
    a = fmaf(w, WPRODT1[c*64+d], a);
    b = fmaf(w, WSCT1[c*64+d], b);
  }
  gvp[d] = a;
  gnfc[d] = b + we0[d];
}

// ================= poly backward (k=0 plane) =================
__global__ __launch_bounds__(256) void k_polybwd0(
    const float* __restrict__ gmp, int per_node, const float* __restrict__ msgbase,
    const float* __restrict__ wp, float* __restrict__ out){
  int lane = threadIdx.x & 63;
  int n = blockIdx.x*4 + (threadIdx.x >> 6);
  if (n >= NN) return;
  float g = per_node ? gmp[(size_t)n*64 + lane] : gmp[lane];
  float s0 = msgbase[(size_t)n*256 + lane];
  float p0 = wp[lane*3], p1 = wp[lane*3+1], p2 = wp[lane*3+2];
  float poly = fmaf(fmaf(p2, s0, p1), s0, p0);
  float dp   = fmaf(2.f*p2, s0, p1);
  out[(size_t)n*64 + lane] = g*fmaf(s0, dp, poly);
}

// ================= per-receiver backward: rr = sum_d Q*h*gm, gvec = rr*u =================
__global__ __launch_bounds__(256) void k_edge_bwd_q(
    const float* __restrict__ nf, const float* __restrict__ gagg0, const float* __restrict__ qbuf,
    const float* __restrict__ uv, const int* __restrict__ ei,
    const int* __restrict__ offr, const int* __restrict__ listr,
    float* __restrict__ gvec, int accum){
  int lane = threadIdx.x & 63;
  int wid = blockIdx.x*4 + (threadIdx.x >> 6);
  int nw  = gridDim.x*4;
  for (int n = wid; n < NN; n += nw){
    float gm = gagg0[(size_t)n*64 + lane]*(1.f/16.f);
    int lo = offr[n], hi = offr[n+1];
    for (int i = lo; i < hi; ++i){
      int e = __builtin_amdgcn_readfirstlane(listr[i]);
      int s = __builtin_amdgcn_readfirstlane(ei[e]);
      float rr = qbuf[(size_t)e*64 + lane] * nf[(size_t)s*256 + lane] * gm;
      #pragma unroll
      for (int o = 32; o; o >>= 1) rr += __shfl_xor(rr, o, 64);
      if (lane < 3){
        float comp = rr*uv[(size_t)e*3 + lane];
        size_t gi = (size_t)e*3 + lane;
        if (accum) gvec[gi] += comp; else gvec[gi] = comp;
      }
    }
  }
}

// ================= gh gather via sender CSR (reads w and gagg directly) =================
__global__ __launch_bounds__(256) void k_ghgather0(
    const float* __restrict__ wbuf, const float* __restrict__ gagg0, const int* __restrict__ ei,
    const int* __restrict__ offs_, const int* __restrict__ lists,
    const float* __restrict__ gnfc, float* __restrict__ out){
  int lane = threadIdx.x & 63;
  int wid = blockIdx.x*4 + (threadIdx.x >> 6);
  int nw  = gridDim.x*4;
  for (int n = wid; n < NN; n += nw){
    int lo = offs_[n], hi = offs_[n+1];
    float acc = 0.f;
    for (int i = lo; i < hi; ++i){
      int e = __builtin_amdgcn_readfirstlane(lists[i]);
      int r = __builtin_amdgcn_readfirstlane(ei[NE+e]);
      acc = fmaf(wbuf[(size_t)e*64 + lane], gagg0[(size_t)r*64 + lane], acc);
    }
    out[(size_t)n*64 + lane] = gnfc[lane] + acc*(1.f/16.f);
  }
}

// ---------- CSR-based force assembly ----------
__global__ void k_gpos(const float* __restrict__ gvec,
                       const int* __restrict__ offr, const int* __restrict__ listr,
                       const int* __restrict__ offs_, const int* __restrict__ lists,
                       float* __restrict__ gpos){
  int n = blockIdx.x*256 + threadIdx.x;
  if (n >= NN) return;
  float ax = 0.f, ay = 0.f, az = 0.f;
  for (int i = offs_[n]; i < offs_[n+1]; ++i){
    int e = lists[i];
    ax += gvec[(size_t)e*3]; ay += gvec[(size_t)e*3+1]; az += gvec[(size_t)e*3+2];
  }
  for (int i = offr[n]; i < offr[n+1]; ++i){
    int e = listr[i];
    ax -= gvec[(size_t)e*3]; ay -= gvec[(size_t)e*3+1]; az -= gvec[(size_t)e*3+2];
  }
  gpos[n*3+0] = ax; gpos[n*3+1] = ay; gpos[n*3+2] = az;
}

__global__ void k_writeout(const float* __restrict__ e0g, const float* __restrict__ Etg,
                           const float* __restrict__ td, const float* __restrict__ adp,
                           const float* __restrict__ gpos, void* __restrict__ outv,
                           const int* __restrict__ flag){
  int i = blockIdx.x*256 + threadIdx.x;
  const int total = NG + NG*3 + NN*3 + NG*3 + NN*3; // 60112
  if (i >= total) return;
  float v;
  if (i < 16){
    v = e0g[i] + Etg[i] + Etg[16+i];
  } else if (i < 64){
    int j = i - 16; int g = j/3, t = j - g*3;
    v = (t == 0) ? e0g[g] : Etg[(t-1)*16 + g];
  } else if (i < 64 + NN*3){
    v = -gpos[i-64];
  } else if (i < 64 + NN*3 + 48){
    v = td[i - (64 + NN*3)];
  } else {
    v = adp[i - (64 + NN*3 + 48)];
  }
  if (flag[0]) ((__hip_bfloat16*)outv)[i] = __float2bfloat16(v);
  else         ((float*)outv)[i] = v;
}

extern "C" void kernel_launch(void* const* d_in, const int* in_sizes, int n_in,
                              void* d_out, int out_size, void* d_ws, size_t ws_size,
                              hipStream_t stream) {
  if (ws_size < WS_FLOATS*sizeof(float)) return; // ~164 MB
  const int* ei    = (const int*)d_in[14];
  const int* batch = (const int*)d_in[15];
  float* ws = (float*)d_ws;
  int* flag = (int*)(ws + O_FLAG);

  hipMemsetAsync(ws + OFF_ACC, 0, ACC_FLOATS*sizeof(float), stream);
  k_detect<<<1, 256, 0, stream>>>((const unsigned*)d_in[1], flag);
  k_load_all<<<(LD_TOTAL+255)/256, 256, 0, stream>>>(
      d_in[0], d_in[1], d_in[2], d_in[3], d_in[4], d_in[5], d_in[6], d_in[7],
      d_in[8], d_in[9], d_in[10], d_in[11], d_in[12], d_in[13], ws, flag);
  k_transpose_all<<<320, 256, 0, stream>>>(ws);

  k_geom<<<(NE+255)/256, 256, 0, stream>>>(ws+OFF_PIN, ws+OFF_SHF, ei,
                                           ws+OFF_SH, ws+OFF_EF, ws+OFF_RL, ws+OFF_UV);
  k_init_nodes<<<(NN+3)/4, 256, 0, stream>>>(ws+OFF_ATT, ws+O_WEMB, ws+O_AE, ws+OFF_NF0, ws+O_E0N);

  float* WBUF = ws + O_WBUF;
  float* QBUF = ws + O_QBUF;
  int* offr  = (int*)(ws + O_OFFR);
  int* offs_ = (int*)(ws + O_OFFS);
  int* curr  = (int*)(ws + O_CURR);
  int* curs  = (int*)(ws + O_CURS);
  int* listr = (int*)(ws + O_LISTR);
  int* lists = (int*)(ws + O_LISTS);
  hipMemsetAsync(curr, 0, 2*NN*sizeof(int), stream);
  k_csr_count<<<(NE+255)/256, 256, 0, stream>>>(ei, curr, curs);
  k_csr_scan<<<1, 256, 0, stream>>>(curr, curs, offr, offs_);
  k_csr_fill<<<(NE+255)/256, 256, 0, stream>>>(ei, curr, curs, listr, lists);

  const size_t NF[3]  = {OFF_NF0, OFF_NF1, OFF_NF2};
  const size_t MSG[2] = {OFF_MSG0, OFF_MSG1};
  dim3 ling(120, 4);
  float* GA0 = ws + OFF_AGG;                 // compact NN*64 (AGG free after forward)
  float* GB0 = ws + OFF_AGG + (size_t)NN*64;

  // ---------- forward ----------
  for (int t = 0; t < NT; ++t){
    k_radial<<<1024, 256, 0, stream>>>(ws+OFF_EF, ws+O_R1 + (size_t)t*512, ws+O_R2 + (size_t)t*4096, WBUF);
    k_agg<<<640, 256, 0, stream>>>(WBUF, ws+OFF_SH, ws+NF[t], ei, offr, listr, ws+OFF_AGG);
    k_lin2<<<ling, 256, 0, stream>>>(ws+OFF_AGG, ws+O_WMIX + (size_t)t*12288, nullptr, ws+MSG[t], 0);
    k_lin2<<<ling, 256, 0, stream>>>(ws+NF[t],   ws+O_WSC  + (size_t)t*12288, nullptr, ws+NF[t+1], 0);
    k_lin2<<<ling, 256, 0, stream>>>(ws+MSG[t],  ws+O_WPROD+ (size_t)t*12288, ws+O_WPOLY + (size_t)t*192,
                                     ws+NF[t+1], 3);
    k_edip<<<(NN+3)/4, 256, 0, stream>>>(ws+NF[t+1], ws+O_WE + (size_t)t*64, ws+O_WD + (size_t)t*64,
                                         ws + (t ? O_EN1 : O_EN0), ws+O_ADP);
  }

  // ---------- backward (k=0 plane only) ----------
  k_bwd_head<<<1, 64, 0, stream>>>(ws+O_WPRODT+12288, ws+O_WSCT+12288, ws+O_WE+64, ws+O_WE,
                                   ws+O_GVP, ws+O_GNFC);
  { // t = 1 (WBUF holds w1 from forward)
    k_polybwd0<<<(NN+3)/4, 256, 0, stream>>>(ws+O_GVP, 0, ws+MSG[1], ws+O_WPOLY+192, GB0);
    k_lin0<<<640, 256, 0, stream>>>(GB0, ws+O_WMIXT+12288, GA0);   // gagg0 for t=1
    k_radialQ<<<1024, 256, 0, stream>>>(ws+OFF_EF, ws+OFF_RL, ws+O_R1+512, ws+O_R2+4096, QBUF);
    k_edge_bwd_q<<<640, 256, 0, stream>>>(ws+NF[1], GA0, QBUF, ws+OFF_UV, ei,
                                          offr, listr, ws+O_GVEC, 0);
    k_ghgather0<<<640, 256, 0, stream>>>(WBUF, GA0, ei, offs_, lists, ws+O_GNFC, GB0);
  }
  { // t = 0
    k_lin0<<<640, 256, 0, stream>>>(GB0, ws+O_WPRODT, GA0);        // gmp0 per node
    k_polybwd0<<<(NN+3)/4, 256, 0, stream>>>(GA0, 1, ws+MSG[0], ws+O_WPOLY, GB0);
    k_lin0<<<640, 256, 0, stream>>>(GB0, ws+O_WMIXT, GA0);         // gagg0 for t=0
    k_radialQ<<<1024, 256, 0, stream>>>(ws+OFF_EF, ws+OFF_RL, ws+O_R1, ws+O_R2, QBUF);
    k_edge_bwd_q<<<640, 256, 0, stream>>>(ws+NF[0], GA0, QBUF, ws+OFF_UV, ei,
                                          offr, listr, ws+O_GVEC, 1);
  }

  // reduce BEFORE gpos (per-node energy staging aliases the gpos slots)
  k_reduce<<<(NN+255)/256, 256, 0, stream>>>(ws+O_E0N, ws+O_EN0, ws+O_EN1, ws+O_ADP,
                                             ws+OFF_CHG, ws+OFF_PIN, batch,
                                             ws+O_E0G, ws+O_ETG, ws+O_TD);
  k_gpos<<<(NN+255)/256, 256, 0, stream>>>(ws+O_GVEC, offr, listr, offs_, lists, ws+O_GPOS);
  k_writeout<<<(60112+255)/256, 256, 0, stream>>>(ws+O_E0G, ws+O_ETG, ws+O_TD, ws+O_ADP, ws+O_GPOS, d_out, flag);
}

// Round 8
// 926.840 us; speedup vs baseline: 1.2041x; 1.2041x over previous
//
#include <hip/hip_runtime.h>
#include <hip/hip_bf16.h>

#define NN 10000
#define NE 160000
#define NZ 10
#define NC 64
#define NBES 8
#define NG 16
#define NT 2

static constexpr float PI_F  = 3.14159265358979323846f;
static constexpr float KBES  = 0.63245553203367587f;  // sqrt(2/5)
static constexpr float S3    = 1.73205080756887729f;
static constexpr float S5    = 2.23606797749978969f;
static constexpr float S15   = 3.87298334620741688f;

// ---- workspace layout (float offsets); node tensors stride 256 (planes 0..3) ----
static constexpr size_t OFF_SH   = 0;
static constexpr size_t OFF_EF   = OFF_SH  + (size_t)NE*9;
static constexpr size_t OFF_RL   = OFF_EF  + (size_t)NE*8;
static constexpr size_t OFF_UV   = OFF_RL  + (size_t)NE;
static constexpr size_t OFF_PIN  = OFF_UV  + (size_t)NE*3;
static constexpr size_t OFF_ATT  = OFF_PIN + (size_t)NN*3;
static constexpr size_t OFF_CHG  = OFF_ATT + (size_t)NN*NZ;
static constexpr size_t OFF_SHF  = OFF_CHG + (size_t)NN;
static constexpr size_t NFS      = (size_t)NN*256;
static constexpr size_t OFF_NF0  = OFF_SHF + (size_t)NE*3;
static constexpr size_t OFF_NF1  = OFF_NF0 + NFS;
static constexpr size_t OFF_NF2  = OFF_NF1 + NFS;
static constexpr size_t OFF_MSG0 = OFF_NF2 + NFS;
static constexpr size_t OFF_MSG1 = OFF_MSG0+ NFS;
static constexpr size_t OFF_AGG  = OFF_MSG1+ NFS;    // fwd agg; bwd compact GA0/GB0
static constexpr size_t OFF_W    = OFF_AGG + NFS;
static constexpr size_t O_WEMB   = OFF_W;
static constexpr size_t O_AE     = O_WEMB + 640;
static constexpr size_t O_R1     = O_AE   + 16;
static constexpr size_t O_R2     = O_R1   + 1024;
static constexpr size_t O_R2T    = O_R2   + 8192;
static constexpr size_t O_WMIX   = O_R2T  + 8192;
static constexpr size_t O_WMIXT  = O_WMIX + 24576;
static constexpr size_t O_WSC    = O_WMIXT+ 24576;
static constexpr size_t O_WSCT   = O_WSC  + 24576;
static constexpr size_t O_WPROD  = O_WSCT + 24576;
static constexpr size_t O_WPRODT = O_WPROD+ 24576;
static constexpr size_t O_WPOLY  = O_WPRODT+24576;
static constexpr size_t O_WE     = O_WPOLY+ 384;
static constexpr size_t O_WD     = O_WE   + 128;
static constexpr size_t OFF_ACC  = O_WD   + 128;
static constexpr size_t O_E0G    = OFF_ACC;
static constexpr size_t O_ETG    = O_E0G + 16;
static constexpr size_t O_TD     = O_ETG + 32;
static constexpr size_t O_ADP    = O_TD  + 48;
static constexpr size_t O_GPOS   = O_ADP + (size_t)NN*3;
// per-node energy staging ALIASES gpos (k_reduce runs before k_gpos)
static constexpr size_t O_EN0    = O_GPOS;
static constexpr size_t O_EN1    = O_GPOS + NN;
static constexpr size_t O_E0N    = O_GPOS + 2*NN;
static constexpr size_t O_GVEC   = O_GPOS+ (size_t)NN*3;     // per-edge dE/dvec (NOT zeroed)
static constexpr size_t ACC_FLOATS = O_GVEC - OFF_ACC;
static constexpr size_t O_FLAG   = O_GVEC + (size_t)NE*3;
static constexpr size_t O_GVP    = O_FLAG + 4;
static constexpr size_t O_GNFC   = O_GVP + 64;
static constexpr size_t O_WBUF   = O_GNFC + 64;              // E*64 radial w (fwd) / gh staging (bwd)
static constexpr size_t O_OFFR   = O_WBUF + (size_t)NE*64;   // ints from here
static constexpr size_t O_OFFS   = O_OFFR + (NN+1);
static constexpr size_t O_CURR   = O_OFFS + (NN+1);
static constexpr size_t O_CURS   = O_CURR + NN;
static constexpr size_t O_LISTR  = O_CURS + NN;
static constexpr size_t O_LISTS  = O_LISTR + (size_t)NE;
static constexpr size_t WS_FLOATS= O_LISTS + (size_t)NE;     // ~123 MB

__device__ __forceinline__ float rlane(float v, int l){
  return __int_as_float(__builtin_amdgcn_readlane(__float_as_int(v), l));
}

__device__ __forceinline__ void edge_defdr(float L, float* dd){
  float ur = L*0.2f;
  if (ur < 1.f){
    float u2=ur*ur, u4=u2*u2, u5=u4*ur;
    float fc = 1.f - 21.f*u5 + 35.f*u5*ur - 15.f*u5*u2;
    float omu = 1.f - ur;
    float dfc = -105.f*u4*omu*omu;
    float invr = 1.f/(L + 1e-9f);
    #pragma unroll
    for (int b = 0; b < 8; ++b){
      float nb = (float)(b+1);
      float arg = nb*PI_F*ur;
      float sn = sinf(arg), cs = cosf(arg);
      float bes = KBES*sn*invr;
      float dbes = KBES*(nb*PI_F*0.2f)*cs*invr - bes*invr;
      dd[b] = dbes*fc + bes*dfc*0.2f;
    }
  } else {
    #pragma unroll
    for (int b = 0; b < 8; ++b) dd[b] = 0.f;
  }
}

// ---------- dtype detection ----------
__global__ void k_detect(const unsigned* __restrict__ raw, int* __restrict__ flag){
  __shared__ int found;
  if (threadIdx.x == 0) found = 0;
  __syncthreads();
  for (int i = threadIdx.x; i < 4096; i += 256){
    unsigned w = raw[i];
    if (w == 0x00003F80u || w == 0x3F803F80u) found = 1;
  }
  __syncthreads();
  if (threadIdx.x == 0) flag[0] = found;
}

// ---------- fused loader ----------
static constexpr int LD_CNT[14] = {NN*3, NN*NZ, NN, NE*3, NZ*64, NZ, NT*NBES*64, NT*64*64,
                                   NT*3*64*64, NT*3*64*64, NT*64*3, NT*3*64*64, NT*64, NT*64};
static constexpr int LD_TOTAL = NN*3 + NN*NZ + NN + NE*3 + NZ*64 + NZ + NT*NBES*64 + NT*64*64
                              + 3*(NT*3*64*64) + NT*64*3 + 4*(NT*64) - NT*64*2;
__global__ __launch_bounds__(256) void k_load_all(
    const void* s0, const void* s1, const void* s2, const void* s3, const void* s4,
    const void* s5, const void* s6, const void* s7, const void* s8, const void* s9,
    const void* s10, const void* s11, const void* s12, const void* s13,
    float* __restrict__ ws, const int* __restrict__ flag){
  const void* srcs[14] = {s0,s1,s2,s3,s4,s5,s6,s7,s8,s9,s10,s11,s12,s13};
  const size_t dsts[14] = {OFF_PIN, OFF_ATT, OFF_CHG, OFF_SHF, O_WEMB, O_AE, O_R1, O_R2,
                           O_WMIX, O_WSC, O_WPOLY, O_WPROD, O_WE, O_WD};
  int i = blockIdx.x*256 + threadIdx.x;
  int seg = -1, off = i;
  #pragma unroll
  for (int j = 0; j < 14; ++j){
    if (seg < 0){
      if (off < LD_CNT[j]) seg = j;
      else off -= LD_CNT[j];
    }
  }
  if (seg < 0) return;
  float v = flag[0] ? __bfloat162float(((const __hip_bfloat16*)srcs[seg])[off])
                    : ((const float*)srcs[seg])[off];
  ws[dsts[seg] + off] = v;
}

// ---------- fused transposes ----------
__global__ void k_transpose_all(float* __restrict__ ws){
  const size_t srcs[4] = {O_R2, O_WMIX, O_WSC, O_WPROD};
  const size_t dsts[4] = {O_R2T, O_WMIXT, O_WSCT, O_WPRODT};
  const int cnts[4] = {2, 6, 6, 6};
  int i = blockIdx.x*256 + threadIdx.x;
  if (i >= 20*4096) return;
  int mm = i >> 12, r = (i >> 6) & 63, c = i & 63;
  int grp = 0, m = mm;
  #pragma unroll
  for (int j = 0; j < 4; ++j){ if (m >= cnts[j] && j < 3){ m -= cnts[j]; grp = j+1; } }
  ws[dsts[grp] + (size_t)m*4096 + (size_t)c*64 + r] =
      ws[srcs[grp] + (size_t)m*4096 + (size_t)r*64 + c];
}

// ---------- edge geometry ----------
__global__ void k_geom(const float* __restrict__ pos, const float* __restrict__ shifts,
                       const int* __restrict__ ei, float* __restrict__ sh, float* __restrict__ ef,
                       float* __restrict__ rl, float* __restrict__ uv){
  int e = blockIdx.x*256 + threadIdx.x;
  if (e >= NE) return;
  int s = ei[e], r = ei[NE + e];
  float vx = pos[s*3+0] - pos[r*3+0] + shifts[(size_t)e*3+0];
  float vy = pos[s*3+1] - pos[r*3+1] + shifts[(size_t)e*3+1];
  float vz = pos[s*3+2] - pos[r*3+2] + shifts[(size_t)e*3+2];
  float L = sqrtf(vx*vx + vy*vy + vz*vz + 1e-12f);
  float inv = 1.f / L;
  float x = vx*inv, y = vy*inv, z = vz*inv;
  float* shp = sh + (size_t)e*9;
  shp[0] = 1.f;     shp[1] = S3*x;    shp[2] = S3*y;   shp[3] = S3*z;
  shp[4] = S15*x*y; shp[5] = S15*y*z; shp[6] = 0.5f*S5*(3.f*z*z - 1.f);
  shp[7] = S15*x*z; shp[8] = 0.5f*S15*(x*x - y*y);
  rl[e] = L;
  uv[(size_t)e*3+0] = x; uv[(size_t)e*3+1] = y; uv[(size_t)e*3+2] = z;
  float ur = L * 0.2f;
  float fc = 0.f;
  if (ur < 1.f){
    float u2 = ur*ur, u4 = u2*u2, u5 = u4*ur;
    fc = 1.f - 21.f*u5 + 35.f*u5*ur - 15.f*u5*u2;
  }
  float invr = 1.f / (L + 1e-9f);
  float* efp = ef + (size_t)e*8;
  #pragma unroll
  for (int b = 0; b < 8; ++b){
    float arg = (float)(b+1) * PI_F * ur;
    efp[b] = KBES * sinf(arg) * invr * fc;
  }
}

// ---------- node init ----------
__global__ __launch_bounds__(256) void k_init_nodes(
    const float* __restrict__ attrs, const float* __restrict__ Wemb,
    const float* __restrict__ ae, float* __restrict__ nf0, float* __restrict__ e0n){
  int lane = threadIdx.x & 63;
  int n = blockIdx.x*4 + (threadIdx.x >> 6);
  if (n >= NN) return;
  float acc = 0.f;
  #pragma unroll
  for (int z = 0; z < NZ; ++z) acc = fmaf(attrs[(size_t)n*NZ+z], Wemb[z*64+lane], acc);
  size_t base = (size_t)n*256;
  nf0[base + lane] = acc;
  #pragma unroll
  for (int k = 1; k < 4; ++k) nf0[base + (size_t)k*64 + lane] = 0.f;
  if (lane == 0){
    float e = 0.f;
    #pragma unroll
    for (int z = 0; z < NZ; ++z) e = fmaf(attrs[(size_t)n*NZ+z], ae[z], e);
    e0n[n] = e;
  }
}

// ================= CSR construction =================
__global__ void k_csr_count(const int* __restrict__ ei, int* __restrict__ cntr, int* __restrict__ cnts){
  int e = blockIdx.x*256 + threadIdx.x;
  if (e >= NE) return;
  atomicAdd(&cntr[ei[NE+e]], 1);
  atomicAdd(&cnts[ei[e]], 1);
}

__global__ void k_csr_scan(int* __restrict__ cntr, int* __restrict__ cnts,
                           int* __restrict__ offr, int* __restrict__ offs_){
  __shared__ int part[256];
  for (int q = 0; q < 2; ++q){
    int* c   = q ? cnts  : cntr;
    int* off = q ? offs_ : offr;
    const int chunk = (NN + 255)/256;
    int lo = threadIdx.x*chunk, hi = lo+chunk; if (hi > NN) hi = NN; if (lo > NN) lo = NN;
    int s = 0;
    for (int i = lo; i < hi; ++i) s += c[i];
    part[threadIdx.x] = s;
    __syncthreads();
    for (int o = 1; o < 256; o <<= 1){
      int v = (threadIdx.x >= o) ? part[threadIdx.x-o] : 0;
      __syncthreads();
      part[threadIdx.x] += v;
      __syncthreads();
    }
    int run = (threadIdx.x == 0) ? 0 : part[threadIdx.x-1];
    for (int i = lo; i < hi; ++i){
      int ci = c[i];
      off[i] = run; c[i] = run;
      run += ci;
    }
    if (threadIdx.x == 255) off[NN] = run;
    __syncthreads();
  }
}

__global__ void k_csr_fill(const int* __restrict__ ei, int* __restrict__ curr, int* __restrict__ curs,
                           int* __restrict__ listr, int* __restrict__ lists){
  int e = blockIdx.x*256 + threadIdx.x;
  if (e >= NE) return;
  int pr = atomicAdd(&curr[ei[NE+e]], 1); listr[pr] = e;
  int ps = atomicAdd(&curs[ei[e]], 1);    lists[ps] = e;
}

// ================= radial MLP forward (VGPR-resident) =================
__global__ __launch_bounds__(256) void k_radial(
    const float* __restrict__ ef, const float* __restrict__ R1, const float* __restrict__ R2,
    float* __restrict__ wbuf){
  int lane = threadIdx.x & 63;
  int wid = blockIdx.x*4 + (threadIdx.x >> 6);
  int nw  = gridDim.x*4;
  float r1c[8], r2c[64];
  #pragma unroll
  for (int j = 0; j < 8; ++j)  r1c[j] = R1[j*64 + lane];
  #pragma unroll
  for (int j = 0; j < 64; ++j) r2c[j] = R2[j*64 + lane];
  for (int e = wid; e < NE; e += nw){
    float efv = ef[(size_t)e*8 + (lane & 7)];
    float a = 0.f;
    #pragma unroll
    for (int b = 0; b < 8; ++b) a = fmaf(rlane(efv, b), r1c[b], a);
    float sg = 1.f/(1.f + __expf(-a));
    float sl = a*sg;
    float w0 = 0.f, w1 = 0.f, w2 = 0.f, w3 = 0.f;
    #pragma unroll
    for (int j = 0; j < 64; j += 4){
      w0 = fmaf(rlane(sl, j  ), r2c[j  ], w0);
      w1 = fmaf(rlane(sl, j+1), r2c[j+1], w1);
      w2 = fmaf(rlane(sl, j+2), r2c[j+2], w2);
      w3 = fmaf(rlane(sl, j+3), r2c[j+3], w3);
    }
    wbuf[(size_t)e*64 + lane] = (w0+w1) + (w2+w3);
  }
}

// ================= aggregation via receiver CSR (planes 0..3), 2x unrolled =================
__global__ __launch_bounds__(256) void k_agg(
    const float* __restrict__ wbuf, const float* __restrict__ sh, const float* __restrict__ nf,
    const int* __restrict__ ei, const int* __restrict__ offr, const int* __restrict__ listr,
    float* __restrict__ agg){
  int lane = threadIdx.x & 63;
  int wid = blockIdx.x*4 + (threadIdx.x >> 6);
  int nw  = gridDim.x*4;
  for (int n = wid; n < NN; n += nw){
    int lo = offr[n], hi = offr[n+1];
    float acc[4];
    #pragma unroll
    for (int k = 0; k < 4; ++k) acc[k] = 0.f;
    int i = lo;
    for (; i + 2 <= hi; i += 2){
      int e0 = __builtin_amdgcn_readfirstlane(listr[i]);
      int e1 = __builtin_amdgcn_readfirstlane(listr[i+1]);
      int s0 = __builtin_amdgcn_readfirstlane(ei[e0]);
      int s1 = __builtin_amdgcn_readfirstlane(ei[e1]);
      float w0 = wbuf[(size_t)e0*64 + lane];
      float w1 = wbuf[(size_t)e1*64 + lane];
      float h0 = nf[(size_t)s0*256 + lane];
      float h1 = nf[(size_t)s1*256 + lane];
      float wh0 = w0*h0, wh1 = w1*h1;
      const float* sp0 = sh + (size_t)e0*9;
      const float* sp1 = sh + (size_t)e1*9;
      #pragma unroll
      for (int k = 0; k < 4; ++k) acc[k] = fmaf(wh1, sp1[k], fmaf(wh0, sp0[k], acc[k]));
    }
    if (i < hi){
      int e = __builtin_amdgcn_readfirstlane(listr[i]);
      int s = __builtin_amdgcn_readfirstlane(ei[e]);
      float wh = wbuf[(size_t)e*64 + lane] * nf[(size_t)s*256 + lane];
      const float* shp = sh + (size_t)e*9;
      #pragma unroll
      for (int k = 0; k < 4; ++k) acc[k] = fmaf(wh, shp[k], acc[k]);
    }
    size_t ob = (size_t)n*256 + lane;
    #pragma unroll
    for (int k = 0; k < 4; ++k) agg[ob + (size_t)k*64] = acc[k]*(1.f/16.f);
  }
}

// ================= per-l linear, readlane matvec (gridDim.y = 4) =================
__global__ __launch_bounds__(256) void k_lin2(
    const float* __restrict__ in, const float* __restrict__ W3, const float* __restrict__ wp,
    float* __restrict__ out, int flags){
  int k = blockIdx.y;
  int l = (k==0) ? 0 : 1;
  const float* W = W3 + (size_t)l*4096;
  int lane = threadIdx.x & 63;
  float wcol[64];
  #pragma unroll
  for (int j = 0; j < 64; ++j) wcol[j] = W[j*64 + lane];
  float p0 = 0.f, p1 = 0.f, p2 = 0.f;
  if (flags & 2){ p0 = wp[lane*3]; p1 = wp[lane*3+1]; p2 = wp[lane*3+2]; }
  int wid = blockIdx.x*4 + (threadIdx.x >> 6);
  int nw  = gridDim.x*4;
  for (int n = wid; n < NN; n += nw){
    size_t base = (size_t)n*256;
    float x = in[base + (size_t)k*64 + lane];
    if (flags & 2){
      float s0 = in[base + lane];
      x *= fmaf(fmaf(p2, s0, p1), s0, p0);
    }
    float a0 = 0.f, a1 = 0.f, a2 = 0.f, a3 = 0.f;
    #pragma unroll
    for (int j = 0; j < 64; j += 4){
      a0 = fmaf(rlane(x, j  ), wcol[j  ], a0);
      a1 = fmaf(rlane(x, j+1), wcol[j+1], a1);
      a2 = fmaf(rlane(x, j+2), wcol[j+2], a2);
      a3 = fmaf(rlane(x, j+3), wcol[j+3], a3);
    }
    float acc = (a0+a1) + (a2+a3);
    float* o = out + base + (size_t)k*64 + lane;
    if (flags & 1) *o += acc; else *o = acc;
  }
}

// ================= compact 64-wide matvec =================
__global__ __launch_bounds__(256) void k_lin0(
    const float* __restrict__ in, const float* __restrict__ W, float* __restrict__ out){
  int lane = threadIdx.x & 63;
  float wcol[64];
  #pragma unroll
  for (int j = 0; j < 64; ++j) wcol[j] = W[j*64 + lane];
  int wid = blockIdx.x*4 + (threadIdx.x >> 6);
  int nw  = gridDim.x*4;
  for (int n = wid; n < NN; n += nw){
    float x = in[(size_t)n*64 + lane];
    float a0 = 0.f, a1 = 0.f, a2 = 0.f, a3 = 0.f;
    #pragma unroll
    for (int j = 0; j < 64; j += 4){
      a0 = fmaf(rlane(x, j  ), wcol[j  ], a0);
      a1 = fmaf(rlane(x, j+1), wcol[j+1], a1);
      a2 = fmaf(rlane(x, j+2), wcol[j+2], a2);
      a3 = fmaf(rlane(x, j+3), wcol[j+3], a3);
    }
    out[(size_t)n*64 + lane] = (a0+a1) + (a2+a3);
  }
}

// ================= energies & dipoles: per-node staging =================
__global__ __launch_bounds__(256) void k_edip(
    const float* __restrict__ nf, const float* __restrict__ we,
    const float* __restrict__ wd, float* __restrict__ en, float* __restrict__ adp){
  int lane = threadIdx.x & 63;
  int n = blockIdx.x*4 + (threadIdx.x >> 6);
  if (n >= NN) return;
  float v = nf[(size_t)n*256 + lane]*we[lane];
  #pragma unroll
  for (int o = 32; o; o >>= 1) v += __shfl_xor(v, o, 64);
  if (lane == 0) en[n] = v;
  #pragma unroll
  for (int j = 0; j < 3; ++j){
    float dv = nf[(size_t)n*256 + (size_t)(j+1)*64 + lane]*wd[lane];
    #pragma unroll
    for (int o = 32; o; o >>= 1) dv += __shfl_xor(dv, o, 64);
    if (lane == 0) adp[n*3+j] += dv;
  }
}

// ================= segmented final reduction =================
__global__ void k_reduce(const float* __restrict__ e0n, const float* __restrict__ en0,
                         const float* __restrict__ en1, const float* __restrict__ adp,
                         const float* __restrict__ q, const float* __restrict__ pos,
                         const int* __restrict__ batch, float* __restrict__ e0g,
                         float* __restrict__ Etg, float* __restrict__ td){
  int n = blockIdx.x*256 + threadIdx.x;
  int lane = threadIdx.x & 63;
  bool valid = (n < NN);
  int g = valid ? batch[n] : -1;
  float v0=0.f, v1=0.f, v2=0.f, tx=0.f, ty=0.f, tz=0.f;
  if (valid){
    v0 = e0n[n]; v1 = en0[n]; v2 = en1[n];
    float qq = q[n];
    tx = adp[n*3+0] + qq*pos[n*3+0];
    ty = adp[n*3+1] + qq*pos[n*3+1];
    tz = adp[n*3+2] + qq*pos[n*3+2];
  }
  int g0 = __shfl(g, 0, 64), g63 = __shfl(g, 63, 64);
  if (g0 == g63 && g0 >= 0){
    #pragma unroll
    for (int o = 32; o; o >>= 1){
      v0 += __shfl_xor(v0, o, 64); v1 += __shfl_xor(v1, o, 64); v2 += __shfl_xor(v2, o, 64);
      tx += __shfl_xor(tx, o, 64); ty += __shfl_xor(ty, o, 64); tz += __shfl_xor(tz, o, 64);
    }
    if (lane == 0){
      atomicAdd(&e0g[g0], v0); atomicAdd(&Etg[g0], v1); atomicAdd(&Etg[16+g0], v2);
      atomicAdd(&td[g0*3+0], tx); atomicAdd(&td[g0*3+1], ty); atomicAdd(&td[g0*3+2], tz);
    }
  } else if (valid){
    atomicAdd(&e0g[g], v0); atomicAdd(&Etg[g], v1); atomicAdd(&Etg[16+g], v2);
    atomicAdd(&td[g*3+0], tx); atomicAdd(&td[g*3+1], ty); atomicAdd(&td[g*3+2], tz);
  }
}

// ================= backward head =================
__global__ void k_bwd_head(const float* __restrict__ WPRODT1, const float* __restrict__ WSCT1,
                           const float* __restrict__ we1, const float* __restrict__ we0,
                           float* __restrict__ gvp, float* __restrict__ gnfc){
  int d = threadIdx.x;
  float a = 0.f, b = 0.f;
  #pragma unroll
  for (int c = 0; c < 64; ++c){
    float w = we1[c];
    a = fmaf(w, WPRODT1[c*64+d], a);
    b = fmaf(w, WSCT1[c*64+d], b);
  }
  gvp[d] = a;
  gnfc[d] = b + we0[d];
}

// ================= poly backward (k=0 plane) =================
__global__ __launch_bounds__(256) void k_polybwd0(
    const float* __restrict__ gmp, int per_node, const float* __restrict__ msgbase,
    const float* __restrict__ wp, float* __restrict__ out){
  int lane = threadIdx.x & 63;
  int n = blockIdx.x*4 + (threadIdx.x >> 6);
  if (n >= NN) return;
  float g = per_node ? gmp[(size_t)n*64 + lane] : gmp[lane];
  float s0 = msgbase[(size_t)n*256 + lane];
  float p0 = wp[lane*3], p1 = wp[lane*3+1], p2 = wp[lane*3+2];
  float poly = fmaf(fmaf(p2, s0, p1), s0, p0);
  float dp   = fmaf(2.f*p2, s0, p1);
  out[(size_t)n*64 + lane] = g*fmaf(s0, dp, poly);
}

// ================= edge-parallel fused backward =================
// Per edge: recompute a, silu', defdr, t; Q[d] = sum_j silu'_j t_j R2[j][d];
// rr = sum_d Q[d]*h_s[d]*gm_r[d]; gvec = rr*u. If need_gh: W[d]=sum_j silu(a_j)R2[j][d],
// stage gh = W*gm into wbuf (streamed by k_ghgather0).
// Iterations are independent -> loads pipeline across edges (fixes the latency chain).
__global__ __launch_bounds__(256) void k_bwdE(
    const float* __restrict__ ef, const float* __restrict__ rl, const float* __restrict__ uv,
    const float* __restrict__ nf, const float* __restrict__ gagg0, const int* __restrict__ ei,
    const float* __restrict__ R1, const float* __restrict__ R2,
    float* __restrict__ wbuf, float* __restrict__ gvec, int need_gh, int accum){
  int lane = threadIdx.x & 63;
  int wid = blockIdx.x*4 + (threadIdx.x >> 6);
  int nw  = gridDim.x*4;
  float r1c[8], r2c[64];
  #pragma unroll
  for (int j = 0; j < 8; ++j)  r1c[j] = R1[j*64 + lane];
  #pragma unroll
  for (int j = 0; j < 64; ++j) r2c[j] = R2[j*64 + lane];
  for (int e = wid; e < NE; e += nw){
    int s = __builtin_amdgcn_readfirstlane(ei[e]);
    int r = __builtin_amdgcn_readfirstlane(ei[NE+e]);
    float efv = ef[(size_t)e*8 + (lane & 7)];
    float L   = rl[e];
    float h   = nf[(size_t)s*256 + lane];
    float gm  = gagg0[(size_t)r*64 + lane]*(1.f/16.f);
    float a = 0.f;
    #pragma unroll
    for (int b = 0; b < 8; ++b) a = fmaf(rlane(efv, b), r1c[b], a);
    float sg = 1.f/(1.f + __expf(-a));
    float dd[8];
    edge_defdr(L, dd);
    float t = 0.f;
    #pragma unroll
    for (int b = 0; b < 8; ++b) t = fmaf(r1c[b], dd[b], t);
    float q  = sg*fmaf(a, 1.f - sg, 1.f)*t;   // silu'(a_j)*t_j  (lane = j)
    float sl = a*sg;                           // silu(a_j)
    float Q0=0.f, Q1=0.f, W0=0.f, W1=0.f;
    if (need_gh){
      #pragma unroll
      for (int j = 0; j < 64; j += 2){
        Q0 = fmaf(rlane(q,  j  ), r2c[j  ], Q0);
        Q1 = fmaf(rlane(q,  j+1), r2c[j+1], Q1);
        W0 = fmaf(rlane(sl, j  ), r2c[j  ], W0);
        W1 = fmaf(rlane(sl, j+1), r2c[j+1], W1);
      }
    } else {
      #pragma unroll
      for (int j = 0; j < 64; j += 2){
        Q0 = fmaf(rlane(q,  j  ), r2c[j  ], Q0);
        Q1 = fmaf(rlane(q,  j+1), r2c[j+1], Q1);
      }
    }
    float rr = (Q0+Q1)*h*gm;                   // lane = d
    #pragma unroll
    for (int o = 32; o; o >>= 1) rr += __shfl_xor(rr, o, 64);
    if (lane < 3){
      float comp = rr*uv[(size_t)e*3 + lane];
      size_t gi = (size_t)e*3 + lane;
      if (accum) gvec[gi] += comp; else gvec[gi] = comp;
    }
    if (need_gh) wbuf[(size_t)e*64 + lane] = (W0+W1)*gm;
  }
}

// ================= gh gather via sender CSR (streams staged gh), 2x unrolled =================
__global__ __launch_bounds__(256) void k_ghgather0(
    const float* __restrict__ ghc, const int* __restrict__ offs_, const int* __restrict__ lists,
    const float* __restrict__ gnfc, float* __restrict__ out){
  int lane = threadIdx.x & 63;
  int wid = blockIdx.x*4 + (threadIdx.x >> 6);
  int nw  = gridDim.x*4;
  for (int n = wid; n < NN; n += nw){
    int lo = offs_[n], hi = offs_[n+1];
    float acc = gnfc[lane];
    int i = lo;
    for (; i + 2 <= hi; i += 2){
      int e0 = __builtin_amdgcn_readfirstlane(lists[i]);
      int e1 = __builtin_amdgcn_readfirstlane(lists[i+1]);
      float v0 = ghc[(size_t)e0*64 + lane];
      float v1 = ghc[(size_t)e1*64 + lane];
      acc += v0 + v1;
    }
    if (i < hi){
      int e = __builtin_amdgcn_readfirstlane(lists[i]);
      acc += ghc[(size_t)e*64 + lane];
    }
    out[(size_t)n*64 + lane] = acc;
  }
}

// ---------- CSR-based force assembly ----------
__global__ void k_gpos(const float* __restrict__ gvec,
                       const int* __restrict__ offr, const int* __restrict__ listr,
                       const int* __restrict__ offs_, const int* __restrict__ lists,
                       float* __restrict__ gpos){
  int n = blockIdx.x*256 + threadIdx.x;
  if (n >= NN) return;
  float ax = 0.f, ay = 0.f, az = 0.f;
  for (int i = offs_[n]; i < offs_[n+1]; ++i){
    int e = lists[i];
    ax += gvec[(size_t)e*3]; ay += gvec[(size_t)e*3+1]; az += gvec[(size_t)e*3+2];
  }
  for (int i = offr[n]; i < offr[n+1]; ++i){
    int e = listr[i];
    ax -= gvec[(size_t)e*3]; ay -= gvec[(size_t)e*3+1]; az -= gvec[(size_t)e*3+2];
  }
  gpos[n*3+0] = ax; gpos[n*3+1] = ay; gpos[n*3+2] = az;
}

__global__ void k_writeout(const float* __restrict__ e0g, const float* __restrict__ Etg,
                           const float* __restrict__ td, const float* __restrict__ adp,
                           const float* __restrict__ gpos, void* __restrict__ outv,
                           const int* __restrict__ flag){
  int i = blockIdx.x*256 + threadIdx.x;
  const int total = NG + NG*3 + NN*3 + NG*3 + NN*3; // 60112
  if (i >= total) return;
  float v;
  if (i < 16){
    v = e0g[i] + Etg[i] + Etg[16+i];
  } else if (i < 64){
    int j = i - 16; int g = j/3, t = j - g*3;
    v = (t == 0) ? e0g[g] : Etg[(t-1)*16 + g];
  } else if (i < 64 + NN*3){
    v = -gpos[i-64];
  } else if (i < 64 + NN*3 + 48){
    v = td[i - (64 + NN*3)];
  } else {
    v = adp[i - (64 + NN*3 + 48)];
  }
  if (flag[0]) ((__hip_bfloat16*)outv)[i] = __float2bfloat16(v);
  else         ((float*)outv)[i] = v;
}

extern "C" void kernel_launch(void* const* d_in, const int* in_sizes, int n_in,
                              void* d_out, int out_size, void* d_ws, size_t ws_size,
                              hipStream_t stream) {
  if (ws_size < WS_FLOATS*sizeof(float)) return; // ~123 MB
  const int* ei    = (const int*)d_in[14];
  const int* batch = (const int*)d_in[15];
  float* ws = (float*)d_ws;
  int* flag = (int*)(ws + O_FLAG);

  hipMemsetAsync(ws + OFF_ACC, 0, ACC_FLOATS*sizeof(float), stream);
  k_detect<<<1, 256, 0, stream>>>((const unsigned*)d_in[1], flag);
  k_load_all<<<(LD_TOTAL+255)/256, 256, 0, stream>>>(
      d_in[0], d_in[1], d_in[2], d_in[3], d_in[4], d_in[5], d_in[6], d_in[7],
      d_in[8], d_in[9], d_in[10], d_in[11], d_in[12], d_in[13], ws, flag);
  k_transpose_all<<<320, 256, 0, stream>>>(ws);

  k_geom<<<(NE+255)/256, 256, 0, stream>>>(ws+OFF_PIN, ws+OFF_SHF, ei,
                                           ws+OFF_SH, ws+OFF_EF, ws+OFF_RL, ws+OFF_UV);
  k_init_nodes<<<(NN+3)/4, 256, 0, stream>>>(ws+OFF_ATT, ws+O_WEMB, ws+O_AE, ws+OFF_NF0, ws+O_E0N);

  float* WBUF = ws + O_WBUF;
  int* offr  = (int*)(ws + O_OFFR);
  int* offs_ = (int*)(ws + O_OFFS);
  int* curr  = (int*)(ws + O_CURR);
  int* curs  = (int*)(ws + O_CURS);
  int* listr = (int*)(ws + O_LISTR);
  int* lists = (int*)(ws + O_LISTS);
  hipMemsetAsync(curr, 0, 2*NN*sizeof(int), stream);
  k_csr_count<<<(NE+255)/256, 256, 0, stream>>>(ei, curr, curs);
  k_csr_scan<<<1, 256, 0, stream>>>(curr, curs, offr, offs_);
  k_csr_fill<<<(NE+255)/256, 256, 0, stream>>>(ei, curr, curs, listr, lists);

  const size_t NF[3]  = {OFF_NF0, OFF_NF1, OFF_NF2};
  const size_t MSG[2] = {OFF_MSG0, OFF_MSG1};
  dim3 ling(120, 4);
  float* GA0 = ws + OFF_AGG;                 // compact NN*64 (AGG free after forward)
  float* GB0 = ws + OFF_AGG + (size_t)NN*64;

  // ---------- forward ----------
  for (int t = 0; t < NT; ++t){
    k_radial<<<1024, 256, 0, stream>>>(ws+OFF_EF, ws+O_R1 + (size_t)t*512, ws+O_R2 + (size_t)t*4096, WBUF);
    k_agg<<<640, 256, 0, stream>>>(WBUF, ws+OFF_SH, ws+NF[t], ei, offr, listr, ws+OFF_AGG);
    k_lin2<<<ling, 256, 0, stream>>>(ws+OFF_AGG, ws+O_WMIX + (size_t)t*12288, nullptr, ws+MSG[t], 0);
    k_lin2<<<ling, 256, 0, stream>>>(ws+NF[t],   ws+O_WSC  + (size_t)t*12288, nullptr, ws+NF[t+1], 0);
    k_lin2<<<ling, 256, 0, stream>>>(ws+MSG[t],  ws+O_WPROD+ (size_t)t*12288, ws+O_WPOLY + (size_t)t*192,
                                     ws+NF[t+1], 3);
    k_edip<<<(NN+3)/4, 256, 0, stream>>>(ws+NF[t+1], ws+O_WE + (size_t)t*64, ws+O_WD + (size_t)t*64,
                                         ws + (t ? O_EN1 : O_EN0), ws+O_ADP);
  }

  // ---------- backward (k=0 plane only) ----------
  k_bwd_head<<<1, 64, 0, stream>>>(ws+O_WPRODT+12288, ws+O_WSCT+12288, ws+O_WE+64, ws+O_WE,
                                   ws+O_GVP, ws+O_GNFC);
  { // t = 1
    k_polybwd0<<<(NN+3)/4, 256, 0, stream>>>(ws+O_GVP, 0, ws+MSG[1], ws+O_WPOLY+192, GB0);
    k_lin0<<<640, 256, 0, stream>>>(GB0, ws+O_WMIXT+12288, GA0);   // gagg0 for t=1
    k_bwdE<<<1024, 256, 0, stream>>>(ws+OFF_EF, ws+OFF_RL, ws+OFF_UV,
                                     ws+NF[1], GA0, ei,
                                     ws+O_R1+512, ws+O_R2+4096,
                                     WBUF, ws+O_GVEC, 1, 0);
    k_ghgather0<<<640, 256, 0, stream>>>(WBUF, offs_, lists, ws+O_GNFC, GB0);
  }
  { // t = 0
    k_lin0<<<640, 256, 0, stream>>>(GB0, ws+O_WPRODT, GA0);        // gmp0 per node
    k_polybwd0<<<(NN+3)/4, 256, 0, stream>>>(GA0, 1, ws+MSG[0], ws+O_WPOLY, GB0);
    k_lin0<<<640, 256, 0, stream>>>(GB0, ws+O_WMIXT, GA0);         // gagg0 for t=0
    k_bwdE<<<1024, 256, 0, stream>>>(ws+OFF_EF, ws+OFF_RL, ws+OFF_UV,
                                     ws+NF[0], GA0, ei,
                                     ws+O_R1, ws+O_R2,
                                     WBUF, ws+O_GVEC, 0, 1);
  }

  // reduce BEFORE gpos (per-node energy staging aliases the gpos slots)
  k_reduce<<<(NN+255)/256, 256, 0, stream>>>(ws+O_E0N, ws+O_EN0, ws+O_EN1, ws+O_ADP,
                                             ws+OFF_CHG, ws+OFF_PIN, batch,
                                             ws+O_E0G, ws+O_ETG, ws+O_TD);
  k_gpos<<<(NN+255)/256, 256, 0, stream>>>(ws+O_GVEC, offr, listr, offs_, lists, ws+O_GPOS);
  k_writeout<<<(60112+255)/256, 256, 0, stream>>>(ws+O_E0G, ws+O_ETG, ws+O_TD, ws+O_ADP, ws+O_GPOS, d_out, flag);
}

// Round 9
// 760.361 us; speedup vs baseline: 1.4677x; 1.2189x over previous
//
#include <hip/hip_runtime.h>
#include <hip/hip_bf16.h>

#define NN 10000
#define NE 160000
#define NZ 10
#define NC 64
#define NBES 8
#define NG 16
#define NT 2

static constexpr float PI_F  = 3.14159265358979323846f;
static constexpr float KBES  = 0.63245553203367587f;  // sqrt(2/5)
static constexpr float S3    = 1.73205080756887729f;
static constexpr float S5    = 2.23606797749978969f;
static constexpr float S15   = 3.87298334620741688f;

// ---- workspace layout (float offsets); node tensors stride 256 (planes 0..3) ----
static constexpr size_t OFF_SH   = 0;
static constexpr size_t OFF_EF   = OFF_SH  + (size_t)NE*9;
static constexpr size_t OFF_RL   = OFF_EF  + (size_t)NE*8;
static constexpr size_t OFF_UV   = OFF_RL  + (size_t)NE;
static constexpr size_t OFF_PIN  = OFF_UV  + (size_t)NE*3;
static constexpr size_t OFF_ATT  = OFF_PIN + (size_t)NN*3;
static constexpr size_t OFF_CHG  = OFF_ATT + (size_t)NN*NZ;
static constexpr size_t OFF_SHF  = OFF_CHG + (size_t)NN;
static constexpr size_t NFS      = (size_t)NN*256;
static constexpr size_t OFF_NF0  = OFF_SHF + (size_t)NE*3;
static constexpr size_t OFF_NF1  = OFF_NF0 + NFS;
static constexpr size_t OFF_NF2  = OFF_NF1 + NFS;
static constexpr size_t OFF_MSG0 = OFF_NF2 + NFS;
static constexpr size_t OFF_MSG1 = OFF_MSG0+ NFS;
static constexpr size_t OFF_AGG  = OFF_MSG1+ NFS;    // fwd agg; bwd compact GA0/GB0
static constexpr size_t OFF_W    = OFF_AGG + NFS;
static constexpr size_t O_WEMB   = OFF_W;
static constexpr size_t O_AE     = O_WEMB + 640;
static constexpr size_t O_R1     = O_AE   + 16;
static constexpr size_t O_R2     = O_R1   + 1024;
static constexpr size_t O_R2T    = O_R2   + 8192;
static constexpr size_t O_WMIX   = O_R2T  + 8192;
static constexpr size_t O_WMIXT  = O_WMIX + 24576;
static constexpr size_t O_WSC    = O_WMIXT+ 24576;
static constexpr size_t O_WSCT   = O_WSC  + 24576;
static constexpr size_t O_WPROD  = O_WSCT + 24576;
static constexpr size_t O_WPRODT = O_WPROD+ 24576;
static constexpr size_t O_WPOLY  = O_WPRODT+24576;
static constexpr size_t O_WE     = O_WPOLY+ 384;
static constexpr size_t O_WD     = O_WE   + 128;
static constexpr size_t OFF_ACC  = O_WD   + 128;
static constexpr size_t O_E0G    = OFF_ACC;
static constexpr size_t O_ETG    = O_E0G + 16;
static constexpr size_t O_TD     = O_ETG + 32;
static constexpr size_t O_ADP    = O_TD  + 48;
static constexpr size_t O_GPOS   = O_ADP + (size_t)NN*3;
// per-node energy staging ALIASES gpos (k_reduce runs before k_gpos)
static constexpr size_t O_EN0    = O_GPOS;
static constexpr size_t O_EN1    = O_GPOS + NN;
static constexpr size_t O_E0N    = O_GPOS + 2*NN;
static constexpr size_t O_GVEC   = O_GPOS+ (size_t)NN*3;     // per-edge dE/dvec (NOT zeroed)
static constexpr size_t ACC_FLOATS = O_GVEC - OFF_ACC;
static constexpr size_t O_FLAG   = O_GVEC + (size_t)NE*3;
static constexpr size_t O_GVP    = O_FLAG + 4;
static constexpr size_t O_GNFC   = O_GVP + 64;
static constexpr size_t O_WBUF   = O_GNFC + 64;              // E*64 radial w
static constexpr size_t O_OFFR   = O_WBUF + (size_t)NE*64;   // ints from here
static constexpr size_t O_OFFS   = O_OFFR + (NN+1);
static constexpr size_t O_CURR   = O_OFFS + (NN+1);
static constexpr size_t O_CURS   = O_CURR + NN;
static constexpr size_t O_LISTR  = O_CURS + NN;
static constexpr size_t O_LISTS  = O_LISTR + (size_t)NE;
static constexpr size_t WS_FLOATS= O_LISTS + (size_t)NE;     // ~123 MB

__device__ __forceinline__ float rlane(float v, int l){
  return __int_as_float(__builtin_amdgcn_readlane(__float_as_int(v), l));
}

__device__ __forceinline__ void edge_defdr(float L, float* dd){
  float ur = L*0.2f;
  if (ur < 1.f){
    float u2=ur*ur, u4=u2*u2, u5=u4*ur;
    float fc = 1.f - 21.f*u5 + 35.f*u5*ur - 15.f*u5*u2;
    float omu = 1.f - ur;
    float dfc = -105.f*u4*omu*omu;
    float invr = 1.f/(L + 1e-9f);
    #pragma unroll
    for (int b = 0; b < 8; ++b){
      float nb = (float)(b+1);
      float arg = nb*PI_F*ur;
      float sn = __sinf(arg), cs = __cosf(arg);
      float bes = KBES*sn*invr;
      float dbes = KBES*(nb*PI_F*0.2f)*cs*invr - bes*invr;
      dd[b] = dbes*fc + bes*dfc*0.2f;
    }
  } else {
    #pragma unroll
    for (int b = 0; b < 8; ++b) dd[b] = 0.f;
  }
}

// ---------- dtype detection ----------
__global__ void k_detect(const unsigned* __restrict__ raw, int* __restrict__ flag){
  __shared__ int found;
  if (threadIdx.x == 0) found = 0;
  __syncthreads();
  for (int i = threadIdx.x; i < 4096; i += 256){
    unsigned w = raw[i];
    if (w == 0x00003F80u || w == 0x3F803F80u) found = 1;
  }
  __syncthreads();
  if (threadIdx.x == 0) flag[0] = found;
}

// ---------- fused loader ----------
static constexpr int LD_CNT[14] = {NN*3, NN*NZ, NN, NE*3, NZ*64, NZ, NT*NBES*64, NT*64*64,
                                   NT*3*64*64, NT*3*64*64, NT*64*3, NT*3*64*64, NT*64, NT*64};
static constexpr int LD_TOTAL = NN*3 + NN*NZ + NN + NE*3 + NZ*64 + NZ + NT*NBES*64 + NT*64*64
                              + 3*(NT*3*64*64) + NT*64*3 + 4*(NT*64) - NT*64*2;
__global__ __launch_bounds__(256) void k_load_all(
    const void* s0, const void* s1, const void* s2, const void* s3, const void* s4,
    const void* s5, const void* s6, const void* s7, const void* s8, const void* s9,
    const void* s10, const void* s11, const void* s12, const void* s13,
    float* __restrict__ ws, const int* __restrict__ flag){
  const void* srcs[14] = {s0,s1,s2,s3,s4,s5,s6,s7,s8,s9,s10,s11,s12,s13};
  const size_t dsts[14] = {OFF_PIN, OFF_ATT, OFF_CHG, OFF_SHF, O_WEMB, O_AE, O_R1, O_R2,
                           O_WMIX, O_WSC, O_WPOLY, O_WPROD, O_WE, O_WD};
  int i = blockIdx.x*256 + threadIdx.x;
  int seg = -1, off = i;
  #pragma unroll
  for (int j = 0; j < 14; ++j){
    if (seg < 0){
      if (off < LD_CNT[j]) seg = j;
      else off -= LD_CNT[j];
    }
  }
  if (seg < 0) return;
  float v = flag[0] ? __bfloat162float(((const __hip_bfloat16*)srcs[seg])[off])
                    : ((const float*)srcs[seg])[off];
  ws[dsts[seg] + off] = v;
}

// ---------- fused transposes ----------
__global__ void k_transpose_all(float* __restrict__ ws){
  const size_t srcs[4] = {O_R2, O_WMIX, O_WSC, O_WPROD};
  const size_t dsts[4] = {O_R2T, O_WMIXT, O_WSCT, O_WPRODT};
  const int cnts[4] = {2, 6, 6, 6};
  int i = blockIdx.x*256 + threadIdx.x;
  if (i >= 20*4096) return;
  int mm = i >> 12, r = (i >> 6) & 63, c = i & 63;
  int grp = 0, m = mm;
  #pragma unroll
  for (int j = 0; j < 4; ++j){ if (m >= cnts[j] && j < 3){ m -= cnts[j]; grp = j+1; } }
  ws[dsts[grp] + (size_t)m*4096 + (size_t)c*64 + r] =
      ws[srcs[grp] + (size_t)m*4096 + (size_t)r*64 + c];
}

// ---------- edge geometry ----------
__global__ void k_geom(const float* __restrict__ pos, const float* __restrict__ shifts,
                       const int* __restrict__ ei, float* __restrict__ sh, float* __restrict__ ef,
                       float* __restrict__ rl, float* __restrict__ uv){
  int e = blockIdx.x*256 + threadIdx.x;
  if (e >= NE) return;
  int s = ei[e], r = ei[NE + e];
  float vx = pos[s*3+0] - pos[r*3+0] + shifts[(size_t)e*3+0];
  float vy = pos[s*3+1] - pos[r*3+1] + shifts[(size_t)e*3+1];
  float vz = pos[s*3+2] - pos[r*3+2] + shifts[(size_t)e*3+2];
  float L = sqrtf(vx*vx + vy*vy + vz*vz + 1e-12f);
  float inv = 1.f / L;
  float x = vx*inv, y = vy*inv, z = vz*inv;
  float* shp = sh + (size_t)e*9;
  shp[0] = 1.f;     shp[1] = S3*x;    shp[2] = S3*y;   shp[3] = S3*z;
  shp[4] = S15*x*y; shp[5] = S15*y*z; shp[6] = 0.5f*S5*(3.f*z*z - 1.f);
  shp[7] = S15*x*z; shp[8] = 0.5f*S15*(x*x - y*y);
  rl[e] = L;
  uv[(size_t)e*3+0] = x; uv[(size_t)e*3+1] = y; uv[(size_t)e*3+2] = z;
  float ur = L * 0.2f;
  float fc = 0.f;
  if (ur < 1.f){
    float u2 = ur*ur, u4 = u2*u2, u5 = u4*ur;
    fc = 1.f - 21.f*u5 + 35.f*u5*ur - 15.f*u5*u2;
  }
  float invr = 1.f / (L + 1e-9f);
  float* efp = ef + (size_t)e*8;
  #pragma unroll
  for (int b = 0; b < 8; ++b){
    float arg = (float)(b+1) * PI_F * ur;
    efp[b] = KBES * __sinf(arg) * invr * fc;
  }
}

// ---------- node init ----------
__global__ __launch_bounds__(256) void k_init_nodes(
    const float* __restrict__ attrs, const float* __restrict__ Wemb,
    const float* __restrict__ ae, float* __restrict__ nf0, float* __restrict__ e0n){
  int lane = threadIdx.x & 63;
  int n = blockIdx.x*4 + (threadIdx.x >> 6);
  if (n >= NN) return;
  float acc = 0.f;
  #pragma unroll
  for (int z = 0; z < NZ; ++z) acc = fmaf(attrs[(size_t)n*NZ+z], Wemb[z*64+lane], acc);
  size_t base = (size_t)n*256;
  nf0[base + lane] = acc;
  #pragma unroll
  for (int k = 1; k < 4; ++k) nf0[base + (size_t)k*64 + lane] = 0.f;
  if (lane == 0){
    float e = 0.f;
    #pragma unroll
    for (int z = 0; z < NZ; ++z) e = fmaf(attrs[(size_t)n*NZ+z], ae[z], e);
    e0n[n] = e;
  }
}

// ================= CSR construction =================
__global__ void k_csr_count(const int* __restrict__ ei, int* __restrict__ cntr, int* __restrict__ cnts){
  int e = blockIdx.x*256 + threadIdx.x;
  if (e >= NE) return;
  atomicAdd(&cntr[ei[NE+e]], 1);
  atomicAdd(&cnts[ei[e]], 1);
}

__global__ void k_csr_scan(int* __restrict__ cntr, int* __restrict__ cnts,
                           int* __restrict__ offr, int* __restrict__ offs_){
  __shared__ int part[256];
  for (int q = 0; q < 2; ++q){
    int* c   = q ? cnts  : cntr;
    int* off = q ? offs_ : offr;
    const int chunk = (NN + 255)/256;
    int lo = threadIdx.x*chunk, hi = lo+chunk; if (hi > NN) hi = NN; if (lo > NN) lo = NN;
    int s = 0;
    for (int i = lo; i < hi; ++i) s += c[i];
    part[threadIdx.x] = s;
    __syncthreads();
    for (int o = 1; o < 256; o <<= 1){
      int v = (threadIdx.x >= o) ? part[threadIdx.x-o] : 0;
      __syncthreads();
      part[threadIdx.x] += v;
      __syncthreads();
    }
    int run = (threadIdx.x == 0) ? 0 : part[threadIdx.x-1];
    for (int i = lo; i < hi; ++i){
      int ci = c[i];
      off[i] = run; c[i] = run;
      run += ci;
    }
    if (threadIdx.x == 255) off[NN] = run;
    __syncthreads();
  }
}

__global__ void k_csr_fill(const int* __restrict__ ei, int* __restrict__ curr, int* __restrict__ curs,
                           int* __restrict__ listr, int* __restrict__ lists){
  int e = blockIdx.x*256 + threadIdx.x;
  if (e >= NE) return;
  int pr = atomicAdd(&curr[ei[NE+e]], 1); listr[pr] = e;
  int ps = atomicAdd(&curs[ei[e]], 1);    lists[ps] = e;
}

// ================= radial MLP forward (VGPR-resident) =================
__global__ __launch_bounds__(256) void k_radial(
    const float* __restrict__ ef, const float* __restrict__ R1, const float* __restrict__ R2,
    float* __restrict__ wbuf){
  int lane = threadIdx.x & 63;
  int wid = blockIdx.x*4 + (threadIdx.x >> 6);
  int nw  = gridDim.x*4;
  float r1c[8], r2c[64];
  #pragma unroll
  for (int j = 0; j < 8; ++j)  r1c[j] = R1[j*64 + lane];
  #pragma unroll
  for (int j = 0; j < 64; ++j) r2c[j] = R2[j*64 + lane];
  for (int e = wid; e < NE; e += nw){
    float efv = ef[(size_t)e*8 + (lane & 7)];
    float a = 0.f;
    #pragma unroll
    for (int b = 0; b < 8; ++b) a = fmaf(rlane(efv, b), r1c[b], a);
    float sg = 1.f/(1.f + __expf(-a));
    float sl = a*sg;
    float w0 = 0.f, w1 = 0.f, w2 = 0.f, w3 = 0.f;
    #pragma unroll
    for (int j = 0; j < 64; j += 4){
      w0 = fmaf(rlane(sl, j  ), r2c[j  ], w0);
      w1 = fmaf(rlane(sl, j+1), r2c[j+1], w1);
      w2 = fmaf(rlane(sl, j+2), r2c[j+2], w2);
      w3 = fmaf(rlane(sl, j+3), r2c[j+3], w3);
    }
    wbuf[(size_t)e*64 + lane] = (w0+w1) + (w2+w3);
  }
}

// ================= aggregation via receiver CSR (planes 0..3), 2x unrolled =================
__global__ __launch_bounds__(256) void k_agg(
    const float* __restrict__ wbuf, const float* __restrict__ sh, const float* __restrict__ nf,
    const int* __restrict__ ei, const int* __restrict__ offr, const int* __restrict__ listr,
    float* __restrict__ agg){
  int lane = threadIdx.x & 63;
  int wid = blockIdx.x*4 + (threadIdx.x >> 6);
  int nw  = gridDim.x*4;
  for (int n = wid; n < NN; n += nw){
    int lo = offr[n], hi = offr[n+1];
    float acc[4];
    #pragma unroll
    for (int k = 0; k < 4; ++k) acc[k] = 0.f;
    int i = lo;
    for (; i + 2 <= hi; i += 2){
      int e0 = __builtin_amdgcn_readfirstlane(listr[i]);
      int e1 = __builtin_amdgcn_readfirstlane(listr[i+1]);
      int s0 = __builtin_amdgcn_readfirstlane(ei[e0]);
      int s1 = __builtin_amdgcn_readfirstlane(ei[e1]);
      float w0 = wbuf[(size_t)e0*64 + lane];
      float w1 = wbuf[(size_t)e1*64 + lane];
      float h0 = nf[(size_t)s0*256 + lane];
      float h1 = nf[(size_t)s1*256 + lane];
      float wh0 = w0*h0, wh1 = w1*h1;
      const float* sp0 = sh + (size_t)e0*9;
      const float* sp1 = sh + (size_t)e1*9;
      #pragma unroll
      for (int k = 0; k < 4; ++k) acc[k] = fmaf(wh1, sp1[k], fmaf(wh0, sp0[k], acc[k]));
    }
    if (i < hi){
      int e = __builtin_amdgcn_readfirstlane(listr[i]);
      int s = __builtin_amdgcn_readfirstlane(ei[e]);
      float wh = wbuf[(size_t)e*64 + lane] * nf[(size_t)s*256 + lane];
      const float* shp = sh + (size_t)e*9;
      #pragma unroll
      for (int k = 0; k < 4; ++k) acc[k] = fmaf(wh, shp[k], acc[k]);
    }
    size_t ob = (size_t)n*256 + lane;
    #pragma unroll
    for (int k = 0; k < 4; ++k) agg[ob + (size_t)k*64] = acc[k]*(1.f/16.f);
  }
}

// ================= per-l linear, readlane matvec (gridDim.y = 4) =================
__global__ __launch_bounds__(256) void k_lin2(
    const float* __restrict__ in, const float* __restrict__ W3, const float* __restrict__ wp,
    float* __restrict__ out, int flags){
  int k = blockIdx.y;
  int l = (k==0) ? 0 : 1;
  const float* W = W3 + (size_t)l*4096;
  int lane = threadIdx.x & 63;
  float wcol[64];
  #pragma unroll
  for (int j = 0; j < 64; ++j) wcol[j] = W[j*64 + lane];
  float p0 = 0.f, p1 = 0.f, p2 = 0.f;
  if (flags & 2){ p0 = wp[lane*3]; p1 = wp[lane*3+1]; p2 = wp[lane*3+2]; }
  int wid = blockIdx.x*4 + (threadIdx.x >> 6);
  int nw  = gridDim.x*4;
  for (int n = wid; n < NN; n += nw){
    size_t base = (size_t)n*256;
    float x = in[base + (size_t)k*64 + lane];
    if (flags & 2){
      float s0 = in[base + lane];
      x *= fmaf(fmaf(p2, s0, p1), s0, p0);
    }
    float a0 = 0.f, a1 = 0.f, a2 = 0.f, a3 = 0.f;
    #pragma unroll
    for (int j = 0; j < 64; j += 4){
      a0 = fmaf(rlane(x, j  ), wcol[j  ], a0);
      a1 = fmaf(rlane(x, j+1), wcol[j+1], a1);
      a2 = fmaf(rlane(x, j+2), wcol[j+2], a2);
      a3 = fmaf(rlane(x, j+3), wcol[j+3], a3);
    }
    float acc = (a0+a1) + (a2+a3);
    float* o = out + base + (size_t)k*64 + lane;
    if (flags & 1) *o += acc; else *o = acc;
  }
}

// ================= compact 64-wide matvec =================
__global__ __launch_bounds__(256) void k_lin0(
    const float* __restrict__ in, const float* __restrict__ W, float* __restrict__ out){
  int lane = threadIdx.x & 63;
  float wcol[64];
  #pragma unroll
  for (int j = 0; j < 64; ++j) wcol[j] = W[j*64 + lane];
  int wid = blockIdx.x*4 + (threadIdx.x >> 6);
  int nw  = gridDim.x*4;
  for (int n = wid; n < NN; n += nw){
    float x = in[(size_t)n*64 + lane];
    float a0 = 0.f, a1 = 0.f, a2 = 0.f, a3 = 0.f;
    #pragma unroll
    for (int j = 0; j < 64; j += 4){
      a0 = fmaf(rlane(x, j  ), wcol[j  ], a0);
      a1 = fmaf(rlane(x, j+1), wcol[j+1], a1);
      a2 = fmaf(rlane(x, j+2), wcol[j+2], a2);
      a3 = fmaf(rlane(x, j+3), wcol[j+3], a3);
    }
    out[(size_t)n*64 + lane] = (a0+a1) + (a2+a3);
  }
}

// ================= energies & dipoles: per-node staging =================
__global__ __launch_bounds__(256) void k_edip(
    const float* __restrict__ nf, const float* __restrict__ we,
    const float* __restrict__ wd, float* __restrict__ en, float* __restrict__ adp){
  int lane = threadIdx.x & 63;
  int n = blockIdx.x*4 + (threadIdx.x >> 6);
  if (n >= NN) return;
  float v = nf[(size_t)n*256 + lane]*we[lane];
  #pragma unroll
  for (int o = 32; o; o >>= 1) v += __shfl_xor(v, o, 64);
  if (lane == 0) en[n] = v;
  #pragma unroll
  for (int j = 0; j < 3; ++j){
    float dv = nf[(size_t)n*256 + (size_t)(j+1)*64 + lane]*wd[lane];
    #pragma unroll
    for (int o = 32; o; o >>= 1) dv += __shfl_xor(dv, o, 64);
    if (lane == 0) adp[n*3+j] += dv;
  }
}

// ================= segmented final reduction =================
__global__ void k_reduce(const float* __restrict__ e0n, const float* __restrict__ en0,
                         const float* __restrict__ en1, const float* __restrict__ adp,
                         const float* __restrict__ q, const float* __restrict__ pos,
                         const int* __restrict__ batch, float* __restrict__ e0g,
                         float* __restrict__ Etg, float* __restrict__ td){
  int n = blockIdx.x*256 + threadIdx.x;
  int lane = threadIdx.x & 63;
  bool valid = (n < NN);
  int g = valid ? batch[n] : -1;
  float v0=0.f, v1=0.f, v2=0.f, tx=0.f, ty=0.f, tz=0.f;
  if (valid){
    v0 = e0n[n]; v1 = en0[n]; v2 = en1[n];
    float qq = q[n];
    tx = adp[n*3+0] + qq*pos[n*3+0];
    ty = adp[n*3+1] + qq*pos[n*3+1];
    tz = adp[n*3+2] + qq*pos[n*3+2];
  }
  int g0 = __shfl(g, 0, 64), g63 = __shfl(g, 63, 64);
  if (g0 == g63 && g0 >= 0){
    #pragma unroll
    for (int o = 32; o; o >>= 1){
      v0 += __shfl_xor(v0, o, 64); v1 += __shfl_xor(v1, o, 64); v2 += __shfl_xor(v2, o, 64);
      tx += __shfl_xor(tx, o, 64); ty += __shfl_xor(ty, o, 64); tz += __shfl_xor(tz, o, 64);
    }
    if (lane == 0){
      atomicAdd(&e0g[g0], v0); atomicAdd(&Etg[g0], v1); atomicAdd(&Etg[16+g0], v2);
      atomicAdd(&td[g0*3+0], tx); atomicAdd(&td[g0*3+1], ty); atomicAdd(&td[g0*3+2], tz);
    }
  } else if (valid){
    atomicAdd(&e0g[g], v0); atomicAdd(&Etg[g], v1); atomicAdd(&Etg[16+g], v2);
    atomicAdd(&td[g*3+0], tx); atomicAdd(&td[g*3+1], ty); atomicAdd(&td[g*3+2], tz);
  }
}

// ================= backward head =================
__global__ void k_bwd_head(const float* __restrict__ WPRODT1, const float* __restrict__ WSCT1,
                           const float* __restrict__ we1, const float* __restrict__ we0,
                           float* __restrict__ gvp, float* __restrict__ gnfc){
  int d = threadIdx.x;
  float a = 0.f, b = 0.f;
  #pragma unroll
  for (int c = 0; c < 64; ++c){
    float w = we1[c];
    a = fmaf(w, WPRODT1[c*64+d], a);
    b = fmaf(w, WSCT1[c*64+d], b);
  }
  gvp[d] = a;
  gnfc[d] = b + we0[d];
}

// ================= poly backward (k=0 plane) =================
__global__ __launch_bounds__(256) void k_polybwd0(
    const float* __restrict__ gmp, int per_node, const float* __restrict__ msgbase,
    const float* __restrict__ wp, float* __restrict__ out){
  int lane = threadIdx.x & 63;
  int n = blockIdx.x*4 + (threadIdx.x >> 6);
  if (n >= NN) return;
  float g = per_node ? gmp[(size_t)n*64 + lane] : gmp[lane];
  float s0 = msgbase[(size_t)n*256 + lane];
  float p0 = wp[lane*3], p1 = wp[lane*3+1], p2 = wp[lane*3+2];
  float poly = fmaf(fmaf(p2, s0, p1), s0, p0);
  float dp   = fmaf(2.f*p2, s0, p1);
  out[(size_t)n*64 + lane] = g*fmaf(s0, dp, poly);
}

// ================= edge-parallel fused backward (Q matvec only) =================
__global__ __launch_bounds__(256) void k_bwdE(
    const float* __restrict__ ef, const float* __restrict__ rl, const float* __restrict__ uv,
    const float* __restrict__ nf, const float* __restrict__ gagg0, const int* __restrict__ ei,
    const float* __restrict__ R1, const float* __restrict__ R2,
    float* __restrict__ gvec, int accum){
  int lane = threadIdx.x & 63;
  int wid = blockIdx.x*4 + (threadIdx.x >> 6);
  int nw  = gridDim.x*4;
  float r1c[8], r2c[64];
  #pragma unroll
  for (int j = 0; j < 8; ++j)  r1c[j] = R1[j*64 + lane];
  #pragma unroll
  for (int j = 0; j < 64; ++j) r2c[j] = R2[j*64 + lane];
  for (int e = wid; e < NE; e += nw){
    int s = __builtin_amdgcn_readfirstlane(ei[e]);
    int r = __builtin_amdgcn_readfirstlane(ei[NE+e]);
    float efv = ef[(size_t)e*8 + (lane & 7)];
    float L   = rl[e];
    float h   = nf[(size_t)s*256 + lane];
    float gm  = gagg0[(size_t)r*64 + lane]*(1.f/16.f);
    float a = 0.f;
    #pragma unroll
    for (int b = 0; b < 8; ++b) a = fmaf(rlane(efv, b), r1c[b], a);
    float sg = 1.f/(1.f + __expf(-a));
    float dd[8];
    edge_defdr(L, dd);
    float t = 0.f;
    #pragma unroll
    for (int b = 0; b < 8; ++b) t = fmaf(r1c[b], dd[b], t);
    float q = sg*fmaf(a, 1.f - sg, 1.f)*t;   // silu'(a_j)*t_j  (lane = j)
    float Q0=0.f, Q1=0.f, Q2=0.f, Q3=0.f;
    #pragma unroll
    for (int j = 0; j < 64; j += 4){
      Q0 = fmaf(rlane(q, j  ), r2c[j  ], Q0);
      Q1 = fmaf(rlane(q, j+1), r2c[j+1], Q1);
      Q2 = fmaf(rlane(q, j+2), r2c[j+2], Q2);
      Q3 = fmaf(rlane(q, j+3), r2c[j+3], Q3);
    }
    float rr = ((Q0+Q1) + (Q2+Q3))*h*gm;     // lane = d
    #pragma unroll
    for (int o = 32; o; o >>= 1) rr += __shfl_xor(rr, o, 64);
    if (lane < 3){
      float comp = rr*uv[(size_t)e*3 + lane];
      size_t gi = (size_t)e*3 + lane;
      if (accum) gvec[gi] += comp; else gvec[gi] = comp;
    }
  }
}

// ================= gh gather via sender CSR (w * gagg[receiver]), 2x unrolled =================
__global__ __launch_bounds__(256) void k_ghgather0(
    const float* __restrict__ wbuf, const float* __restrict__ gagg0, const int* __restrict__ ei,
    const int* __restrict__ offs_, const int* __restrict__ lists,
    const float* __restrict__ gnfc, float* __restrict__ out){
  int lane = threadIdx.x & 63;
  int wid = blockIdx.x*4 + (threadIdx.x >> 6);
  int nw  = gridDim.x*4;
  for (int n = wid; n < NN; n += nw){
    int lo = offs_[n], hi = offs_[n+1];
    float acc = 0.f;
    int i = lo;
    for (; i + 2 <= hi; i += 2){
      int e0 = __builtin_amdgcn_readfirstlane(lists[i]);
      int e1 = __builtin_amdgcn_readfirstlane(lists[i+1]);
      int r0 = __builtin_amdgcn_readfirstlane(ei[NE+e0]);
      int r1 = __builtin_amdgcn_readfirstlane(ei[NE+e1]);
      float w0 = wbuf[(size_t)e0*64 + lane];
      float w1 = wbuf[(size_t)e1*64 + lane];
      float g0 = gagg0[(size_t)r0*64 + lane];
      float g1 = gagg0[(size_t)r1*64 + lane];
      acc = fmaf(w1, g1, fmaf(w0, g0, acc));
    }
    if (i < hi){
      int e = __builtin_amdgcn_readfirstlane(lists[i]);
      int r = __builtin_amdgcn_readfirstlane(ei[NE+e]);
      acc = fmaf(wbuf[(size_t)e*64 + lane], gagg0[(size_t)r*64 + lane], acc);
    }
    out[(size_t)n*64 + lane] = gnfc[lane] + acc*(1.f/16.f);
  }
}

// ---------- CSR-based force assembly ----------
__global__ void k_gpos(const float* __restrict__ gvec,
                       const int* __restrict__ offr, const int* __restrict__ listr,
                       const int* __restrict__ offs_, const int* __restrict__ lists,
                       float* __restrict__ gpos){
  int n = blockIdx.x*256 + threadIdx.x;
  if (n >= NN) return;
  float ax = 0.f, ay = 0.f, az = 0.f;
  for (int i = offs_[n]; i < offs_[n+1]; ++i){
    int e = lists[i];
    ax += gvec[(size_t)e*3]; ay += gvec[(size_t)e*3+1]; az += gvec[(size_t)e*3+2];
  }
  for (int i = offr[n]; i < offr[n+1]; ++i){
    int e = listr[i];
    ax -= gvec[(size_t)e*3]; ay -= gvec[(size_t)e*3+1]; az -= gvec[(size_t)e*3+2];
  }
  gpos[n*3+0] = ax; gpos[n*3+1] = ay; gpos[n*3+2] = az;
}

__global__ void k_writeout(const float* __restrict__ e0g, const float* __restrict__ Etg,
                           const float* __restrict__ td, const float* __restrict__ adp,
                           const float* __restrict__ gpos, void* __restrict__ outv,
                           const int* __restrict__ flag){
  int i = blockIdx.x*256 + threadIdx.x;
  const int total = NG + NG*3 + NN*3 + NG*3 + NN*3; // 60112
  if (i >= total) return;
  float v;
  if (i < 16){
    v = e0g[i] + Etg[i] + Etg[16+i];
  } else if (i < 64){
    int j = i - 16; int g = j/3, t = j - g*3;
    v = (t == 0) ? e0g[g] : Etg[(t-1)*16 + g];
  } else if (i < 64 + NN*3){
    v = -gpos[i-64];
  } else if (i < 64 + NN*3 + 48){
    v = td[i - (64 + NN*3)];
  } else {
    v = adp[i - (64 + NN*3 + 48)];
  }
  if (flag[0]) ((__hip_bfloat16*)outv)[i] = __float2bfloat16(v);
  else         ((float*)outv)[i] = v;
}

extern "C" void kernel_launch(void* const* d_in, const int* in_sizes, int n_in,
                              void* d_out, int out_size, void* d_ws, size_t ws_size,
                              hipStream_t stream) {
  if (ws_size < WS_FLOATS*sizeof(float)) return; // ~123 MB
  const int* ei    = (const int*)d_in[14];
  const int* batch = (const int*)d_in[15];
  float* ws = (float*)d_ws;
  int* flag = (int*)(ws + O_FLAG);

  hipMemsetAsync(ws + OFF_ACC, 0, ACC_FLOATS*sizeof(float), stream);
  k_detect<<<1, 256, 0, stream>>>((const unsigned*)d_in[1], flag);
  k_load_all<<<(LD_TOTAL+255)/256, 256, 0, stream>>>(
      d_in[0], d_in[1], d_in[2], d_in[3], d_in[4], d_in[5], d_in[6], d_in[7],
      d_in[8], d_in[9], d_in[10], d_in[11], d_in[12], d_in[13], ws, flag);
  k_transpose_all<<<320, 256, 0, stream>>>(ws);

  k_geom<<<(NE+255)/256, 256, 0, stream>>>(ws+OFF_PIN, ws+OFF_SHF, ei,
                                           ws+OFF_SH, ws+OFF_EF, ws+OFF_RL, ws+OFF_UV);
  k_init_nodes<<<(NN+3)/4, 256, 0, stream>>>(ws+OFF_ATT, ws+O_WEMB, ws+O_AE, ws+OFF_NF0, ws+O_E0N);

  float* WBUF = ws + O_WBUF;
  int* offr  = (int*)(ws + O_OFFR);
  int* offs_ = (int*)(ws + O_OFFS);
  int* curr  = (int*)(ws + O_CURR);
  int* curs  = (int*)(ws + O_CURS);
  int* listr = (int*)(ws + O_LISTR);
  int* lists = (int*)(ws + O_LISTS);
  hipMemsetAsync(curr, 0, 2*NN*sizeof(int), stream);
  k_csr_count<<<(NE+255)/256, 256, 0, stream>>>(ei, curr, curs);
  k_csr_scan<<<1, 256, 0, stream>>>(curr, curs, offr, offs_);
  k_csr_fill<<<(NE+255)/256, 256, 0, stream>>>(ei, curr, curs, listr, lists);

  const size_t NF[3]  = {OFF_NF0, OFF_NF1, OFF_NF2};
  const size_t MSG[2] = {OFF_MSG0, OFF_MSG1};
  dim3 ling(256, 4);
  float* GA0 = ws + OFF_AGG;                 // compact NN*64 (AGG free after forward)
  float* GB0 = ws + OFF_AGG + (size_t)NN*64;

  // ---------- forward ----------
  for (int t = 0; t < NT; ++t){
    k_radial<<<2048, 256, 0, stream>>>(ws+OFF_EF, ws+O_R1 + (size_t)t*512, ws+O_R2 + (size_t)t*4096, WBUF);
    k_agg<<<1024, 256, 0, stream>>>(WBUF, ws+OFF_SH, ws+NF[t], ei, offr, listr, ws+OFF_AGG);
    k_lin2<<<ling, 256, 0, stream>>>(ws+OFF_AGG, ws+O_WMIX + (size_t)t*12288, nullptr, ws+MSG[t], 0);
    k_lin2<<<ling, 256, 0, stream>>>(ws+NF[t],   ws+O_WSC  + (size_t)t*12288, nullptr, ws+NF[t+1], 0);
    k_lin2<<<ling, 256, 0, stream>>>(ws+MSG[t],  ws+O_WPROD+ (size_t)t*12288, ws+O_WPOLY + (size_t)t*192,
                                     ws+NF[t+1], 3);
    k_edip<<<(NN+3)/4, 256, 0, stream>>>(ws+NF[t+1], ws+O_WE + (size_t)t*64, ws+O_WD + (size_t)t*64,
                                         ws + (t ? O_EN1 : O_EN0), ws+O_ADP);
  }

  // ---------- backward (k=0 plane only) ----------
  k_bwd_head<<<1, 64, 0, stream>>>(ws+O_WPRODT+12288, ws+O_WSCT+12288, ws+O_WE+64, ws+O_WE,
                                   ws+O_GVP, ws+O_GNFC);
  { // t = 1 (WBUF holds w1 from forward; gh handled by k_ghgather0 directly)
    k_polybwd0<<<(NN+3)/4, 256, 0, stream>>>(ws+O_GVP, 0, ws+MSG[1], ws+O_WPOLY+192, GB0);
    k_lin0<<<1024, 256, 0, stream>>>(GB0, ws+O_WMIXT+12288, GA0);   // gagg0 for t=1
    k_bwdE<<<2048, 256, 0, stream>>>(ws+OFF_EF, ws+OFF_RL, ws+OFF_UV,
                                     ws+NF[1], GA0, ei,
                                     ws+O_R1+512, ws+O_R2+4096,
                                     ws+O_GVEC, 0);
    k_ghgather0<<<1024, 256, 0, stream>>>(WBUF, GA0, ei, offs_, lists, ws+O_GNFC, GB0);
  }
  { // t = 0
    k_lin0<<<1024, 256, 0, stream>>>(GB0, ws+O_WPRODT, GA0);        // gmp0 per node
    k_polybwd0<<<(NN+3)/4, 256, 0, stream>>>(GA0, 1, ws+MSG[0], ws+O_WPOLY, GB0);
    k_lin0<<<1024, 256, 0, stream>>>(GB0, ws+O_WMIXT, GA0);         // gagg0 for t=0
    k_bwdE<<<2048, 256, 0, stream>>>(ws+OFF_EF, ws+OFF_RL, ws+OFF_UV,
                                     ws+NF[0], GA0, ei,
                                     ws+O_R1, ws+O_R2,
                                     ws+O_GVEC, 1);
  }

  // reduce BEFORE gpos (per-node energy staging aliases the gpos slots)
  k_reduce<<<(NN+255)/256, 256, 0, stream>>>(ws+O_E0N, ws+O_EN0, ws+O_EN1, ws+O_ADP,
                                             ws+OFF_CHG, ws+OFF_PIN, batch,
                                             ws+O_E0G, ws+O_ETG, ws+O_TD);
  k_gpos<<<(NN+255)/256, 256, 0, stream>>>(ws+O_GVEC, offr, listr, offs_, lists, ws+O_GPOS);
  k_writeout<<<(60112+255)/256, 256, 0, stream>>>(ws+O_E0G, ws+O_ETG, ws+O_TD, ws+O_ADP, ws+O_GPOS, d_out, flag);
}

// Round 10
// 554.398 us; speedup vs baseline: 2.0130x; 1.3715x over previous
//
#include <hip/hip_runtime.h>
#include <hip/hip_bf16.h>

#define NN 10000
#define NE 160000
#define NZ 10
#define NC 64
#define NBES 8
#define NG 16
#define NT 2
#define NB 2048
#define NB1 2049

static constexpr float PI_F  = 3.14159265358979323846f;
static constexpr float KBES  = 0.63245553203367587f;  // sqrt(2/5)
static constexpr float S3    = 1.73205080756887729f;
static constexpr float S5    = 2.23606797749978969f;
static constexpr float S15   = 3.87298334620741688f;

// ---- workspace layout (float offsets); node tensors stride 256 (planes 0..3) ----
static constexpr size_t OFF_RL   = 0;
static constexpr size_t OFF_UV   = OFF_RL  + (size_t)NE;
static constexpr size_t OFF_PIN  = OFF_UV  + (size_t)NE*3;
static constexpr size_t OFF_ATT  = OFF_PIN + (size_t)NN*3;
static constexpr size_t OFF_CHG  = OFF_ATT + (size_t)NN*NZ;
static constexpr size_t OFF_SHF  = OFF_CHG + (size_t)NN;
static constexpr size_t NFS      = (size_t)NN*256;
static constexpr size_t OFF_NF0  = OFF_SHF + (size_t)NE*3;
static constexpr size_t OFF_NF1  = OFF_NF0 + NFS;
static constexpr size_t OFF_NF2  = OFF_NF1 + NFS;
static constexpr size_t OFF_MSG0 = OFF_NF2 + NFS;
static constexpr size_t OFF_MSG1 = OFF_MSG0+ NFS;
static constexpr size_t OFF_AGG  = OFF_MSG1+ NFS;    // fwd agg; bwd compact GA0/GB0
static constexpr size_t OFF_W    = OFF_AGG + NFS;
static constexpr size_t O_WEMB   = OFF_W;
static constexpr size_t O_AE     = O_WEMB + 640;
static constexpr size_t O_R1     = O_AE   + 16;
static constexpr size_t O_R2     = O_R1   + 1024;
static constexpr size_t O_WMIX   = O_R2   + 8192;
static constexpr size_t O_WMIXT  = O_WMIX + 24576;
static constexpr size_t O_WSC    = O_WMIXT+ 24576;
static constexpr size_t O_WSCT   = O_WSC  + 24576;
static constexpr size_t O_WPROD  = O_WSCT + 24576;
static constexpr size_t O_WPRODT = O_WPROD+ 24576;
static constexpr size_t O_WPOLY  = O_WPRODT+24576;
static constexpr size_t O_WE     = O_WPOLY+ 384;
static constexpr size_t O_WD     = O_WE   + 128;
static constexpr size_t OFF_ACC  = O_WD   + 128;
static constexpr size_t O_E0G    = OFF_ACC;
static constexpr size_t O_ETG    = O_E0G + 16;
static constexpr size_t O_TD     = O_ETG + 32;
static constexpr size_t O_ADP    = O_TD  + 48;
static constexpr size_t O_GPOS   = O_ADP + (size_t)NN*3;
// per-node energy staging ALIASES gpos (k_reduce runs before k_gpos)
static constexpr size_t O_EN0    = O_GPOS;
static constexpr size_t O_EN1    = O_GPOS + NN;
static constexpr size_t O_E0N    = O_GPOS + 2*NN;
static constexpr size_t O_GVEC   = O_GPOS+ (size_t)NN*3;     // per-edge dE/dvec (NOT zeroed)
static constexpr size_t ACC_FLOATS = O_GVEC - OFF_ACC;
static constexpr size_t O_FLAG   = O_GVEC + (size_t)NE*3;
static constexpr size_t O_GVP    = O_FLAG + 4;
static constexpr size_t O_GNFC   = O_GVP + 64;
static constexpr size_t O_TW     = O_GNFC + 64;              // 2 layers x NB1 x 64
static constexpr size_t O_TQ     = O_TW + (size_t)2*NB1*64;
static constexpr size_t O_OFFR   = O_TQ + (size_t)2*NB1*64;  // ints from here
static constexpr size_t O_OFFS   = O_OFFR + (NN+1);
static constexpr size_t O_CURR   = O_OFFS + (NN+1);
static constexpr size_t O_CURS   = O_CURR + NN;
static constexpr size_t O_LISTR  = O_CURS + NN;
static constexpr size_t O_LISTS  = O_LISTR + (size_t)NE;
static constexpr size_t WS_FLOATS= O_LISTS + (size_t)NE;     // ~78 MB

__device__ __forceinline__ float rlane(float v, int l){
  return __int_as_float(__builtin_amdgcn_readlane(__float_as_int(v), l));
}

// ---------- dtype detection ----------
__global__ void k_detect(const unsigned* __restrict__ raw, int* __restrict__ flag){
  __shared__ int found;
  if (threadIdx.x == 0) found = 0;
  __syncthreads();
  for (int i = threadIdx.x; i < 4096; i += 256){
    unsigned w = raw[i];
    if (w == 0x00003F80u || w == 0x3F803F80u) found = 1;
  }
  __syncthreads();
  if (threadIdx.x == 0) flag[0] = found;
}

// ---------- fused loader ----------
static constexpr int LD_CNT[14] = {NN*3, NN*NZ, NN, NE*3, NZ*64, NZ, NT*NBES*64, NT*64*64,
                                   NT*3*64*64, NT*3*64*64, NT*64*3, NT*3*64*64, NT*64, NT*64};
static constexpr int LD_TOTAL = NN*3 + NN*NZ + NN + NE*3 + NZ*64 + NZ + NT*NBES*64 + NT*64*64
                              + 3*(NT*3*64*64) + NT*64*3 + 4*(NT*64) - NT*64*2;
__global__ __launch_bounds__(256) void k_load_all(
    const void* s0, const void* s1, const void* s2, const void* s3, const void* s4,
    const void* s5, const void* s6, const void* s7, const void* s8, const void* s9,
    const void* s10, const void* s11, const void* s12, const void* s13,
    float* __restrict__ ws, const int* __restrict__ flag){
  const void* srcs[14] = {s0,s1,s2,s3,s4,s5,s6,s7,s8,s9,s10,s11,s12,s13};
  const size_t dsts[14] = {OFF_PIN, OFF_ATT, OFF_CHG, OFF_SHF, O_WEMB, O_AE, O_R1, O_R2,
                           O_WMIX, O_WSC, O_WPOLY, O_WPROD, O_WE, O_WD};
  int i = blockIdx.x*256 + threadIdx.x;
  int seg = -1, off = i;
  #pragma unroll
  for (int j = 0; j < 14; ++j){
    if (seg < 0){
      if (off < LD_CNT[j]) seg = j;
      else off -= LD_CNT[j];
    }
  }
  if (seg < 0) return;
  float v = flag[0] ? __bfloat162float(((const __hip_bfloat16*)srcs[seg])[off])
                    : ((const float*)srcs[seg])[off];
  ws[dsts[seg] + off] = v;
}

// ---------- fused transposes (WMIX, WSC, WPROD = 18 matrices) ----------
__global__ void k_transpose_all(float* __restrict__ ws){
  const size_t srcs[3] = {O_WMIX, O_WSC, O_WPROD};
  const size_t dsts[3] = {O_WMIXT, O_WSCT, O_WPRODT};
  int i = blockIdx.x*256 + threadIdx.x;
  if (i >= 18*4096) return;
  int mm = i >> 12, r = (i >> 6) & 63, c = i & 63;
  int grp = mm / 6, m = mm % 6;
  ws[dsts[grp] + (size_t)m*4096 + (size_t)c*64 + r] =
      ws[srcs[grp] + (size_t)m*4096 + (size_t)r*64 + c];
}

// ---------- edge geometry: only L and unit vector ----------
__global__ void k_geom(const float* __restrict__ pos, const float* __restrict__ shifts,
                       const int* __restrict__ ei, float* __restrict__ rl, float* __restrict__ uv){
  int e = blockIdx.x*256 + threadIdx.x;
  if (e >= NE) return;
  int s = ei[e], r = ei[NE + e];
  float vx = pos[s*3+0] - pos[r*3+0] + shifts[(size_t)e*3+0];
  float vy = pos[s*3+1] - pos[r*3+1] + shifts[(size_t)e*3+1];
  float vz = pos[s*3+2] - pos[r*3+2] + shifts[(size_t)e*3+2];
  float L = sqrtf(vx*vx + vy*vy + vz*vz + 1e-12f);
  float inv = 1.f / L;
  rl[e] = L;
  uv[(size_t)e*3+0] = vx*inv; uv[(size_t)e*3+1] = vy*inv; uv[(size_t)e*3+2] = vz*inv;
}

// ---------- radial tables: TW[t][node][d] = w(L), TQ[t][node][d] = Q(L) ----------
__global__ __launch_bounds__(256) void k_tables(
    const float* __restrict__ R1all, const float* __restrict__ R2all,
    float* __restrict__ TW, float* __restrict__ TQ){
  int lane = threadIdx.x & 63;
  int task = blockIdx.x*4 + (threadIdx.x >> 6);
  if (task >= 2*NB1) return;
  int t = task / NB1, node = task % NB1;
  const float* R1 = R1all + (size_t)t*512;
  const float* R2 = R2all + (size_t)t*4096;
  float r1c[8];
  #pragma unroll
  for (int j = 0; j < 8; ++j) r1c[j] = R1[j*64 + lane];
  float L = fmaxf((float)node * (5.f/NB), 1e-6f);
  float ur = L*0.2f;
  float ef[8], dd[8];
  if (ur < 1.f){
    float u2=ur*ur, u4=u2*u2, u5=u4*ur;
    float fc = 1.f - 21.f*u5 + 35.f*u5*ur - 15.f*u5*u2;
    float omu = 1.f - ur;
    float dfc = -105.f*u4*omu*omu;
    float invr = 1.f/(L + 1e-9f);
    #pragma unroll
    for (int b = 0; b < 8; ++b){
      float nb = (float)(b+1);
      float arg = nb*PI_F*ur;
      float sn = __sinf(arg), cs = __cosf(arg);
      float bes = KBES*sn*invr;
      float dbes = KBES*(nb*PI_F*0.2f)*cs*invr - bes*invr;
      ef[b] = bes*fc;
      dd[b] = dbes*fc + bes*dfc*0.2f;
    }
  } else {
    #pragma unroll
    for (int b = 0; b < 8; ++b){ ef[b] = 0.f; dd[b] = 0.f; }
  }
  float a = 0.f, tt = 0.f;
  #pragma unroll
  for (int b = 0; b < 8; ++b){ a = fmaf(ef[b], r1c[b], a); tt = fmaf(r1c[b], dd[b], tt); }
  float sg = 1.f/(1.f + __expf(-a));
  float sl = a*sg;                          // silu(a_j), j = lane
  float q  = sg*fmaf(a, 1.f - sg, 1.f)*tt;  // silu'(a_j)*t_j
  float r2c[64];
  #pragma unroll
  for (int j = 0; j < 64; ++j) r2c[j] = R2[j*64 + lane];
  float W0=0.f, W1=0.f, Q0=0.f, Q1=0.f;
  #pragma unroll
  for (int j = 0; j < 64; j += 2){
    W0 = fmaf(rlane(sl, j  ), r2c[j  ], W0);
    W1 = fmaf(rlane(sl, j+1), r2c[j+1], W1);
    Q0 = fmaf(rlane(q,  j  ), r2c[j  ], Q0);
    Q1 = fmaf(rlane(q,  j+1), r2c[j+1], Q1);
  }
  size_t idx = ((size_t)t*NB1 + node)*64 + lane;
  TW[idx] = W0+W1;
  TQ[idx] = Q0+Q1;
}

// ---------- node init ----------
__global__ __launch_bounds__(256) void k_init_nodes(
    const float* __restrict__ attrs, const float* __restrict__ Wemb,
    const float* __restrict__ ae, float* __restrict__ nf0, float* __restrict__ e0n){
  int lane = threadIdx.x & 63;
  int n = blockIdx.x*4 + (threadIdx.x >> 6);
  if (n >= NN) return;
  float acc = 0.f;
  #pragma unroll
  for (int z = 0; z < NZ; ++z) acc = fmaf(attrs[(size_t)n*NZ+z], Wemb[z*64+lane], acc);
  size_t base = (size_t)n*256;
  nf0[base + lane] = acc;
  #pragma unroll
  for (int k = 1; k < 4; ++k) nf0[base + (size_t)k*64 + lane] = 0.f;
  if (lane == 0){
    float e = 0.f;
    #pragma unroll
    for (int z = 0; z < NZ; ++z) e = fmaf(attrs[(size_t)n*NZ+z], ae[z], e);
    e0n[n] = e;
  }
}

// ================= CSR construction =================
__global__ void k_csr_count(const int* __restrict__ ei, int* __restrict__ cntr, int* __restrict__ cnts){
  int e = blockIdx.x*256 + threadIdx.x;
  if (e >= NE) return;
  atomicAdd(&cntr[ei[NE+e]], 1);
  atomicAdd(&cnts[ei[e]], 1);
}

__global__ void k_csr_scan(int* __restrict__ cntr, int* __restrict__ cnts,
                           int* __restrict__ offr, int* __restrict__ offs_){
  __shared__ int part[256];
  for (int q = 0; q < 2; ++q){
    int* c   = q ? cnts  : cntr;
    int* off = q ? offs_ : offr;
    const int chunk = (NN + 255)/256;
    int lo = threadIdx.x*chunk, hi = lo+chunk; if (hi > NN) hi = NN; if (lo > NN) lo = NN;
    int s = 0;
    for (int i = lo; i < hi; ++i) s += c[i];
    part[threadIdx.x] = s;
    __syncthreads();
    for (int o = 1; o < 256; o <<= 1){
      int v = (threadIdx.x >= o) ? part[threadIdx.x-o] : 0;
      __syncthreads();
      part[threadIdx.x] += v;
      __syncthreads();
    }
    int run = (threadIdx.x == 0) ? 0 : part[threadIdx.x-1];
    for (int i = lo; i < hi; ++i){
      int ci = c[i];
      off[i] = run; c[i] = run;
      run += ci;
    }
    if (threadIdx.x == 255) off[NN] = run;
    __syncthreads();
  }
}

__global__ void k_csr_fill(const int* __restrict__ ei, int* __restrict__ curr, int* __restrict__ curs,
                           int* __restrict__ listr, int* __restrict__ lists){
  int e = blockIdx.x*256 + threadIdx.x;
  if (e >= NE) return;
  int pr = atomicAdd(&curr[ei[NE+e]], 1); listr[pr] = e;
  int ps = atomicAdd(&curs[ei[e]], 1);    lists[ps] = e;
}

// ================= aggregation via receiver CSR; w from table; L>=5 skip =================
__global__ __launch_bounds__(256) void k_agg(
    const float* __restrict__ TW, const float* __restrict__ rl, const float* __restrict__ uv,
    const float* __restrict__ nf, const int* __restrict__ ei,
    const int* __restrict__ offr, const int* __restrict__ listr,
    float* __restrict__ agg){
  int lane = threadIdx.x & 63;
  int wid = blockIdx.x*4 + (threadIdx.x >> 6);
  int nw  = gridDim.x*4;
  for (int n = wid; n < NN; n += nw){
    int lo = offr[n], hi = offr[n+1];
    float acc0=0.f, acc1=0.f, acc2=0.f, acc3=0.f;
    for (int i = lo; i < hi; ++i){
      int e = __builtin_amdgcn_readfirstlane(listr[i]);
      float L = rl[e];
      if (L >= 5.f) continue;
      int s = __builtin_amdgcn_readfirstlane(ei[e]);
      float pos = L*(NB/5.f);
      int bi = (int)pos;
      float f = pos - (float)bi;
      const float* T = TW + (size_t)bi*64 + lane;
      float w = fmaf(T[64]-T[0], f, T[0]);
      float wh = w * nf[(size_t)s*256 + lane];
      float ux = uv[(size_t)e*3], uy = uv[(size_t)e*3+1], uz = uv[(size_t)e*3+2];
      acc0 += wh;
      acc1 = fmaf(wh, S3*ux, acc1);
      acc2 = fmaf(wh, S3*uy, acc2);
      acc3 = fmaf(wh, S3*uz, acc3);
    }
    size_t ob = (size_t)n*256 + lane;
    agg[ob]       = acc0*(1.f/16.f);
    agg[ob+64]    = acc1*(1.f/16.f);
    agg[ob+128]   = acc2*(1.f/16.f);
    agg[ob+192]   = acc3*(1.f/16.f);
  }
}

// ================= per-l linear (mix), readlane matvec (gridDim.y = 4) =================
__global__ __launch_bounds__(256) void k_lin2(
    const float* __restrict__ in, const float* __restrict__ W3, float* __restrict__ out){
  int k = blockIdx.y;
  int l = (k==0) ? 0 : 1;
  const float* W = W3 + (size_t)l*4096;
  int lane = threadIdx.x & 63;
  float wcol[64];
  #pragma unroll
  for (int j = 0; j < 64; ++j) wcol[j] = W[j*64 + lane];
  int wid = blockIdx.x*4 + (threadIdx.x >> 6);
  int nw  = gridDim.x*4;
  for (int n = wid; n < NN; n += nw){
    size_t base = (size_t)n*256;
    float x = in[base + (size_t)k*64 + lane];
    float a0 = 0.f, a1 = 0.f, a2 = 0.f, a3 = 0.f;
    #pragma unroll
    for (int j = 0; j < 64; j += 4){
      a0 = fmaf(rlane(x, j  ), wcol[j  ], a0);
      a1 = fmaf(rlane(x, j+1), wcol[j+1], a1);
      a2 = fmaf(rlane(x, j+2), wcol[j+2], a2);
      a3 = fmaf(rlane(x, j+3), wcol[j+3], a3);
    }
    out[base + (size_t)k*64 + lane] = (a0+a1) + (a2+a3);
  }
}

// ================= fused layer tail: sc-lin + poly-gated prod-lin + energy/dipole =================
// Block = 4 waves; wave w owns plane w. Writes nf_out plane, en (wave0), adp (waves 1-3).
__global__ __launch_bounds__(256) void k_tail(
    const float* __restrict__ nf_in, const float* __restrict__ msg,
    const float* __restrict__ Wsc, const float* __restrict__ Wprod, const float* __restrict__ wp,
    const float* __restrict__ we, const float* __restrict__ wd,
    float* __restrict__ nf_out, float* __restrict__ en, float* __restrict__ adp){
  int lane = threadIdx.x & 63;
  int k = threadIdx.x >> 6;
  int l = (k==0) ? 0 : 1;
  float wcs[64], wcp[64];
  #pragma unroll
  for (int j = 0; j < 64; ++j){
    wcs[j] = Wsc[(size_t)l*4096 + j*64 + lane];
    wcp[j] = Wprod[(size_t)l*4096 + j*64 + lane];
  }
  float p0 = wp[lane*3], p1 = wp[lane*3+1], p2 = wp[lane*3+2];
  float rw = (k==0) ? we[lane] : wd[lane];
  for (int n = blockIdx.x; n < NN; n += gridDim.x){
    size_t base = (size_t)n*256;
    float s0 = msg[base + lane];
    float xm = (k==0) ? s0 : msg[base + (size_t)k*64 + lane];
    float xg = xm * fmaf(fmaf(p2, s0, p1), s0, p0);
    float xs = nf_in[base + (size_t)k*64 + lane];
    float a0=0.f, a1=0.f, b0=0.f, b1=0.f;
    #pragma unroll
    for (int j = 0; j < 64; j += 2){
      a0 = fmaf(rlane(xs, j  ), wcs[j  ], a0);
      a1 = fmaf(rlane(xs, j+1), wcs[j+1], a1);
      b0 = fmaf(rlane(xg, j  ), wcp[j  ], b0);
      b1 = fmaf(rlane(xg, j+1), wcp[j+1], b1);
    }
    float out = (a0+a1) + (b0+b1);
    nf_out[base + (size_t)k*64 + lane] = out;
    float red = out * rw;
    #pragma unroll
    for (int o = 32; o; o >>= 1) red += __shfl_xor(red, o, 64);
    if (lane == 0){
      if (k == 0) en[n] = red;
      else        adp[n*3 + (k-1)] += red;
    }
  }
}

// ================= segmented final reduction =================
__global__ void k_reduce(const float* __restrict__ e0n, const float* __restrict__ en0,
                         const float* __restrict__ en1, const float* __restrict__ adp,
                         const float* __restrict__ q, const float* __restrict__ pos,
                         const int* __restrict__ batch, float* __restrict__ e0g,
                         float* __restrict__ Etg, float* __restrict__ td){
  int n = blockIdx.x*256 + threadIdx.x;
  int lane = threadIdx.x & 63;
  bool valid = (n < NN);
  int g = valid ? batch[n] : -1;
  float v0=0.f, v1=0.f, v2=0.f, tx=0.f, ty=0.f, tz=0.f;
  if (valid){
    v0 = e0n[n]; v1 = en0[n]; v2 = en1[n];
    float qq = q[n];
    tx = adp[n*3+0] + qq*pos[n*3+0];
    ty = adp[n*3+1] + qq*pos[n*3+1];
    tz = adp[n*3+2] + qq*pos[n*3+2];
  }
  int g0 = __shfl(g, 0, 64), g63 = __shfl(g, 63, 64);
  if (g0 == g63 && g0 >= 0){
    #pragma unroll
    for (int o = 32; o; o >>= 1){
      v0 += __shfl_xor(v0, o, 64); v1 += __shfl_xor(v1, o, 64); v2 += __shfl_xor(v2, o, 64);
      tx += __shfl_xor(tx, o, 64); ty += __shfl_xor(ty, o, 64); tz += __shfl_xor(tz, o, 64);
    }
    if (lane == 0){
      atomicAdd(&e0g[g0], v0); atomicAdd(&Etg[g0], v1); atomicAdd(&Etg[16+g0], v2);
      atomicAdd(&td[g0*3+0], tx); atomicAdd(&td[g0*3+1], ty); atomicAdd(&td[g0*3+2], tz);
    }
  } else if (valid){
    atomicAdd(&e0g[g], v0); atomicAdd(&Etg[g], v1); atomicAdd(&Etg[16+g], v2);
    atomicAdd(&td[g*3+0], tx); atomicAdd(&td[g*3+1], ty); atomicAdd(&td[g*3+2], tz);
  }
}

// ================= backward head =================
__global__ void k_bwd_head(const float* __restrict__ WPRODT1, const float* __restrict__ WSCT1,
                           const float* __restrict__ we1, const float* __restrict__ we0,
                           float* __restrict__ gvp, float* __restrict__ gnfc){
  int d = threadIdx.x;
  float a = 0.f, b = 0.f;
  #pragma unroll
  for (int c = 0; c < 64; ++c){
    float w = we1[c];
    a = fmaf(w, WPRODT1[c*64+d], a);
    b = fmaf(w, WSCT1[c*64+d], b);
  }
  gvp[d] = a;
  gnfc[d] = b + we0[d];
}

// ================= poly backward (k=0 plane) =================
__global__ __launch_bounds__(256) void k_polybwd0(
    const float* __restrict__ gmp, int per_node, const float* __restrict__ msgbase,
    const float* __restrict__ wp, float* __restrict__ out){
  int lane = threadIdx.x & 63;
  int n = blockIdx.x*4 + (threadIdx.x >> 6);
  if (n >= NN) return;
  float g = per_node ? gmp[(size_t)n*64 + lane] : gmp[lane];
  float s0 = msgbase[(size_t)n*256 + lane];
  float p0 = wp[lane*3], p1 = wp[lane*3+1], p2 = wp[lane*3+2];
  float poly = fmaf(fmaf(p2, s0, p1), s0, p0);
  float dp   = fmaf(2.f*p2, s0, p1);
  out[(size_t)n*64 + lane] = g*fmaf(s0, dp, poly);
}

// ================= compact 64-wide matvec =================
__global__ __launch_bounds__(256) void k_lin0(
    const float* __restrict__ in, const float* __restrict__ W, float* __restrict__ out){
  int lane = threadIdx.x & 63;
  float wcol[64];
  #pragma unroll
  for (int j = 0; j < 64; ++j) wcol[j] = W[j*64 + lane];
  int wid = blockIdx.x*4 + (threadIdx.x >> 6);
  int nw  = gridDim.x*4;
  for (int n = wid; n < NN; n += nw){
    float x = in[(size_t)n*64 + lane];
    float a0 = 0.f, a1 = 0.f, a2 = 0.f, a3 = 0.f;
    #pragma unroll
    for (int j = 0; j < 64; j += 4){
      a0 = fmaf(rlane(x, j  ), wcol[j  ], a0);
      a1 = fmaf(rlane(x, j+1), wcol[j+1], a1);
      a2 = fmaf(rlane(x, j+2), wcol[j+2], a2);
      a3 = fmaf(rlane(x, j+3), wcol[j+3], a3);
    }
    out[(size_t)n*64 + lane] = (a0+a1) + (a2+a3);
  }
}

// ================= edge-parallel backward: rr = lerp(TQ)·h·gm, gvec = rr·u =================
__global__ __launch_bounds__(256) void k_bwdE(
    const float* __restrict__ TQ, const float* __restrict__ rl, const float* __restrict__ uv,
    const float* __restrict__ nf, const float* __restrict__ gagg0, const int* __restrict__ ei,
    float* __restrict__ gvec, int accum){
  int lane = threadIdx.x & 63;
  int wid = blockIdx.x*4 + (threadIdx.x >> 6);
  int nw  = gridDim.x*4;
  for (int e = wid; e < NE; e += nw){
    float L = rl[e];
    if (L >= 5.f){
      if (!accum && lane < 3) gvec[(size_t)e*3 + lane] = 0.f;
      continue;
    }
    int s = __builtin_amdgcn_readfirstlane(ei[e]);
    int r = __builtin_amdgcn_readfirstlane(ei[NE+e]);
    float h  = nf[(size_t)s*256 + lane];
    float gm = gagg0[(size_t)r*64 + lane]*(1.f/16.f);
    float pos = L*(NB/5.f);
    int bi = (int)pos;
    float f = pos - (float)bi;
    const float* T = TQ + (size_t)bi*64 + lane;
    float Q = fmaf(T[64]-T[0], f, T[0]);
    float rr = Q*h*gm;
    #pragma unroll
    for (int o = 32; o; o >>= 1) rr += __shfl_xor(rr, o, 64);
    if (lane < 3){
      float comp = rr*uv[(size_t)e*3 + lane];
      size_t gi = (size_t)e*3 + lane;
      if (accum) gvec[gi] += comp; else gvec[gi] = comp;
    }
  }
}

// ================= gh gather via sender CSR (w from table, gagg[receiver]) =================
__global__ __launch_bounds__(256) void k_ghgather0(
    const float* __restrict__ TW, const float* __restrict__ rl, const float* __restrict__ gagg0,
    const int* __restrict__ ei, const int* __restrict__ offs_, const int* __restrict__ lists,
    const float* __restrict__ gnfc, float* __restrict__ out){
  int lane = threadIdx.x & 63;
  int wid = blockIdx.x*4 + (threadIdx.x >> 6);
  int nw  = gridDim.x*4;
  for (int n = wid; n < NN; n += nw){
    int lo = offs_[n], hi = offs_[n+1];
    float acc = 0.f;
    for (int i = lo; i < hi; ++i){
      int e = __builtin_amdgcn_readfirstlane(lists[i]);
      float L = rl[e];
      if (L >= 5.f) continue;
      int r = __builtin_amdgcn_readfirstlane(ei[NE+e]);
      float pos = L*(NB/5.f);
      int bi = (int)pos;
      float f = pos - (float)bi;
      const float* T = TW + (size_t)bi*64 + lane;
      float w = fmaf(T[64]-T[0], f, T[0]);
      acc = fmaf(w, gagg0[(size_t)r*64 + lane], acc);
    }
    out[(size_t)n*64 + lane] = gnfc[lane] + acc*(1.f/16.f);
  }
}

// ---------- CSR-based force assembly ----------
__global__ void k_gpos(const float* __restrict__ gvec,
                       const int* __restrict__ offr, const int* __restrict__ listr,
                       const int* __restrict__ offs_, const int* __restrict__ lists,
                       float* __restrict__ gpos){
  int n = blockIdx.x*256 + threadIdx.x;
  if (n >= NN) return;
  float ax = 0.f, ay = 0.f, az = 0.f;
  for (int i = offs_[n]; i < offs_[n+1]; ++i){
    int e = lists[i];
    ax += gvec[(size_t)e*3]; ay += gvec[(size_t)e*3+1]; az += gvec[(size_t)e*3+2];
  }
  for (int i = offr[n]; i < offr[n+1]; ++i){
    int e = listr[i];
    ax -= gvec[(size_t)e*3]; ay -= gvec[(size_t)e*3+1]; az -= gvec[(size_t)e*3+2];
  }
  gpos[n*3+0] = ax; gpos[n*3+1] = ay; gpos[n*3+2] = az;
}

__global__ void k_writeout(const float* __restrict__ e0g, const float* __restrict__ Etg,
                           const float* __restrict__ td, const float* __restrict__ adp,
                           const float* __restrict__ gpos, void* __restrict__ outv,
                           const int* __restrict__ flag){
  int i = blockIdx.x*256 + threadIdx.x;
  const int total = NG + NG*3 + NN*3 + NG*3 + NN*3; // 60112
  if (i >= total) return;
  float v;
  if (i < 16){
    v = e0g[i] + Etg[i] + Etg[16+i];
  } else if (i < 64){
    int j = i - 16; int g = j/3, t = j - g*3;
    v = (t == 0) ? e0g[g] : Etg[(t-1)*16 + g];
  } else if (i < 64 + NN*3){
    v = -gpos[i-64];
  } else if (i < 64 + NN*3 + 48){
    v = td[i - (64 + NN*3)];
  } else {
    v = adp[i - (64 + NN*3 + 48)];
  }
  if (flag[0]) ((__hip_bfloat16*)outv)[i] = __float2bfloat16(v);
  else         ((float*)outv)[i] = v;
}

extern "C" void kernel_launch(void* const* d_in, const int* in_sizes, int n_in,
                              void* d_out, int out_size, void* d_ws, size_t ws_size,
                              hipStream_t stream) {
  if (ws_size < WS_FLOATS*sizeof(float)) return; // ~78 MB
  const int* ei    = (const int*)d_in[14];
  const int* batch = (const int*)d_in[15];
  float* ws = (float*)d_ws;
  int* flag = (int*)(ws + O_FLAG);

  hipMemsetAsync(ws + OFF_ACC, 0, ACC_FLOATS*sizeof(float), stream);
  k_detect<<<1, 256, 0, stream>>>((const unsigned*)d_in[1], flag);
  k_load_all<<<(LD_TOTAL+255)/256, 256, 0, stream>>>(
      d_in[0], d_in[1], d_in[2], d_in[3], d_in[4], d_in[5], d_in[6], d_in[7],
      d_in[8], d_in[9], d_in[10], d_in[11], d_in[12], d_in[13], ws, flag);
  k_transpose_all<<<288, 256, 0, stream>>>(ws);

  k_geom<<<(NE+255)/256, 256, 0, stream>>>(ws+OFF_PIN, ws+OFF_SHF, ei, ws+OFF_RL, ws+OFF_UV);
  k_tables<<<(2*NB1+3)/4, 256, 0, stream>>>(ws+O_R1, ws+O_R2, ws+O_TW, ws+O_TQ);
  k_init_nodes<<<(NN+3)/4, 256, 0, stream>>>(ws+OFF_ATT, ws+O_WEMB, ws+O_AE, ws+OFF_NF0, ws+O_E0N);

  int* offr  = (int*)(ws + O_OFFR);
  int* offs_ = (int*)(ws + O_OFFS);
  int* curr  = (int*)(ws + O_CURR);
  int* curs  = (int*)(ws + O_CURS);
  int* listr = (int*)(ws + O_LISTR);
  int* lists = (int*)(ws + O_LISTS);
  hipMemsetAsync(curr, 0, 2*NN*sizeof(int), stream);
  k_csr_count<<<(NE+255)/256, 256, 0, stream>>>(ei, curr, curs);
  k_csr_scan<<<1, 256, 0, stream>>>(curr, curs, offr, offs_);
  k_csr_fill<<<(NE+255)/256, 256, 0, stream>>>(ei, curr, curs, listr, lists);

  const size_t NF[3]  = {OFF_NF0, OFF_NF1, OFF_NF2};
  const size_t MSG[2] = {OFF_MSG0, OFF_MSG1};
  dim3 ling(256, 4);
  float* GA0 = ws + OFF_AGG;                 // compact NN*64 (AGG free after forward)
  float* GB0 = ws + OFF_AGG + (size_t)NN*64;

  // ---------- forward ----------
  for (int t = 0; t < NT; ++t){
    k_agg<<<1024, 256, 0, stream>>>(ws+O_TW + (size_t)t*NB1*64, ws+OFF_RL, ws+OFF_UV,
                                    ws+NF[t], ei, offr, listr, ws+OFF_AGG);
    k_lin2<<<ling, 256, 0, stream>>>(ws+OFF_AGG, ws+O_WMIX + (size_t)t*12288, ws+MSG[t]);
    k_tail<<<1024, 256, 0, stream>>>(ws+NF[t], ws+MSG[t],
                                     ws+O_WSC + (size_t)t*12288, ws+O_WPROD + (size_t)t*12288,
                                     ws+O_WPOLY + (size_t)t*192, ws+O_WE + (size_t)t*64,
                                     ws+O_WD + (size_t)t*64,
                                     ws+NF[t+1], ws + (t ? O_EN1 : O_EN0), ws+O_ADP);
  }

  // ---------- backward (k=0 plane only) ----------
  k_bwd_head<<<1, 64, 0, stream>>>(ws+O_WPRODT+12288, ws+O_WSCT+12288, ws+O_WE+64, ws+O_WE,
                                   ws+O_GVP, ws+O_GNFC);
  { // t = 1
    k_polybwd0<<<(NN+3)/4, 256, 0, stream>>>(ws+O_GVP, 0, ws+MSG[1], ws+O_WPOLY+192, GB0);
    k_lin0<<<1024, 256, 0, stream>>>(GB0, ws+O_WMIXT+12288, GA0);   // gagg0 for t=1
    k_bwdE<<<2048, 256, 0, stream>>>(ws+O_TQ + (size_t)NB1*64, ws+OFF_RL, ws+OFF_UV,
                                     ws+NF[1], GA0, ei, ws+O_GVEC, 0);
    k_ghgather0<<<1024, 256, 0, stream>>>(ws+O_TW + (size_t)NB1*64, ws+OFF_RL, GA0, ei,
                                          offs_, lists, ws+O_GNFC, GB0);
  }
  { // t = 0
    k_lin0<<<1024, 256, 0, stream>>>(GB0, ws+O_WPRODT, GA0);        // gmp0 per node
    k_polybwd0<<<(NN+3)/4, 256, 0, stream>>>(GA0, 1, ws+MSG[0], ws+O_WPOLY, GB0);
    k_lin0<<<1024, 256, 0, stream>>>(GB0, ws+O_WMIXT, GA0);         // gagg0 for t=0
    k_bwdE<<<2048, 256, 0, stream>>>(ws+O_TQ, ws+OFF_RL, ws+OFF_UV,
                                     ws+NF[0], GA0, ei, ws+O_GVEC, 1);
  }

  // reduce BEFORE gpos (per-node energy staging aliases the gpos slots)
  k_reduce<<<(NN+255)/256, 256, 0, stream>>>(ws+O_E0N, ws+O_EN0, ws+O_EN1, ws+O_ADP,
                                             ws+OFF_CHG, ws+OFF_PIN, batch,
                                             ws+O_E0G, ws+O_ETG, ws+O_TD);
  k_gpos<<<(NN+255)/256, 256, 0, stream>>>(ws+O_GVEC, offr, listr, offs_, lists, ws+O_GPOS);
  k_writeout<<<(60112+255)/256, 256, 0, stream>>>(ws+O_E0G, ws+O_ETG, ws+O_TD, ws+O_ADP, ws+O_GPOS, d_out, flag);
}

// Round 11
// 429.162 us; speedup vs baseline: 2.6004x; 1.2918x over previous
//
#include <hip/hip_runtime.h>
#include <hip/hip_bf16.h>

#define NN 10000
#define NE 160000
#define NZ 10
#define NC 64
#define NBES 8
#define NG 16
#define NT 2
#define NB 2048
#define NB1 2049

static constexpr float PI_F  = 3.14159265358979323846f;
static constexpr float KBES  = 0.63245553203367587f;  // sqrt(2/5)
static constexpr float S3    = 1.73205080756887729f;

// ---- workspace layout (float offsets); node tensors stride 256 (planes 0..3) ----
static constexpr size_t OFF_UVL  = 0;                        // NE*4 : (ux,uy,uz,L)
static constexpr size_t OFF_PIN  = OFF_UVL + (size_t)NE*4;
static constexpr size_t OFF_ATT  = OFF_PIN + (size_t)NN*3;
static constexpr size_t OFF_CHG  = OFF_ATT + (size_t)NN*NZ;
static constexpr size_t OFF_SHF  = OFF_CHG + (size_t)NN;
static constexpr size_t NFS      = (size_t)NN*256;
static constexpr size_t OFF_NF0  = OFF_SHF + (size_t)NE*3;
static constexpr size_t OFF_NF1  = OFF_NF0 + NFS;
static constexpr size_t OFF_NF2  = OFF_NF1 + NFS;
static constexpr size_t OFF_MSG0 = OFF_NF2 + NFS;
static constexpr size_t OFF_MSG1 = OFF_MSG0+ NFS;
static constexpr size_t OFF_AGG  = OFF_MSG1+ NFS;    // fwd agg; bwd compact GA0/GB0
static constexpr size_t OFF_W    = OFF_AGG + NFS;
static constexpr size_t O_WEMB   = OFF_W;
static constexpr size_t O_AE     = O_WEMB + 640;
static constexpr size_t O_R1     = O_AE   + 16;
static constexpr size_t O_R2     = O_R1   + 1024;
static constexpr size_t O_WMIX   = O_R2   + 8192;
static constexpr size_t O_WMIXT  = O_WMIX + 24576;
static constexpr size_t O_WSC    = O_WMIXT+ 24576;
static constexpr size_t O_WSCT   = O_WSC  + 24576;
static constexpr size_t O_WPROD  = O_WSCT + 24576;
static constexpr size_t O_WPRODT = O_WPROD+ 24576;
static constexpr size_t O_WPOLY  = O_WPRODT+24576;
static constexpr size_t O_WE     = O_WPOLY+ 384;
static constexpr size_t O_WD     = O_WE   + 128;
static constexpr size_t OFF_ACC  = O_WD   + 128;             // zeroed region start
static constexpr size_t O_E0G    = OFF_ACC;
static constexpr size_t O_ETG    = O_E0G + 16;
static constexpr size_t O_TD     = O_ETG + 32;
static constexpr size_t O_ADP    = O_TD  + 48;
static constexpr size_t ACC_FLOATS = 96 + (size_t)NN*3;      // e0g..adp
static constexpr size_t O_GPOS   = O_ADP + (size_t)NN*3;
static constexpr size_t O_EN0    = O_GPOS + (size_t)NN*3;    // separate (no alias)
static constexpr size_t O_EN1    = O_EN0 + NN;
static constexpr size_t O_E0N    = O_EN1 + NN;
static constexpr size_t O_GVEC   = O_E0N + NN;               // per-edge dE/dvec (live only)
static constexpr size_t O_FLAG   = O_GVEC + (size_t)NE*3;
static constexpr size_t O_GVP    = O_FLAG + 4;
static constexpr size_t O_GNFC   = O_GVP + 64;
static constexpr size_t O_TW     = O_GNFC + 64;              // 2 layers x NB1 x 64
static constexpr size_t O_TQ     = O_TW + (size_t)2*NB1*64;
static constexpr size_t O_OFFR   = O_TQ + (size_t)2*NB1*64;  // ints from here
static constexpr size_t O_OFFS   = O_OFFR + (NN+1);
static constexpr size_t O_CURR   = O_OFFS + (NN+1);
static constexpr size_t O_CURS   = O_CURR + NN;
static constexpr size_t O_LISTR  = O_CURS + NN;
static constexpr size_t O_LISTS  = O_LISTR + (size_t)NE;
static constexpr size_t WS_FLOATS= O_LISTS + (size_t)NE;     // ~79 MB

__device__ __forceinline__ float rlane(float v, int l){
  return __int_as_float(__builtin_amdgcn_readlane(__float_as_int(v), l));
}

// ---------- dtype detection ----------
__global__ void k_detect(const unsigned* __restrict__ raw, int* __restrict__ flag){
  __shared__ int found;
  if (threadIdx.x == 0) found = 0;
  __syncthreads();
  for (int i = threadIdx.x; i < 4096; i += 256){
    unsigned w = raw[i];
    if (w == 0x00003F80u || w == 0x3F803F80u) found = 1;
  }
  __syncthreads();
  if (threadIdx.x == 0) flag[0] = found;
}

// ---------- fused loader ----------
static constexpr int LD_CNT[14] = {NN*3, NN*NZ, NN, NE*3, NZ*64, NZ, NT*NBES*64, NT*64*64,
                                   NT*3*64*64, NT*3*64*64, NT*64*3, NT*3*64*64, NT*64, NT*64};
static constexpr int LD_TOTAL = NN*3 + NN*NZ + NN + NE*3 + NZ*64 + NZ + NT*NBES*64 + NT*64*64
                              + 3*(NT*3*64*64) + NT*64*3 + 4*(NT*64) - NT*64*2;
__global__ __launch_bounds__(256) void k_load_all(
    const void* s0, const void* s1, const void* s2, const void* s3, const void* s4,
    const void* s5, const void* s6, const void* s7, const void* s8, const void* s9,
    const void* s10, const void* s11, const void* s12, const void* s13,
    float* __restrict__ ws, const int* __restrict__ flag){
  const void* srcs[14] = {s0,s1,s2,s3,s4,s5,s6,s7,s8,s9,s10,s11,s12,s13};
  const size_t dsts[14] = {OFF_PIN, OFF_ATT, OFF_CHG, OFF_SHF, O_WEMB, O_AE, O_R1, O_R2,
                           O_WMIX, O_WSC, O_WPOLY, O_WPROD, O_WE, O_WD};
  int i = blockIdx.x*256 + threadIdx.x;
  int seg = -1, off = i;
  #pragma unroll
  for (int j = 0; j < 14; ++j){
    if (seg < 0){
      if (off < LD_CNT[j]) seg = j;
      else off -= LD_CNT[j];
    }
  }
  if (seg < 0) return;
  float v = flag[0] ? __bfloat162float(((const __hip_bfloat16*)srcs[seg])[off])
                    : ((const float*)srcs[seg])[off];
  ws[dsts[seg] + off] = v;
}

// ---------- fused transposes (WMIX, WSC, WPROD) ----------
__global__ void k_transpose_all(float* __restrict__ ws){
  const size_t srcs[3] = {O_WMIX, O_WSC, O_WPROD};
  const size_t dsts[3] = {O_WMIXT, O_WSCT, O_WPRODT};
  int i = blockIdx.x*256 + threadIdx.x;
  if (i >= 18*4096) return;
  int mm = i >> 12, r = (i >> 6) & 63, c = i & 63;
  int grp = mm / 6, m = mm % 6;
  ws[dsts[grp] + (size_t)m*4096 + (size_t)c*64 + r] =
      ws[srcs[grp] + (size_t)m*4096 + (size_t)r*64 + c];
}

// ---------- edge geometry + live-edge counting ----------
__global__ void k_geom(const float* __restrict__ pos, const float* __restrict__ shifts,
                       const int* __restrict__ ei, float* __restrict__ uvl,
                       int* __restrict__ cntr, int* __restrict__ cnts){
  int e = blockIdx.x*256 + threadIdx.x;
  if (e >= NE) return;
  int s = ei[e], r = ei[NE + e];
  float vx = pos[s*3+0] - pos[r*3+0] + shifts[(size_t)e*3+0];
  float vy = pos[s*3+1] - pos[r*3+1] + shifts[(size_t)e*3+1];
  float vz = pos[s*3+2] - pos[r*3+2] + shifts[(size_t)e*3+2];
  float L = sqrtf(vx*vx + vy*vy + vz*vz + 1e-12f);
  float inv = 1.f / L;
  uvl[(size_t)e*4+0] = vx*inv; uvl[(size_t)e*4+1] = vy*inv;
  uvl[(size_t)e*4+2] = vz*inv; uvl[(size_t)e*4+3] = L;
  if (L < 5.f){
    atomicAdd(&cntr[r], 1);
    atomicAdd(&cnts[s], 1);
  }
}

// ---------- radial tables ----------
__global__ __launch_bounds__(256) void k_tables(
    const float* __restrict__ R1all, const float* __restrict__ R2all,
    float* __restrict__ TW, float* __restrict__ TQ){
  int lane = threadIdx.x & 63;
  int task = blockIdx.x*4 + (threadIdx.x >> 6);
  if (task >= 2*NB1) return;
  int t = task / NB1, node = task % NB1;
  const float* R1 = R1all + (size_t)t*512;
  const float* R2 = R2all + (size_t)t*4096;
  float r1c[8];
  #pragma unroll
  for (int j = 0; j < 8; ++j) r1c[j] = R1[j*64 + lane];
  float L = fmaxf((float)node * (5.f/NB), 1e-6f);
  float ur = L*0.2f;
  float ef[8], dd[8];
  if (ur < 1.f){
    float u2=ur*ur, u4=u2*u2, u5=u4*ur;
    float fc = 1.f - 21.f*u5 + 35.f*u5*ur - 15.f*u5*u2;
    float omu = 1.f - ur;
    float dfc = -105.f*u4*omu*omu;
    float invr = 1.f/(L + 1e-9f);
    #pragma unroll
    for (int b = 0; b < 8; ++b){
      float nb = (float)(b+1);
      float arg = nb*PI_F*ur;
      float sn = __sinf(arg), cs = __cosf(arg);
      float bes = KBES*sn*invr;
      float dbes = KBES*(nb*PI_F*0.2f)*cs*invr - bes*invr;
      ef[b] = bes*fc;
      dd[b] = dbes*fc + bes*dfc*0.2f;
    }
  } else {
    #pragma unroll
    for (int b = 0; b < 8; ++b){ ef[b] = 0.f; dd[b] = 0.f; }
  }
  float a = 0.f, tt = 0.f;
  #pragma unroll
  for (int b = 0; b < 8; ++b){ a = fmaf(ef[b], r1c[b], a); tt = fmaf(r1c[b], dd[b], tt); }
  float sg = 1.f/(1.f + __expf(-a));
  float sl = a*sg;
  float q  = sg*fmaf(a, 1.f - sg, 1.f)*tt;
  float r2c[64];
  #pragma unroll
  for (int j = 0; j < 64; ++j) r2c[j] = R2[j*64 + lane];
  float W0=0.f, W1=0.f, Q0=0.f, Q1=0.f;
  #pragma unroll
  for (int j = 0; j < 64; j += 2){
    W0 = fmaf(rlane(sl, j  ), r2c[j  ], W0);
    W1 = fmaf(rlane(sl, j+1), r2c[j+1], W1);
    Q0 = fmaf(rlane(q,  j  ), r2c[j  ], Q0);
    Q1 = fmaf(rlane(q,  j+1), r2c[j+1], Q1);
  }
  size_t idx = ((size_t)t*NB1 + node)*64 + lane;
  TW[idx] = W0+W1;
  TQ[idx] = Q0+Q1;
}

// ---------- node init ----------
__global__ __launch_bounds__(256) void k_init_nodes(
    const float* __restrict__ attrs, const float* __restrict__ Wemb,
    const float* __restrict__ ae, float* __restrict__ nf0, float* __restrict__ e0n){
  int lane = threadIdx.x & 63;
  int n = blockIdx.x*4 + (threadIdx.x >> 6);
  if (n >= NN) return;
  float acc = 0.f;
  #pragma unroll
  for (int z = 0; z < NZ; ++z) acc = fmaf(attrs[(size_t)n*NZ+z], Wemb[z*64+lane], acc);
  size_t base = (size_t)n*256;
  nf0[base + lane] = acc;
  #pragma unroll
  for (int k = 1; k < 4; ++k) nf0[base + (size_t)k*64 + lane] = 0.f;
  if (lane == 0){
    float e = 0.f;
    #pragma unroll
    for (int z = 0; z < NZ; ++z) e = fmaf(attrs[(size_t)n*NZ+z], ae[z], e);
    e0n[n] = e;
  }
}

// ================= LDS-staged prefix scan (counts -> offsets + cursors) =================
__global__ __launch_bounds__(256) void k_csr_scan(
    int* __restrict__ cntr, int* __restrict__ cnts,
    int* __restrict__ offr, int* __restrict__ offs_){
  __shared__ int lds[NN];
  __shared__ int part[256];
  for (int q = 0; q < 2; ++q){
    int* c   = q ? cnts  : cntr;
    int* off = q ? offs_ : offr;
    for (int i = threadIdx.x; i < NN; i += 256) lds[i] = c[i];
    __syncthreads();
    const int chunk = (NN + 255)/256;
    int lo = threadIdx.x*chunk, hi = lo+chunk; if (hi > NN) hi = NN; if (lo > NN) lo = NN;
    int s = 0;
    for (int i = lo; i < hi; ++i) s += lds[i];
    part[threadIdx.x] = s;
    __syncthreads();
    for (int o = 1; o < 256; o <<= 1){
      int v = (threadIdx.x >= o) ? part[threadIdx.x-o] : 0;
      __syncthreads();
      part[threadIdx.x] += v;
      __syncthreads();
    }
    int run = (threadIdx.x == 0) ? 0 : part[threadIdx.x-1];
    for (int i = lo; i < hi; ++i){
      int ci = lds[i];
      off[i] = run; c[i] = run;
      run += ci;
    }
    if (threadIdx.x == 255) off[NN] = run;
    __syncthreads();
  }
}

// ---------- fill: live edges only ----------
__global__ void k_csr_fill(const int* __restrict__ ei, const float* __restrict__ uvl,
                           int* __restrict__ curr, int* __restrict__ curs,
                           int* __restrict__ listr, int* __restrict__ lists){
  int e = blockIdx.x*256 + threadIdx.x;
  if (e >= NE) return;
  if (uvl[(size_t)e*4+3] >= 5.f) return;
  int pr = atomicAdd(&curr[ei[NE+e]], 1); listr[pr] = e;
  int ps = atomicAdd(&curs[ei[e]], 1);    lists[ps] = e;
}

// ================= aggregation via live receiver CSR =================
__global__ __launch_bounds__(256) void k_agg(
    const float* __restrict__ TW, const float* __restrict__ uvl,
    const float* __restrict__ nf, const int* __restrict__ ei,
    const int* __restrict__ offr, const int* __restrict__ listr,
    float* __restrict__ agg){
  int lane = threadIdx.x & 63;
  int wid = blockIdx.x*4 + (threadIdx.x >> 6);
  int nw  = gridDim.x*4;
  for (int n = wid; n < NN; n += nw){
    int lo = offr[n], hi = offr[n+1];
    float acc0=0.f, acc1=0.f, acc2=0.f, acc3=0.f;
    for (int i = lo; i < hi; ++i){
      int e = __builtin_amdgcn_readfirstlane(listr[i]);
      int s = __builtin_amdgcn_readfirstlane(ei[e]);
      float ux = uvl[(size_t)e*4], uy = uvl[(size_t)e*4+1], uz = uvl[(size_t)e*4+2];
      float L  = uvl[(size_t)e*4+3];
      float pos = L*(NB/5.f);
      int bi = (int)pos;
      float f = pos - (float)bi;
      const float* T = TW + (size_t)bi*64 + lane;
      float w = fmaf(T[64]-T[0], f, T[0]);
      float wh = w * nf[(size_t)s*256 + lane];
      acc0 += wh;
      acc1 = fmaf(wh, S3*ux, acc1);
      acc2 = fmaf(wh, S3*uy, acc2);
      acc3 = fmaf(wh, S3*uz, acc3);
    }
    size_t ob = (size_t)n*256 + lane;
    agg[ob]     = acc0*(1.f/16.f);
    agg[ob+64]  = acc1*(1.f/16.f);
    agg[ob+128] = acc2*(1.f/16.f);
    agg[ob+192] = acc3*(1.f/16.f);
  }
}

// ================= per-l linear (mix), readlane matvec (gridDim.y = 4) =================
__global__ __launch_bounds__(256) void k_lin2(
    const float* __restrict__ in, const float* __restrict__ W3, float* __restrict__ out){
  int k = blockIdx.y;
  int l = (k==0) ? 0 : 1;
  const float* W = W3 + (size_t)l*4096;
  int lane = threadIdx.x & 63;
  float wcol[64];
  #pragma unroll
  for (int j = 0; j < 64; ++j) wcol[j] = W[j*64 + lane];
  int wid = blockIdx.x*4 + (threadIdx.x >> 6);
  int nw  = gridDim.x*4;
  for (int n = wid; n < NN; n += nw){
    size_t base = (size_t)n*256;
    float x = in[base + (size_t)k*64 + lane];
    float a0 = 0.f, a1 = 0.f, a2 = 0.f, a3 = 0.f;
    #pragma unroll
    for (int j = 0; j < 64; j += 4){
      a0 = fmaf(rlane(x, j  ), wcol[j  ], a0);
      a1 = fmaf(rlane(x, j+1), wcol[j+1], a1);
      a2 = fmaf(rlane(x, j+2), wcol[j+2], a2);
      a3 = fmaf(rlane(x, j+3), wcol[j+3], a3);
    }
    out[base + (size_t)k*64 + lane] = (a0+a1) + (a2+a3);
  }
}

// ================= fused layer tail: sc-lin + poly-gated prod-lin + energy/dipole =================
__global__ __launch_bounds__(256) void k_tail(
    const float* __restrict__ nf_in, const float* __restrict__ msg,
    const float* __restrict__ Wsc, const float* __restrict__ Wprod, const float* __restrict__ wp,
    const float* __restrict__ we, const float* __restrict__ wd,
    float* __restrict__ nf_out, float* __restrict__ en, float* __restrict__ adp){
  int lane = threadIdx.x & 63;
  int k = threadIdx.x >> 6;
  int l = (k==0) ? 0 : 1;
  float wcs[64], wcp[64];
  #pragma unroll
  for (int j = 0; j < 64; ++j){
    wcs[j] = Wsc[(size_t)l*4096 + j*64 + lane];
    wcp[j] = Wprod[(size_t)l*4096 + j*64 + lane];
  }
  float p0 = wp[lane*3], p1 = wp[lane*3+1], p2 = wp[lane*3+2];
  float rw = (k==0) ? we[lane] : wd[lane];
  for (int n = blockIdx.x; n < NN; n += gridDim.x){
    size_t base = (size_t)n*256;
    float s0 = msg[base + lane];
    float xm = (k==0) ? s0 : msg[base + (size_t)k*64 + lane];
    float xg = xm * fmaf(fmaf(p2, s0, p1), s0, p0);
    float xs = nf_in[base + (size_t)k*64 + lane];
    float a0=0.f, a1=0.f, b0=0.f, b1=0.f;
    #pragma unroll
    for (int j = 0; j < 64; j += 2){
      a0 = fmaf(rlane(xs, j  ), wcs[j  ], a0);
      a1 = fmaf(rlane(xs, j+1), wcs[j+1], a1);
      b0 = fmaf(rlane(xg, j  ), wcp[j  ], b0);
      b1 = fmaf(rlane(xg, j+1), wcp[j+1], b1);
    }
    float out = (a0+a1) + (b0+b1);
    nf_out[base + (size_t)k*64 + lane] = out;
    float red = out * rw;
    #pragma unroll
    for (int o = 32; o; o >>= 1) red += __shfl_xor(red, o, 64);
    if (lane == 0){
      if (k == 0) en[n] = red;
      else        adp[n*3 + (k-1)] += red;
    }
  }
}

// ================= backward head =================
__global__ void k_bwd_head(const float* __restrict__ WPRODT1, const float* __restrict__ WSCT1,
                           const float* __restrict__ we1, const float* __restrict__ we0,
                           float* __restrict__ gvp, float* __restrict__ gnfc){
  int d = threadIdx.x;
  float a = 0.f, b = 0.f;
  #pragma unroll
  for (int c = 0; c < 64; ++c){
    float w = we1[c];
    a = fmaf(w, WPRODT1[c*64+d], a);
    b = fmaf(w, WSCT1[c*64+d], b);
  }
  gvp[d] = a;
  gnfc[d] = b + we0[d];
}

// ================= t=1 backward chain: polybwd(gvp const) + mix^T matvec =================
__global__ __launch_bounds__(256) void k_gback1(
    const float* __restrict__ gvp, const float* __restrict__ msg1, const float* __restrict__ wp,
    const float* __restrict__ WMIXT1, float* __restrict__ out){
  int lane = threadIdx.x & 63;
  float wcol[64];
  #pragma unroll
  for (int j = 0; j < 64; ++j) wcol[j] = WMIXT1[j*64 + lane];
  float g = gvp[lane];
  float p0 = wp[lane*3], p1 = wp[lane*3+1], p2 = wp[lane*3+2];
  int wid = blockIdx.x*4 + (threadIdx.x >> 6);
  int nw  = gridDim.x*4;
  for (int n = wid; n < NN; n += nw){
    float s0 = msg1[(size_t)n*256 + lane];
    float poly = fmaf(fmaf(p2, s0, p1), s0, p0);
    float dp   = fmaf(2.f*p2, s0, p1);
    float gb = g*fmaf(s0, dp, poly);
    float a0=0.f, a1=0.f, a2=0.f, a3=0.f;
    #pragma unroll
    for (int j = 0; j < 64; j += 4){
      a0 = fmaf(rlane(gb, j  ), wcol[j  ], a0);
      a1 = fmaf(rlane(gb, j+1), wcol[j+1], a1);
      a2 = fmaf(rlane(gb, j+2), wcol[j+2], a2);
      a3 = fmaf(rlane(gb, j+3), wcol[j+3], a3);
    }
    out[(size_t)n*64 + lane] = (a0+a1) + (a2+a3);
  }
}

// ================= t=0 backward chain: prod^T + polybwd + mix^T =================
__global__ __launch_bounds__(256) void k_gback0(
    const float* __restrict__ gnf0, const float* __restrict__ msg0, const float* __restrict__ wp,
    const float* __restrict__ WPRODT0, const float* __restrict__ WMIXT0,
    float* __restrict__ out){
  int lane = threadIdx.x & 63;
  float wcp[64], wcm[64];
  #pragma unroll
  for (int j = 0; j < 64; ++j){
    wcp[j] = WPRODT0[j*64 + lane];
    wcm[j] = WMIXT0[j*64 + lane];
  }
  float p0 = wp[lane*3], p1 = wp[lane*3+1], p2 = wp[lane*3+2];
  int wid = blockIdx.x*4 + (threadIdx.x >> 6);
  int nw  = gridDim.x*4;
  for (int n = wid; n < NN; n += nw){
    float x = gnf0[(size_t)n*64 + lane];
    float a0=0.f, a1=0.f;
    #pragma unroll
    for (int j = 0; j < 64; j += 2){
      a0 = fmaf(rlane(x, j  ), wcp[j  ], a0);
      a1 = fmaf(rlane(x, j+1), wcp[j+1], a1);
    }
    float gmp = a0+a1;
    float s0 = msg0[(size_t)n*256 + lane];
    float poly = fmaf(fmaf(p2, s0, p1), s0, p0);
    float dp   = fmaf(2.f*p2, s0, p1);
    float gb = gmp*fmaf(s0, dp, poly);
    float b0=0.f, b1=0.f;
    #pragma unroll
    for (int j = 0; j < 64; j += 2){
      b0 = fmaf(rlane(gb, j  ), wcm[j  ], b0);
      b1 = fmaf(rlane(gb, j+1), wcm[j+1], b1);
    }
    out[(size_t)n*64 + lane] = b0+b1;
  }
}

// ================= edge-parallel backward over LIVE list =================
__global__ __launch_bounds__(256) void k_bwdE(
    const float* __restrict__ TQ, const float* __restrict__ uvl,
    const float* __restrict__ nf, const float* __restrict__ gagg0, const int* __restrict__ ei,
    const int* __restrict__ lists, const int* __restrict__ nlive_ptr,
    float* __restrict__ gvec, int accum){
  int lane = threadIdx.x & 63;
  int wid = blockIdx.x*4 + (threadIdx.x >> 6);
  int nw  = gridDim.x*4;
  int nlive = nlive_ptr[0];
  for (int i = wid; i < nlive; i += nw){
    int e = __builtin_amdgcn_readfirstlane(lists[i]);
    int s = __builtin_amdgcn_readfirstlane(ei[e]);
    int r = __builtin_amdgcn_readfirstlane(ei[NE+e]);
    float h  = nf[(size_t)s*256 + lane];
    float gm = gagg0[(size_t)r*64 + lane]*(1.f/16.f);
    float L  = uvl[(size_t)e*4+3];
    float pos = L*(NB/5.f);
    int bi = (int)pos;
    float f = pos - (float)bi;
    const float* T = TQ + (size_t)bi*64 + lane;
    float Q = fmaf(T[64]-T[0], f, T[0]);
    float rr = Q*h*gm;
    #pragma unroll
    for (int o = 32; o; o >>= 1) rr += __shfl_xor(rr, o, 64);
    if (lane < 3){
      float comp = rr*uvl[(size_t)e*4 + lane];
      size_t gi = (size_t)e*3 + lane;
      if (accum) gvec[gi] += comp; else gvec[gi] = comp;
    }
  }
}

// ================= gh gather via live sender CSR =================
__global__ __launch_bounds__(256) void k_ghgather0(
    const float* __restrict__ TW, const float* __restrict__ uvl, const float* __restrict__ gagg0,
    const int* __restrict__ ei, const int* __restrict__ offs_, const int* __restrict__ lists,
    const float* __restrict__ gnfc, float* __restrict__ out){
  int lane = threadIdx.x & 63;
  int wid = blockIdx.x*4 + (threadIdx.x >> 6);
  int nw  = gridDim.x*4;
  for (int n = wid; n < NN; n += nw){
    int lo = offs_[n], hi = offs_[n+1];
    float acc = 0.f;
    for (int i = lo; i < hi; ++i){
      int e = __builtin_amdgcn_readfirstlane(lists[i]);
      int r = __builtin_amdgcn_readfirstlane(ei[NE+e]);
      float L = uvl[(size_t)e*4+3];
      float pos = L*(NB/5.f);
      int bi = (int)pos;
      float f = pos - (float)bi;
      const float* T = TW + (size_t)bi*64 + lane;
      float w = fmaf(T[64]-T[0], f, T[0]);
      acc = fmaf(w, gagg0[(size_t)r*64 + lane], acc);
    }
    out[(size_t)n*64 + lane] = gnfc[lane] + acc*(1.f/16.f);
  }
}

// ================= final: force assembly (CSR) + segmented reductions =================
__global__ void k_final(const float* __restrict__ gvec,
                        const int* __restrict__ offr, const int* __restrict__ listr,
                        const int* __restrict__ offs_, const int* __restrict__ lists,
                        const float* __restrict__ e0n, const float* __restrict__ en0,
                        const float* __restrict__ en1, const float* __restrict__ adp,
                        const float* __restrict__ q, const float* __restrict__ pos,
                        const int* __restrict__ batch,
                        float* __restrict__ gpos, float* __restrict__ e0g,
                        float* __restrict__ Etg, float* __restrict__ td){
  int n = blockIdx.x*256 + threadIdx.x;
  int lane = threadIdx.x & 63;
  bool valid = (n < NN);
  if (valid){
    float ax = 0.f, ay = 0.f, az = 0.f;
    for (int i = offs_[n]; i < offs_[n+1]; ++i){
      int e = lists[i];
      ax += gvec[(size_t)e*3]; ay += gvec[(size_t)e*3+1]; az += gvec[(size_t)e*3+2];
    }
    for (int i = offr[n]; i < offr[n+1]; ++i){
      int e = listr[i];
      ax -= gvec[(size_t)e*3]; ay -= gvec[(size_t)e*3+1]; az -= gvec[(size_t)e*3+2];
    }
    gpos[n*3+0] = ax; gpos[n*3+1] = ay; gpos[n*3+2] = az;
  }
  int g = valid ? batch[n] : -1;
  float v0=0.f, v1=0.f, v2=0.f, tx=0.f, ty=0.f, tz=0.f;
  if (valid){
    v0 = e0n[n]; v1 = en0[n]; v2 = en1[n];
    float qq = q[n];
    tx = adp[n*3+0] + qq*pos[n*3+0];
    ty = adp[n*3+1] + qq*pos[n*3+1];
    tz = adp[n*3+2] + qq*pos[n*3+2];
  }
  int g0 = __shfl(g, 0, 64), g63 = __shfl(g, 63, 64);
  if (g0 == g63 && g0 >= 0){
    #pragma unroll
    for (int o = 32; o; o >>= 1){
      v0 += __shfl_xor(v0, o, 64); v1 += __shfl_xor(v1, o, 64); v2 += __shfl_xor(v2, o, 64);
      tx += __shfl_xor(tx, o, 64); ty += __shfl_xor(ty, o, 64); tz += __shfl_xor(tz, o, 64);
    }
    if (lane == 0){
      atomicAdd(&e0g[g0], v0); atomicAdd(&Etg[g0], v1); atomicAdd(&Etg[16+g0], v2);
      atomicAdd(&td[g0*3+0], tx); atomicAdd(&td[g0*3+1], ty); atomicAdd(&td[g0*3+2], tz);
    }
  } else if (valid){
    atomicAdd(&e0g[g], v0); atomicAdd(&Etg[g], v1); atomicAdd(&Etg[16+g], v2);
    atomicAdd(&td[g*3+0], tx); atomicAdd(&td[g*3+1], ty); atomicAdd(&td[g*3+2], tz);
  }
}

__global__ void k_writeout(const float* __restrict__ e0g, const float* __restrict__ Etg,
                           const float* __restrict__ td, const float* __restrict__ adp,
                           const float* __restrict__ gpos, void* __restrict__ outv,
                           const int* __restrict__ flag){
  int i = blockIdx.x*256 + threadIdx.x;
  const int total = NG + NG*3 + NN*3 + NG*3 + NN*3; // 60112
  if (i >= total) return;
  float v;
  if (i < 16){
    v = e0g[i] + Etg[i] + Etg[16+i];
  } else if (i < 64){
    int j = i - 16; int g = j/3, t = j - g*3;
    v = (t == 0) ? e0g[g] : Etg[(t-1)*16 + g];
  } else if (i < 64 + NN*3){
    v = -gpos[i-64];
  } else if (i < 64 + NN*3 + 48){
    v = td[i - (64 + NN*3)];
  } else {
    v = adp[i - (64 + NN*3 + 48)];
  }
  if (flag[0]) ((__hip_bfloat16*)outv)[i] = __float2bfloat16(v);
  else         ((float*)outv)[i] = v;
}

extern "C" void kernel_launch(void* const* d_in, const int* in_sizes, int n_in,
                              void* d_out, int out_size, void* d_ws, size_t ws_size,
                              hipStream_t stream) {
  if (ws_size < WS_FLOATS*sizeof(float)) return; // ~79 MB
  const int* ei    = (const int*)d_in[14];
  const int* batch = (const int*)d_in[15];
  float* ws = (float*)d_ws;
  int* flag = (int*)(ws + O_FLAG);

  int* offr  = (int*)(ws + O_OFFR);
  int* offs_ = (int*)(ws + O_OFFS);
  int* curr  = (int*)(ws + O_CURR);
  int* curs  = (int*)(ws + O_CURS);
  int* listr = (int*)(ws + O_LISTR);
  int* lists = (int*)(ws + O_LISTS);

  hipMemsetAsync(ws + OFF_ACC, 0, ACC_FLOATS*sizeof(float), stream);
  hipMemsetAsync(curr, 0, 2*NN*sizeof(int), stream);
  k_detect<<<1, 256, 0, stream>>>((const unsigned*)d_in[1], flag);
  k_load_all<<<(LD_TOTAL+255)/256, 256, 0, stream>>>(
      d_in[0], d_in[1], d_in[2], d_in[3], d_in[4], d_in[5], d_in[6], d_in[7],
      d_in[8], d_in[9], d_in[10], d_in[11], d_in[12], d_in[13], ws, flag);
  k_transpose_all<<<288, 256, 0, stream>>>(ws);

  k_geom<<<(NE+255)/256, 256, 0, stream>>>(ws+OFF_PIN, ws+OFF_SHF, ei, ws+OFF_UVL, curr, curs);
  k_tables<<<(2*NB1+3)/4, 256, 0, stream>>>(ws+O_R1, ws+O_R2, ws+O_TW, ws+O_TQ);
  k_init_nodes<<<(NN+3)/4, 256, 0, stream>>>(ws+OFF_ATT, ws+O_WEMB, ws+O_AE, ws+OFF_NF0, ws+O_E0N);

  k_csr_scan<<<1, 256, 0, stream>>>(curr, curs, offr, offs_);
  k_csr_fill<<<(NE+255)/256, 256, 0, stream>>>(ei, ws+OFF_UVL, curr, curs, listr, lists);

  const size_t NF[3]  = {OFF_NF0, OFF_NF1, OFF_NF2};
  const size_t MSG[2] = {OFF_MSG0, OFF_MSG1};
  dim3 ling(256, 4);
  float* GA0 = ws + OFF_AGG;                 // compact NN*64 (AGG free after forward)
  float* GB0 = ws + OFF_AGG + (size_t)NN*64;

  // ---------- forward ----------
  for (int t = 0; t < NT; ++t){
    k_agg<<<1024, 256, 0, stream>>>(ws+O_TW + (size_t)t*NB1*64, ws+OFF_UVL,
                                    ws+NF[t], ei, offr, listr, ws+OFF_AGG);
    k_lin2<<<ling, 256, 0, stream>>>(ws+OFF_AGG, ws+O_WMIX + (size_t)t*12288, ws+MSG[t]);
    k_tail<<<1024, 256, 0, stream>>>(ws+NF[t], ws+MSG[t],
                                     ws+O_WSC + (size_t)t*12288, ws+O_WPROD + (size_t)t*12288,
                                     ws+O_WPOLY + (size_t)t*192, ws+O_WE + (size_t)t*64,
                                     ws+O_WD + (size_t)t*64,
                                     ws+NF[t+1], ws + (t ? O_EN1 : O_EN0), ws+O_ADP);
  }

  // ---------- backward (k=0 plane only) ----------
  k_bwd_head<<<1, 64, 0, stream>>>(ws+O_WPRODT+12288, ws+O_WSCT+12288, ws+O_WE+64, ws+O_WE,
                                   ws+O_GVP, ws+O_GNFC);
  { // t = 1
    k_gback1<<<1024, 256, 0, stream>>>(ws+O_GVP, ws+MSG[1], ws+O_WPOLY+192,
                                       ws+O_WMIXT+12288, GA0);
    k_bwdE<<<2048, 256, 0, stream>>>(ws+O_TQ + (size_t)NB1*64, ws+OFF_UVL,
                                     ws+NF[1], GA0, ei, lists, offs_ + NN, ws+O_GVEC, 0);
    k_ghgather0<<<1024, 256, 0, stream>>>(ws+O_TW + (size_t)NB1*64, ws+OFF_UVL, GA0, ei,
                                          offs_, lists, ws+O_GNFC, GB0);
  }
  { // t = 0
    k_gback0<<<1024, 256, 0, stream>>>(GB0, ws+MSG[0], ws+O_WPOLY,
                                       ws+O_WPRODT, ws+O_WMIXT, GA0);
    k_bwdE<<<2048, 256, 0, stream>>>(ws+O_TQ, ws+OFF_UVL,
                                     ws+NF[0], GA0, ei, lists, offs_ + NN, ws+O_GVEC, 1);
  }

  k_final<<<(NN+255)/256, 256, 0, stream>>>(ws+O_GVEC, offr, listr, offs_, lists,
                                            ws+O_E0N, ws+O_EN0, ws+O_EN1, ws+O_ADP,
                                            ws+OFF_CHG, ws+OFF_PIN, batch,
                                            ws+O_GPOS, ws+O_E0G, ws+O_ETG, ws+O_TD);
  k_writeout<<<(60112+255)/256, 256, 0, stream>>>(ws+O_E0G, ws+O_ETG, ws+O_TD, ws+O_ADP, ws+O_GPOS, d_out, flag);
}

// Round 12
// 411.874 us; speedup vs baseline: 2.7096x; 1.0420x over previous
//
#include <hip/hip_runtime.h>
#include <hip/hip_bf16.h>

#define NN 10000
#define NE 160000
#define NZ 10
#define NC 64
#define NBES 8
#define NG 16
#define NT 2
#define NB 2048
#define NB1 2049

static constexpr float PI_F  = 3.14159265358979323846f;
static constexpr float KBES  = 0.63245553203367587f;  // sqrt(2/5)
static constexpr float S3    = 1.73205080756887729f;

// ---- workspace layout (float offsets); node tensors stride 256 (planes 0..3) ----
static constexpr size_t OFF_UVL  = 0;                        // NE*4 : (ux,uy,uz,L)
static constexpr size_t OFF_PIN  = OFF_UVL + (size_t)NE*4;
static constexpr size_t OFF_ATT  = OFF_PIN + (size_t)NN*3;
static constexpr size_t OFF_CHG  = OFF_ATT + (size_t)NN*NZ;
static constexpr size_t OFF_SHF  = OFF_CHG + (size_t)NN;
static constexpr size_t NFS      = (size_t)NN*256;
static constexpr size_t OFF_NF0  = OFF_SHF + (size_t)NE*3;
static constexpr size_t OFF_NF1  = OFF_NF0 + NFS;
static constexpr size_t OFF_NF2  = OFF_NF1 + NFS;
static constexpr size_t OFF_MSG0 = OFF_NF2 + NFS;
static constexpr size_t OFF_MSG1 = OFF_MSG0+ NFS;
static constexpr size_t OFF_AGG  = OFF_MSG1+ NFS;    // fwd agg; bwd GA1/GB0/GA0 compact
static constexpr size_t OFF_W    = OFF_AGG + NFS;
static constexpr size_t O_WEMB   = OFF_W;
static constexpr size_t O_AE     = O_WEMB + 640;
static constexpr size_t O_R1     = O_AE   + 16;
static constexpr size_t O_R2     = O_R1   + 1024;
static constexpr size_t O_WMIX   = O_R2   + 8192;
static constexpr size_t O_WMIXT  = O_WMIX + 24576;
static constexpr size_t O_WSC    = O_WMIXT+ 24576;
static constexpr size_t O_WSCT   = O_WSC  + 24576;
static constexpr size_t O_WPROD  = O_WSCT + 24576;
static constexpr size_t O_WPRODT = O_WPROD+ 24576;
static constexpr size_t O_WPOLY  = O_WPRODT+24576;
static constexpr size_t O_WE     = O_WPOLY+ 384;
static constexpr size_t O_WD     = O_WE   + 128;
static constexpr size_t OFF_ACC  = O_WD   + 128;             // zeroed region start
static constexpr size_t O_E0G    = OFF_ACC;
static constexpr size_t O_ETG    = O_E0G + 16;
static constexpr size_t O_TD     = O_ETG + 32;
static constexpr size_t O_ADP    = O_TD  + 48;
static constexpr size_t ACC_FLOATS = 96 + (size_t)NN*3;      // e0g..adp
static constexpr size_t O_GPOS   = O_ADP + (size_t)NN*3;
static constexpr size_t O_EN0    = O_GPOS + (size_t)NN*3;
static constexpr size_t O_EN1    = O_EN0 + NN;
static constexpr size_t O_E0N    = O_EN1 + NN;
static constexpr size_t O_GVEC   = O_E0N + NN;               // per-edge dE/dvec (live only)
static constexpr size_t O_FLAG   = O_GVEC + (size_t)NE*3;
static constexpr size_t O_GVP    = O_FLAG + 4;
static constexpr size_t O_GNFC   = O_GVP + 64;
static constexpr size_t O_TW     = O_GNFC + 64;              // 2 layers x NB1 x 64
static constexpr size_t O_TQ     = O_TW + (size_t)2*NB1*64;
static constexpr size_t O_OFFR   = O_TQ + (size_t)2*NB1*64;  // ints from here
static constexpr size_t O_OFFS   = O_OFFR + (NN+1);
static constexpr size_t O_CURR   = O_OFFS + (NN+1);
static constexpr size_t O_CURS   = O_CURR + NN;
static constexpr size_t O_LISTR  = O_CURS + NN;
static constexpr size_t O_LISTS  = O_LISTR + (size_t)NE;
static constexpr size_t WS_FLOATS= O_LISTS + (size_t)NE;     // ~79 MB

__device__ __forceinline__ float rlane(float v, int l){
  return __int_as_float(__builtin_amdgcn_readlane(__float_as_int(v), l));
}

// ---------- dtype detection ----------
__global__ void k_detect(const unsigned* __restrict__ raw, int* __restrict__ flag){
  __shared__ int found;
  if (threadIdx.x == 0) found = 0;
  __syncthreads();
  for (int i = threadIdx.x; i < 4096; i += 256){
    unsigned w = raw[i];
    if (w == 0x00003F80u || w == 0x3F803F80u) found = 1;
  }
  __syncthreads();
  if (threadIdx.x == 0) flag[0] = found;
}

// ---------- fused loader ----------
static constexpr int LD_CNT[14] = {NN*3, NN*NZ, NN, NE*3, NZ*64, NZ, NT*NBES*64, NT*64*64,
                                   NT*3*64*64, NT*3*64*64, NT*64*3, NT*3*64*64, NT*64, NT*64};
static constexpr int LD_TOTAL = NN*3 + NN*NZ + NN + NE*3 + NZ*64 + NZ + NT*NBES*64 + NT*64*64
                              + 3*(NT*3*64*64) + NT*64*3 + 4*(NT*64) - NT*64*2;
__global__ __launch_bounds__(256) void k_load_all(
    const void* s0, const void* s1, const void* s2, const void* s3, const void* s4,
    const void* s5, const void* s6, const void* s7, const void* s8, const void* s9,
    const void* s10, const void* s11, const void* s12, const void* s13,
    float* __restrict__ ws, const int* __restrict__ flag){
  const void* srcs[14] = {s0,s1,s2,s3,s4,s5,s6,s7,s8,s9,s10,s11,s12,s13};
  const size_t dsts[14] = {OFF_PIN, OFF_ATT, OFF_CHG, OFF_SHF, O_WEMB, O_AE, O_R1, O_R2,
                           O_WMIX, O_WSC, O_WPOLY, O_WPROD, O_WE, O_WD};
  int i = blockIdx.x*256 + threadIdx.x;
  int seg = -1, off = i;
  #pragma unroll
  for (int j = 0; j < 14; ++j){
    if (seg < 0){
      if (off < LD_CNT[j]) seg = j;
      else off -= LD_CNT[j];
    }
  }
  if (seg < 0) return;
  float v = flag[0] ? __bfloat162float(((const __hip_bfloat16*)srcs[seg])[off])
                    : ((const float*)srcs[seg])[off];
  ws[dsts[seg] + off] = v;
}

// ---------- fused transposes ----------
__global__ void k_transpose_all(float* __restrict__ ws){
  const size_t srcs[3] = {O_WMIX, O_WSC, O_WPROD};
  const size_t dsts[3] = {O_WMIXT, O_WSCT, O_WPRODT};
  int i = blockIdx.x*256 + threadIdx.x;
  if (i >= 18*4096) return;
  int mm = i >> 12, r = (i >> 6) & 63, c = i & 63;
  int grp = mm / 6, m = mm % 6;
  ws[dsts[grp] + (size_t)m*4096 + (size_t)c*64 + r] =
      ws[srcs[grp] + (size_t)m*4096 + (size_t)r*64 + c];
}

// ---------- edge geometry + live-edge counting ----------
__global__ void k_geom(const float* __restrict__ pos, const float* __restrict__ shifts,
                       const int* __restrict__ ei, float* __restrict__ uvl,
                       int* __restrict__ cntr, int* __restrict__ cnts){
  int e = blockIdx.x*256 + threadIdx.x;
  if (e >= NE) return;
  int s = ei[e], r = ei[NE + e];
  float vx = pos[s*3+0] - pos[r*3+0] + shifts[(size_t)e*3+0];
  float vy = pos[s*3+1] - pos[r*3+1] + shifts[(size_t)e*3+1];
  float vz = pos[s*3+2] - pos[r*3+2] + shifts[(size_t)e*3+2];
  float L = sqrtf(vx*vx + vy*vy + vz*vz + 1e-12f);
  float inv = 1.f / L;
  uvl[(size_t)e*4+0] = vx*inv; uvl[(size_t)e*4+1] = vy*inv;
  uvl[(size_t)e*4+2] = vz*inv; uvl[(size_t)e*4+3] = L;
  if (L < 5.f){
    atomicAdd(&cntr[r], 1);
    atomicAdd(&cnts[s], 1);
  }
}

// ---------- radial tables ----------
__global__ __launch_bounds__(256) void k_tables(
    const float* __restrict__ R1all, const float* __restrict__ R2all,
    float* __restrict__ TW, float* __restrict__ TQ){
  int lane = threadIdx.x & 63;
  int task = blockIdx.x*4 + (threadIdx.x >> 6);
  if (task >= 2*NB1) return;
  int t = task / NB1, node = task % NB1;
  const float* R1 = R1all + (size_t)t*512;
  const float* R2 = R2all + (size_t)t*4096;
  float r1c[8];
  #pragma unroll
  for (int j = 0; j < 8; ++j) r1c[j] = R1[j*64 + lane];
  float L = fmaxf((float)node * (5.f/NB), 1e-6f);
  float ur = L*0.2f;
  float ef[8], dd[8];
  if (ur < 1.f){
    float u2=ur*ur, u4=u2*u2, u5=u4*ur;
    float fc = 1.f - 21.f*u5 + 35.f*u5*ur - 15.f*u5*u2;
    float omu = 1.f - ur;
    float dfc = -105.f*u4*omu*omu;
    float invr = 1.f/(L + 1e-9f);
    #pragma unroll
    for (int b = 0; b < 8; ++b){
      float nb = (float)(b+1);
      float arg = nb*PI_F*ur;
      float sn = __sinf(arg), cs = __cosf(arg);
      float bes = KBES*sn*invr;
      float dbes = KBES*(nb*PI_F*0.2f)*cs*invr - bes*invr;
      ef[b] = bes*fc;
      dd[b] = dbes*fc + bes*dfc*0.2f;
    }
  } else {
    #pragma unroll
    for (int b = 0; b < 8; ++b){ ef[b] = 0.f; dd[b] = 0.f; }
  }
  float a = 0.f, tt = 0.f;
  #pragma unroll
  for (int b = 0; b < 8; ++b){ a = fmaf(ef[b], r1c[b], a); tt = fmaf(r1c[b], dd[b], tt); }
  float sg = 1.f/(1.f + __expf(-a));
  float sl = a*sg;
  float q  = sg*fmaf(a, 1.f - sg, 1.f)*tt;
  float r2c[64];
  #pragma unroll
  for (int j = 0; j < 64; ++j) r2c[j] = R2[j*64 + lane];
  float W0=0.f, W1=0.f, Q0=0.f, Q1=0.f;
  #pragma unroll
  for (int j = 0; j < 64; j += 2){
    W0 = fmaf(rlane(sl, j  ), r2c[j  ], W0);
    W1 = fmaf(rlane(sl, j+1), r2c[j+1], W1);
    Q0 = fmaf(rlane(q,  j  ), r2c[j  ], Q0);
    Q1 = fmaf(rlane(q,  j+1), r2c[j+1], Q1);
  }
  size_t idx = ((size_t)t*NB1 + node)*64 + lane;
  TW[idx] = W0+W1;
  TQ[idx] = Q0+Q1;
}

// ---------- node init ----------
__global__ __launch_bounds__(256) void k_init_nodes(
    const float* __restrict__ attrs, const float* __restrict__ Wemb,
    const float* __restrict__ ae, float* __restrict__ nf0, float* __restrict__ e0n){
  int lane = threadIdx.x & 63;
  int n = blockIdx.x*4 + (threadIdx.x >> 6);
  if (n >= NN) return;
  float acc = 0.f;
  #pragma unroll
  for (int z = 0; z < NZ; ++z) acc = fmaf(attrs[(size_t)n*NZ+z], Wemb[z*64+lane], acc);
  size_t base = (size_t)n*256;
  nf0[base + lane] = acc;
  #pragma unroll
  for (int k = 1; k < 4; ++k) nf0[base + (size_t)k*64 + lane] = 0.f;
  if (lane == 0){
    float e = 0.f;
    #pragma unroll
    for (int z = 0; z < NZ; ++z) e = fmaf(attrs[(size_t)n*NZ+z], ae[z], e);
    e0n[n] = e;
  }
}

// ================= LDS-staged prefix scan =================
__global__ __launch_bounds__(256) void k_csr_scan(
    int* __restrict__ cntr, int* __restrict__ cnts,
    int* __restrict__ offr, int* __restrict__ offs_){
  __shared__ int lds[NN];
  __shared__ int part[256];
  for (int q = 0; q < 2; ++q){
    int* c   = q ? cnts  : cntr;
    int* off = q ? offs_ : offr;
    for (int i = threadIdx.x; i < NN; i += 256) lds[i] = c[i];
    __syncthreads();
    const int chunk = (NN + 255)/256;
    int lo = threadIdx.x*chunk, hi = lo+chunk; if (hi > NN) hi = NN; if (lo > NN) lo = NN;
    int s = 0;
    for (int i = lo; i < hi; ++i) s += lds[i];
    part[threadIdx.x] = s;
    __syncthreads();
    for (int o = 1; o < 256; o <<= 1){
      int v = (threadIdx.x >= o) ? part[threadIdx.x-o] : 0;
      __syncthreads();
      part[threadIdx.x] += v;
      __syncthreads();
    }
    int run = (threadIdx.x == 0) ? 0 : part[threadIdx.x-1];
    for (int i = lo; i < hi; ++i){
      int ci = lds[i];
      off[i] = run; c[i] = run;
      run += ci;
    }
    if (threadIdx.x == 255) off[NN] = run;
    __syncthreads();
  }
}

// ---------- fill: live edges only ----------
__global__ void k_csr_fill(const int* __restrict__ ei, const float* __restrict__ uvl,
                           int* __restrict__ curr, int* __restrict__ curs,
                           int* __restrict__ listr, int* __restrict__ lists){
  int e = blockIdx.x*256 + threadIdx.x;
  if (e >= NE) return;
  if (uvl[(size_t)e*4+3] >= 5.f) return;
  int pr = atomicAdd(&curr[ei[NE+e]], 1); listr[pr] = e;
  int ps = atomicAdd(&curs[ei[e]], 1);    lists[ps] = e;
}

// ================= aggregation via live receiver CSR =================
__global__ __launch_bounds__(256) void k_agg(
    const float* __restrict__ TW, const float* __restrict__ uvl,
    const float* __restrict__ nf, const int* __restrict__ ei,
    const int* __restrict__ offr, const int* __restrict__ listr,
    float* __restrict__ agg){
  int lane = threadIdx.x & 63;
  int wid = blockIdx.x*4 + (threadIdx.x >> 6);
  int nw  = gridDim.x*4;
  for (int n = wid; n < NN; n += nw){
    int lo = offr[n], hi = offr[n+1];
    float acc0=0.f, acc1=0.f, acc2=0.f, acc3=0.f;
    for (int i = lo; i < hi; ++i){
      int e = __builtin_amdgcn_readfirstlane(listr[i]);
      int s = __builtin_amdgcn_readfirstlane(ei[e]);
      float ux = uvl[(size_t)e*4], uy = uvl[(size_t)e*4+1], uz = uvl[(size_t)e*4+2];
      float L  = uvl[(size_t)e*4+3];
      float pos = L*(NB/5.f);
      int bi = (int)pos;
      float f = pos - (float)bi;
      const float* T = TW + (size_t)bi*64 + lane;
      float w = fmaf(T[64]-T[0], f, T[0]);
      float wh = w * nf[(size_t)s*256 + lane];
      acc0 += wh;
      acc1 = fmaf(wh, S3*ux, acc1);
      acc2 = fmaf(wh, S3*uy, acc2);
      acc3 = fmaf(wh, S3*uz, acc3);
    }
    size_t ob = (size_t)n*256 + lane;
    agg[ob]     = acc0*(1.f/16.f);
    agg[ob+64]  = acc1*(1.f/16.f);
    agg[ob+128] = acc2*(1.f/16.f);
    agg[ob+192] = acc3*(1.f/16.f);
  }
}

// ================= per-l linear (mix) =================
__global__ __launch_bounds__(256) void k_lin2(
    const float* __restrict__ in, const float* __restrict__ W3, float* __restrict__ out){
  int k = blockIdx.y;
  int l = (k==0) ? 0 : 1;
  const float* W = W3 + (size_t)l*4096;
  int lane = threadIdx.x & 63;
  float wcol[64];
  #pragma unroll
  for (int j = 0; j < 64; ++j) wcol[j] = W[j*64 + lane];
  int wid = blockIdx.x*4 + (threadIdx.x >> 6);
  int nw  = gridDim.x*4;
  for (int n = wid; n < NN; n += nw){
    size_t base = (size_t)n*256;
    float x = in[base + (size_t)k*64 + lane];
    float a0 = 0.f, a1 = 0.f, a2 = 0.f, a3 = 0.f;
    #pragma unroll
    for (int j = 0; j < 64; j += 4){
      a0 = fmaf(rlane(x, j  ), wcol[j  ], a0);
      a1 = fmaf(rlane(x, j+1), wcol[j+1], a1);
      a2 = fmaf(rlane(x, j+2), wcol[j+2], a2);
      a3 = fmaf(rlane(x, j+3), wcol[j+3], a3);
    }
    out[base + (size_t)k*64 + lane] = (a0+a1) + (a2+a3);
  }
}

// ================= fused layer tail =================
__global__ __launch_bounds__(256) void k_tail(
    const float* __restrict__ nf_in, const float* __restrict__ msg,
    const float* __restrict__ Wsc, const float* __restrict__ Wprod, const float* __restrict__ wp,
    const float* __restrict__ we, const float* __restrict__ wd,
    float* __restrict__ nf_out, float* __restrict__ en, float* __restrict__ adp){
  int lane = threadIdx.x & 63;
  int k = threadIdx.x >> 6;
  int l = (k==0) ? 0 : 1;
  float wcs[64], wcp[64];
  #pragma unroll
  for (int j = 0; j < 64; ++j){
    wcs[j] = Wsc[(size_t)l*4096 + j*64 + lane];
    wcp[j] = Wprod[(size_t)l*4096 + j*64 + lane];
  }
  float p0 = wp[lane*3], p1 = wp[lane*3+1], p2 = wp[lane*3+2];
  float rw = (k==0) ? we[lane] : wd[lane];
  for (int n = blockIdx.x; n < NN; n += gridDim.x){
    size_t base = (size_t)n*256;
    float s0 = msg[base + lane];
    float xm = (k==0) ? s0 : msg[base + (size_t)k*64 + lane];
    float xg = xm * fmaf(fmaf(p2, s0, p1), s0, p0);
    float xs = nf_in[base + (size_t)k*64 + lane];
    float a0=0.f, a1=0.f, b0=0.f, b1=0.f;
    #pragma unroll
    for (int j = 0; j < 64; j += 2){
      a0 = fmaf(rlane(xs, j  ), wcs[j  ], a0);
      a1 = fmaf(rlane(xs, j+1), wcs[j+1], a1);
      b0 = fmaf(rlane(xg, j  ), wcp[j  ], b0);
      b1 = fmaf(rlane(xg, j+1), wcp[j+1], b1);
    }
    float out = (a0+a1) + (b0+b1);
    nf_out[base + (size_t)k*64 + lane] = out;
    float red = out * rw;
    #pragma unroll
    for (int o = 32; o; o >>= 1) red += __shfl_xor(red, o, 64);
    if (lane == 0){
      if (k == 0) en[n] = red;
      else        adp[n*3 + (k-1)] += red;
    }
  }
}

// ================= backward head =================
__global__ void k_bwd_head(const float* __restrict__ WPRODT1, const float* __restrict__ WSCT1,
                           const float* __restrict__ we1, const float* __restrict__ we0,
                           float* __restrict__ gvp, float* __restrict__ gnfc){
  int d = threadIdx.x;
  float a = 0.f, b = 0.f;
  #pragma unroll
  for (int c = 0; c < 64; ++c){
    float w = we1[c];
    a = fmaf(w, WPRODT1[c*64+d], a);
    b = fmaf(w, WSCT1[c*64+d], b);
  }
  gvp[d] = a;
  gnfc[d] = b + we0[d];
}

// ================= t=1 backward chain =================
__global__ __launch_bounds__(256) void k_gback1(
    const float* __restrict__ gvp, const float* __restrict__ msg1, const float* __restrict__ wp,
    const float* __restrict__ WMIXT1, float* __restrict__ out){
  int lane = threadIdx.x & 63;
  float wcol[64];
  #pragma unroll
  for (int j = 0; j < 64; ++j) wcol[j] = WMIXT1[j*64 + lane];
  float g = gvp[lane];
  float p0 = wp[lane*3], p1 = wp[lane*3+1], p2 = wp[lane*3+2];
  int wid = blockIdx.x*4 + (threadIdx.x >> 6);
  int nw  = gridDim.x*4;
  for (int n = wid; n < NN; n += nw){
    float s0 = msg1[(size_t)n*256 + lane];
    float poly = fmaf(fmaf(p2, s0, p1), s0, p0);
    float dp   = fmaf(2.f*p2, s0, p1);
    float gb = g*fmaf(s0, dp, poly);
    float a0=0.f, a1=0.f, a2=0.f, a3=0.f;
    #pragma unroll
    for (int j = 0; j < 64; j += 4){
      a0 = fmaf(rlane(gb, j  ), wcol[j  ], a0);
      a1 = fmaf(rlane(gb, j+1), wcol[j+1], a1);
      a2 = fmaf(rlane(gb, j+2), wcol[j+2], a2);
      a3 = fmaf(rlane(gb, j+3), wcol[j+3], a3);
    }
    out[(size_t)n*64 + lane] = (a0+a1) + (a2+a3);
  }
}

// ================= t=0 backward chain =================
__global__ __launch_bounds__(256) void k_gback0(
    const float* __restrict__ gnf0, const float* __restrict__ msg0, const float* __restrict__ wp,
    const float* __restrict__ WPRODT0, const float* __restrict__ WMIXT0,
    float* __restrict__ out){
  int lane = threadIdx.x & 63;
  float wcp[64], wcm[64];
  #pragma unroll
  for (int j = 0; j < 64; ++j){
    wcp[j] = WPRODT0[j*64 + lane];
    wcm[j] = WMIXT0[j*64 + lane];
  }
  float p0 = wp[lane*3], p1 = wp[lane*3+1], p2 = wp[lane*3+2];
  int wid = blockIdx.x*4 + (threadIdx.x >> 6);
  int nw  = gridDim.x*4;
  for (int n = wid; n < NN; n += nw){
    float x = gnf0[(size_t)n*64 + lane];
    float a0=0.f, a1=0.f;
    #pragma unroll
    for (int j = 0; j < 64; j += 2){
      a0 = fmaf(rlane(x, j  ), wcp[j  ], a0);
      a1 = fmaf(rlane(x, j+1), wcp[j+1], a1);
    }
    float gmp = a0+a1;
    float s0 = msg0[(size_t)n*256 + lane];
    float poly = fmaf(fmaf(p2, s0, p1), s0, p0);
    float dp   = fmaf(2.f*p2, s0, p1);
    float gb = gmp*fmaf(s0, dp, poly);
    float b0=0.f, b1=0.f;
    #pragma unroll
    for (int j = 0; j < 64; j += 2){
      b0 = fmaf(rlane(gb, j  ), wcm[j  ], b0);
      b1 = fmaf(rlane(gb, j+1), wcm[j+1], b1);
    }
    out[(size_t)n*64 + lane] = b0+b1;
  }
}

// ================= fused both-layer edge backward over LIVE list =================
// gvec_e = (rr0 + rr1) * u;  rr_t = sum_d TQ_t(L)[d] * nf_t[s][d] * gagg_t[r][d]/16
__global__ __launch_bounds__(256) void k_bwdE2(
    const float* __restrict__ TQ, const float* __restrict__ uvl,
    const float* __restrict__ nf0, const float* __restrict__ nf1,
    const float* __restrict__ ga0, const float* __restrict__ ga1,
    const int* __restrict__ ei, const int* __restrict__ lists,
    const int* __restrict__ nlive_ptr, float* __restrict__ gvec){
  int lane = threadIdx.x & 63;
  int wid = blockIdx.x*4 + (threadIdx.x >> 6);
  int nw  = gridDim.x*4;
  int nlive = nlive_ptr[0];
  for (int i = wid; i < nlive; i += nw){
    int e = __builtin_amdgcn_readfirstlane(lists[i]);
    int s = __builtin_amdgcn_readfirstlane(ei[e]);
    int r = __builtin_amdgcn_readfirstlane(ei[NE+e]);
    float L  = uvl[(size_t)e*4+3];
    float pos = L*(NB/5.f);
    int bi = (int)pos;
    float f = pos - (float)bi;
    const float* T0 = TQ + (size_t)bi*64 + lane;
    const float* T1 = T0 + (size_t)NB1*64;
    float Q0 = fmaf(T0[64]-T0[0], f, T0[0]);
    float Q1 = fmaf(T1[64]-T1[0], f, T1[0]);
    float rr = Q0*nf0[(size_t)s*256 + lane]*ga0[(size_t)r*64 + lane]
             + Q1*nf1[(size_t)s*256 + lane]*ga1[(size_t)r*64 + lane];
    rr *= (1.f/16.f);
    #pragma unroll
    for (int o = 32; o; o >>= 1) rr += __shfl_xor(rr, o, 64);
    if (lane < 3) gvec[(size_t)e*3 + lane] = rr*uvl[(size_t)e*4 + lane];
  }
}

// ================= gh gather via live sender CSR =================
__global__ __launch_bounds__(256) void k_ghgather0(
    const float* __restrict__ TW, const float* __restrict__ uvl, const float* __restrict__ gagg0,
    const int* __restrict__ ei, const int* __restrict__ offs_, const int* __restrict__ lists,
    const float* __restrict__ gnfc, float* __restrict__ out){
  int lane = threadIdx.x & 63;
  int wid = blockIdx.x*4 + (threadIdx.x >> 6);
  int nw  = gridDim.x*4;
  for (int n = wid; n < NN; n += nw){
    int lo = offs_[n], hi = offs_[n+1];
    float acc = 0.f;
    for (int i = lo; i < hi; ++i){
      int e = __builtin_amdgcn_readfirstlane(lists[i]);
      int r = __builtin_amdgcn_readfirstlane(ei[NE+e]);
      float L = uvl[(size_t)e*4+3];
      float pos = L*(NB/5.f);
      int bi = (int)pos;
      float f = pos - (float)bi;
      const float* T = TW + (size_t)bi*64 + lane;
      float w = fmaf(T[64]-T[0], f, T[0]);
      acc = fmaf(w, gagg0[(size_t)r*64 + lane], acc);
    }
    out[(size_t)n*64 + lane] = gnfc[lane] + acc*(1.f/16.f);
  }
}

// ================= force assembly: wave per node, lanes stride both lists =================
__global__ __launch_bounds__(256) void k_gposW(
    const float* __restrict__ gvec,
    const int* __restrict__ offr, const int* __restrict__ listr,
    const int* __restrict__ offs_, const int* __restrict__ lists,
    float* __restrict__ gpos){
  int lane = threadIdx.x & 63;
  int n = blockIdx.x*4 + (threadIdx.x >> 6);
  if (n >= NN) return;
  int lor = offr[n], nr = offr[n+1] - lor;
  int los = offs_[n], ns = offs_[n+1] - los;
  int tot = nr + ns;
  float ax = 0.f, ay = 0.f, az = 0.f;
  for (int i = lane; i < tot; i += 64){
    int e; float sgn;
    if (i < ns){ e = lists[los + i]; sgn = 1.f; }
    else       { e = listr[lor + i - ns]; sgn = -1.f; }
    ax = fmaf(sgn, gvec[(size_t)e*3],   ax);
    ay = fmaf(sgn, gvec[(size_t)e*3+1], ay);
    az = fmaf(sgn, gvec[(size_t)e*3+2], az);
  }
  #pragma unroll
  for (int o = 32; o; o >>= 1){
    ax += __shfl_xor(ax, o, 64); ay += __shfl_xor(ay, o, 64); az += __shfl_xor(az, o, 64);
  }
  if (lane == 0){
    gpos[n*3+0] = ax; gpos[n*3+1] = ay; gpos[n*3+2] = az;
  }
}

// ================= segmented final reduction (coalesced streaming) =================
__global__ void k_reduce(const float* __restrict__ e0n, const float* __restrict__ en0,
                         const float* __restrict__ en1, const float* __restrict__ adp,
                         const float* __restrict__ q, const float* __restrict__ pos,
                         const int* __restrict__ batch, float* __restrict__ e0g,
                         float* __restrict__ Etg, float* __restrict__ td){
  int n = blockIdx.x*256 + threadIdx.x;
  int lane = threadIdx.x & 63;
  bool valid = (n < NN);
  int g = valid ? batch[n] : -1;
  float v0=0.f, v1=0.f, v2=0.f, tx=0.f, ty=0.f, tz=0.f;
  if (valid){
    v0 = e0n[n]; v1 = en0[n]; v2 = en1[n];
    float qq = q[n];
    tx = adp[n*3+0] + qq*pos[n*3+0];
    ty = adp[n*3+1] + qq*pos[n*3+1];
    tz = adp[n*3+2] + qq*pos[n*3+2];
  }
  int g0 = __shfl(g, 0, 64), g63 = __shfl(g, 63, 64);
  if (g0 == g63 && g0 >= 0){
    #pragma unroll
    for (int o = 32; o; o >>= 1){
      v0 += __shfl_xor(v0, o, 64); v1 += __shfl_xor(v1, o, 64); v2 += __shfl_xor(v2, o, 64);
      tx += __shfl_xor(tx, o, 64); ty += __shfl_xor(ty, o, 64); tz += __shfl_xor(tz, o, 64);
    }
    if (lane == 0){
      atomicAdd(&e0g[g0], v0); atomicAdd(&Etg[g0], v1); atomicAdd(&Etg[16+g0], v2);
      atomicAdd(&td[g0*3+0], tx); atomicAdd(&td[g0*3+1], ty); atomicAdd(&td[g0*3+2], tz);
    }
  } else if (valid){
    atomicAdd(&e0g[g], v0); atomicAdd(&Etg[g], v1); atomicAdd(&Etg[16+g], v2);
    atomicAdd(&td[g*3+0], tx); atomicAdd(&td[g*3+1], ty); atomicAdd(&td[g*3+2], tz);
  }
}

__global__ void k_writeout(const float* __restrict__ e0g, const float* __restrict__ Etg,
                           const float* __restrict__ td, const float* __restrict__ adp,
                           const float* __restrict__ gpos, void* __restrict__ outv,
                           const int* __restrict__ flag){
  int i = blockIdx.x*256 + threadIdx.x;
  const int total = NG + NG*3 + NN*3 + NG*3 + NN*3; // 60112
  if (i >= total) return;
  float v;
  if (i < 16){
    v = e0g[i] + Etg[i] + Etg[16+i];
  } else if (i < 64){
    int j = i - 16; int g = j/3, t = j - g*3;
    v = (t == 0) ? e0g[g] : Etg[(t-1)*16 + g];
  } else if (i < 64 + NN*3){
    v = -gpos[i-64];
  } else if (i < 64 + NN*3 + 48){
    v = td[i - (64 + NN*3)];
  } else {
    v = adp[i - (64 + NN*3 + 48)];
  }
  if (flag[0]) ((__hip_bfloat16*)outv)[i] = __float2bfloat16(v);
  else         ((float*)outv)[i] = v;
}

extern "C" void kernel_launch(void* const* d_in, const int* in_sizes, int n_in,
                              void* d_out, int out_size, void* d_ws, size_t ws_size,
                              hipStream_t stream) {
  if (ws_size < WS_FLOATS*sizeof(float)) return; // ~79 MB
  const int* ei    = (const int*)d_in[14];
  const int* batch = (const int*)d_in[15];
  float* ws = (float*)d_ws;
  int* flag = (int*)(ws + O_FLAG);

  int* offr  = (int*)(ws + O_OFFR);
  int* offs_ = (int*)(ws + O_OFFS);
  int* curr  = (int*)(ws + O_CURR);
  int* curs  = (int*)(ws + O_CURS);
  int* listr = (int*)(ws + O_LISTR);
  int* lists = (int*)(ws + O_LISTS);

  hipMemsetAsync(ws + OFF_ACC, 0, ACC_FLOATS*sizeof(float), stream);
  hipMemsetAsync(curr, 0, 2*NN*sizeof(int), stream);
  k_detect<<<1, 256, 0, stream>>>((const unsigned*)d_in[1], flag);
  k_load_all<<<(LD_TOTAL+255)/256, 256, 0, stream>>>(
      d_in[0], d_in[1], d_in[2], d_in[3], d_in[4], d_in[5], d_in[6], d_in[7],
      d_in[8], d_in[9], d_in[10], d_in[11], d_in[12], d_in[13], ws, flag);
  k_transpose_all<<<288, 256, 0, stream>>>(ws);

  k_geom<<<(NE+255)/256, 256, 0, stream>>>(ws+OFF_PIN, ws+OFF_SHF, ei, ws+OFF_UVL, curr, curs);
  k_tables<<<(2*NB1+3)/4, 256, 0, stream>>>(ws+O_R1, ws+O_R2, ws+O_TW, ws+O_TQ);
  k_init_nodes<<<(NN+3)/4, 256, 0, stream>>>(ws+OFF_ATT, ws+O_WEMB, ws+O_AE, ws+OFF_NF0, ws+O_E0N);

  k_csr_scan<<<1, 256, 0, stream>>>(curr, curs, offr, offs_);
  k_csr_fill<<<(NE+255)/256, 256, 0, stream>>>(ei, ws+OFF_UVL, curr, curs, listr, lists);

  const size_t NF[3]  = {OFF_NF0, OFF_NF1, OFF_NF2};
  const size_t MSG[2] = {OFF_MSG0, OFF_MSG1};
  dim3 ling(256, 4);
  float* GA1 = ws + OFF_AGG;                        // t=1 gagg (kept)
  float* GB0 = ws + OFF_AGG + (size_t)NN*64;        // gnf t=0
  float* GA0 = ws + OFF_AGG + (size_t)2*NN*64;      // t=0 gagg

  // ---------- forward ----------
  for (int t = 0; t < NT; ++t){
    k_agg<<<1024, 256, 0, stream>>>(ws+O_TW + (size_t)t*NB1*64, ws+OFF_UVL,
                                    ws+NF[t], ei, offr, listr, ws+OFF_AGG);
    k_lin2<<<ling, 256, 0, stream>>>(ws+OFF_AGG, ws+O_WMIX + (size_t)t*12288, ws+MSG[t]);
    k_tail<<<1024, 256, 0, stream>>>(ws+NF[t], ws+MSG[t],
                                     ws+O_WSC + (size_t)t*12288, ws+O_WPROD + (size_t)t*12288,
                                     ws+O_WPOLY + (size_t)t*192, ws+O_WE + (size_t)t*64,
                                     ws+O_WD + (size_t)t*64,
                                     ws+NF[t+1], ws + (t ? O_EN1 : O_EN0), ws+O_ADP);
  }

  // ---------- backward (k=0 plane only) ----------
  k_bwd_head<<<1, 64, 0, stream>>>(ws+O_WPRODT+12288, ws+O_WSCT+12288, ws+O_WE+64, ws+O_WE,
                                   ws+O_GVP, ws+O_GNFC);
  k_gback1<<<1024, 256, 0, stream>>>(ws+O_GVP, ws+MSG[1], ws+O_WPOLY+192,
                                     ws+O_WMIXT+12288, GA1);
  k_ghgather0<<<1024, 256, 0, stream>>>(ws+O_TW + (size_t)NB1*64, ws+OFF_UVL, GA1, ei,
                                        offs_, lists, ws+O_GNFC, GB0);
  k_gback0<<<1024, 256, 0, stream>>>(GB0, ws+MSG[0], ws+O_WPOLY,
                                     ws+O_WPRODT, ws+O_WMIXT, GA0);
  k_bwdE2<<<2048, 256, 0, stream>>>(ws+O_TQ, ws+OFF_UVL,
                                    ws+NF[0], ws+NF[1], GA0, GA1,
                                    ei, lists, offs_ + NN, ws+O_GVEC);

  k_gposW<<<(NN+3)/4, 256, 0, stream>>>(ws+O_GVEC, offr, listr, offs_, lists, ws+O_GPOS);
  k_reduce<<<(NN+255)/256, 256, 0, stream>>>(ws+O_E0N, ws+O_EN0, ws+O_EN1, ws+O_ADP,
                                             ws+OFF_CHG, ws+OFF_PIN, batch,
                                             ws+O_E0G, ws+O_ETG, ws+O_TD);
  k_writeout<<<(60112+255)/256, 256, 0, stream>>>(ws+O_E0G, ws+O_ETG, ws+O_TD, ws+O_ADP, ws+O_GPOS, d_out, flag);
}

// Round 13
// 409.794 us; speedup vs baseline: 2.7233x; 1.0051x over previous
//
#include <hip/hip_runtime.h>
#include <hip/hip_bf16.h>

#define NN 10000
#define NE 160000
#define NZ 10
#define NC 64
#define NBES 8
#define NG 16
#define NT 2
#define NB 2048
#define NB1 2049
#define PL ((size_t)NN*64)   // plane stride (plane-major node tensors)

static constexpr float PI_F  = 3.14159265358979323846f;
static constexpr float KBES  = 0.63245553203367587f;  // sqrt(2/5)
static constexpr float S3    = 1.73205080756887729f;

// ---- workspace layout (float offsets); node tensors PLANE-MAJOR [k][n][64] ----
static constexpr size_t OFF_UVL  = 0;                        // NE*4 : (ux,uy,uz,L)
static constexpr size_t OFF_PIN  = OFF_UVL + (size_t)NE*4;
static constexpr size_t OFF_ATT  = OFF_PIN + (size_t)NN*3;
static constexpr size_t OFF_CHG  = OFF_ATT + (size_t)NN*NZ;
static constexpr size_t OFF_SHF  = OFF_CHG + (size_t)NN;
static constexpr size_t OFF_NF0  = OFF_SHF + (size_t)NE*3;   // 4 planes
static constexpr size_t OFF_NF1  = OFF_NF0 + 4*PL;
static constexpr size_t OFF_MSG0 = OFF_NF1 + 4*PL;
static constexpr size_t OFF_MSG1 = OFF_MSG0+ 4*PL;
static constexpr size_t OFF_AGG  = OFF_MSG1+ 4*PL;           // fwd agg; bwd GA1/GB0/GA0
static constexpr size_t OFF_W    = OFF_AGG + 4*PL;
static constexpr size_t O_WEMB   = OFF_W;
static constexpr size_t O_AE     = O_WEMB + 640;
static constexpr size_t O_R1     = O_AE   + 16;
static constexpr size_t O_R2     = O_R1   + 1024;
static constexpr size_t O_WMIX   = O_R2   + 8192;
static constexpr size_t O_WMIXT  = O_WMIX + 24576;
static constexpr size_t O_WSC    = O_WMIXT+ 24576;
static constexpr size_t O_WSCT   = O_WSC  + 24576;
static constexpr size_t O_WPROD  = O_WSCT + 24576;
static constexpr size_t O_WPRODT = O_WPROD+ 24576;
static constexpr size_t O_WPOLY  = O_WPRODT+24576;
static constexpr size_t O_WE     = O_WPOLY+ 384;
static constexpr size_t O_WD     = O_WE   + 128;
static constexpr size_t OFF_ACC  = O_WD   + 128;             // zeroed region start
static constexpr size_t O_E0G    = OFF_ACC;
static constexpr size_t O_ETG    = O_E0G + 16;
static constexpr size_t O_TD     = O_ETG + 32;
static constexpr size_t O_ADP    = O_TD  + 48;
static constexpr size_t ACC_FLOATS = 96 + (size_t)NN*3;      // e0g..adp
static constexpr size_t O_GPOS   = O_ADP + (size_t)NN*3;
static constexpr size_t O_EN0    = O_GPOS + (size_t)NN*3;
static constexpr size_t O_EN1    = O_EN0 + NN;
static constexpr size_t O_E0N    = O_EN1 + NN;
static constexpr size_t O_GVEC   = O_E0N + NN;               // per-edge dE/dvec (live only)
static constexpr size_t O_FLAG   = O_GVEC + (size_t)NE*3;
static constexpr size_t O_GVP    = O_FLAG + 4;
static constexpr size_t O_GNFC   = O_GVP + 64;
static constexpr size_t O_TW     = O_GNFC + 64;              // 2 layers x NB1 x 64
static constexpr size_t O_TQ     = O_TW + (size_t)2*NB1*64;
static constexpr size_t O_OFFR   = O_TQ + (size_t)2*NB1*64;  // ints from here
static constexpr size_t O_OFFS   = O_OFFR + (NN+1);
static constexpr size_t O_CURR   = O_OFFS + (NN+1);
static constexpr size_t O_CURS   = O_CURR + NN;
static constexpr size_t O_LISTR  = O_CURS + NN;
static constexpr size_t O_LISTS  = O_LISTR + (size_t)NE;
static constexpr size_t WS_FLOATS= O_LISTS + (size_t)NE;     // ~66 MB

__device__ __forceinline__ float rlane(float v, int l){
  return __int_as_float(__builtin_amdgcn_readlane(__float_as_int(v), l));
}

// ---------- dtype detection ----------
__global__ void k_detect(const unsigned* __restrict__ raw, int* __restrict__ flag){
  __shared__ int found;
  if (threadIdx.x == 0) found = 0;
  __syncthreads();
  for (int i = threadIdx.x; i < 4096; i += 256){
    unsigned w = raw[i];
    if (w == 0x00003F80u || w == 0x3F803F80u) found = 1;
  }
  __syncthreads();
  if (threadIdx.x == 0) flag[0] = found;
}

// ---------- fused loader ----------
static constexpr int LD_CNT[14] = {NN*3, NN*NZ, NN, NE*3, NZ*64, NZ, NT*NBES*64, NT*64*64,
                                   NT*3*64*64, NT*3*64*64, NT*64*3, NT*3*64*64, NT*64, NT*64};
static constexpr int LD_TOTAL = NN*3 + NN*NZ + NN + NE*3 + NZ*64 + NZ + NT*NBES*64 + NT*64*64
                              + 3*(NT*3*64*64) + NT*64*3 + 4*(NT*64) - NT*64*2;
__global__ __launch_bounds__(256) void k_load_all(
    const void* s0, const void* s1, const void* s2, const void* s3, const void* s4,
    const void* s5, const void* s6, const void* s7, const void* s8, const void* s9,
    const void* s10, const void* s11, const void* s12, const void* s13,
    float* __restrict__ ws, const int* __restrict__ flag){
  const void* srcs[14] = {s0,s1,s2,s3,s4,s5,s6,s7,s8,s9,s10,s11,s12,s13};
  const size_t dsts[14] = {OFF_PIN, OFF_ATT, OFF_CHG, OFF_SHF, O_WEMB, O_AE, O_R1, O_R2,
                           O_WMIX, O_WSC, O_WPOLY, O_WPROD, O_WE, O_WD};
  int i = blockIdx.x*256 + threadIdx.x;
  int seg = -1, off = i;
  #pragma unroll
  for (int j = 0; j < 14; ++j){
    if (seg < 0){
      if (off < LD_CNT[j]) seg = j;
      else off -= LD_CNT[j];
    }
  }
  if (seg < 0) return;
  float v = flag[0] ? __bfloat162float(((const __hip_bfloat16*)srcs[seg])[off])
                    : ((const float*)srcs[seg])[off];
  ws[dsts[seg] + off] = v;
}

// ---------- fused transposes ----------
__global__ void k_transpose_all(float* __restrict__ ws){
  const size_t srcs[3] = {O_WMIX, O_WSC, O_WPROD};
  const size_t dsts[3] = {O_WMIXT, O_WSCT, O_WPRODT};
  int i = blockIdx.x*256 + threadIdx.x;
  if (i >= 18*4096) return;
  int mm = i >> 12, r = (i >> 6) & 63, c = i & 63;
  int grp = mm / 6, m = mm % 6;
  ws[dsts[grp] + (size_t)m*4096 + (size_t)c*64 + r] =
      ws[srcs[grp] + (size_t)m*4096 + (size_t)r*64 + c];
}

// ---------- edge geometry + live-edge counting ----------
__global__ void k_geom(const float* __restrict__ pos, const float* __restrict__ shifts,
                       const int* __restrict__ ei, float* __restrict__ uvl,
                       int* __restrict__ cntr, int* __restrict__ cnts){
  int e = blockIdx.x*256 + threadIdx.x;
  if (e >= NE) return;
  int s = ei[e], r = ei[NE + e];
  float vx = pos[s*3+0] - pos[r*3+0] + shifts[(size_t)e*3+0];
  float vy = pos[s*3+1] - pos[r*3+1] + shifts[(size_t)e*3+1];
  float vz = pos[s*3+2] - pos[r*3+2] + shifts[(size_t)e*3+2];
  float L = sqrtf(vx*vx + vy*vy + vz*vz + 1e-12f);
  float inv = 1.f / L;
  uvl[(size_t)e*4+0] = vx*inv; uvl[(size_t)e*4+1] = vy*inv;
  uvl[(size_t)e*4+2] = vz*inv; uvl[(size_t)e*4+3] = L;
  if (L < 5.f){
    atomicAdd(&cntr[r], 1);
    atomicAdd(&cnts[s], 1);
  }
}

// ---------- radial tables ----------
__global__ __launch_bounds__(256) void k_tables(
    const float* __restrict__ R1all, const float* __restrict__ R2all,
    float* __restrict__ TW, float* __restrict__ TQ){
  int lane = threadIdx.x & 63;
  int task = blockIdx.x*4 + (threadIdx.x >> 6);
  if (task >= 2*NB1) return;
  int t = task / NB1, node = task % NB1;
  const float* R1 = R1all + (size_t)t*512;
  const float* R2 = R2all + (size_t)t*4096;
  float r1c[8];
  #pragma unroll
  for (int j = 0; j < 8; ++j) r1c[j] = R1[j*64 + lane];
  float L = fmaxf((float)node * (5.f/NB), 1e-6f);
  float ur = L*0.2f;
  float ef[8], dd[8];
  if (ur < 1.f){
    float u2=ur*ur, u4=u2*u2, u5=u4*ur;
    float fc = 1.f - 21.f*u5 + 35.f*u5*ur - 15.f*u5*u2;
    float omu = 1.f - ur;
    float dfc = -105.f*u4*omu*omu;
    float invr = 1.f/(L + 1e-9f);
    #pragma unroll
    for (int b = 0; b < 8; ++b){
      float nb = (float)(b+1);
      float arg = nb*PI_F*ur;
      float sn = __sinf(arg), cs = __cosf(arg);
      float bes = KBES*sn*invr;
      float dbes = KBES*(nb*PI_F*0.2f)*cs*invr - bes*invr;
      ef[b] = bes*fc;
      dd[b] = dbes*fc + bes*dfc*0.2f;
    }
  } else {
    #pragma unroll
    for (int b = 0; b < 8; ++b){ ef[b] = 0.f; dd[b] = 0.f; }
  }
  float a = 0.f, tt = 0.f;
  #pragma unroll
  for (int b = 0; b < 8; ++b){ a = fmaf(ef[b], r1c[b], a); tt = fmaf(r1c[b], dd[b], tt); }
  float sg = 1.f/(1.f + __expf(-a));
  float sl = a*sg;
  float q  = sg*fmaf(a, 1.f - sg, 1.f)*tt;
  float r2c[64];
  #pragma unroll
  for (int j = 0; j < 64; ++j) r2c[j] = R2[j*64 + lane];
  float W0=0.f, W1=0.f, Q0=0.f, Q1=0.f;
  #pragma unroll
  for (int j = 0; j < 64; j += 2){
    W0 = fmaf(rlane(sl, j  ), r2c[j  ], W0);
    W1 = fmaf(rlane(sl, j+1), r2c[j+1], W1);
    Q0 = fmaf(rlane(q,  j  ), r2c[j  ], Q0);
    Q1 = fmaf(rlane(q,  j+1), r2c[j+1], Q1);
  }
  size_t idx = ((size_t)t*NB1 + node)*64 + lane;
  TW[idx] = W0+W1;
  TQ[idx] = Q0+Q1;
}

// ---------- node init (plane-major) ----------
__global__ __launch_bounds__(256) void k_init_nodes(
    const float* __restrict__ attrs, const float* __restrict__ Wemb,
    const float* __restrict__ ae, float* __restrict__ nf0, float* __restrict__ e0n){
  int lane = threadIdx.x & 63;
  int n = blockIdx.x*4 + (threadIdx.x >> 6);
  if (n >= NN) return;
  float acc = 0.f;
  #pragma unroll
  for (int z = 0; z < NZ; ++z) acc = fmaf(attrs[(size_t)n*NZ+z], Wemb[z*64+lane], acc);
  size_t base = (size_t)n*64 + lane;
  nf0[base] = acc;
  #pragma unroll
  for (int k = 1; k < 4; ++k) nf0[base + (size_t)k*PL] = 0.f;
  if (lane == 0){
    float e = 0.f;
    #pragma unroll
    for (int z = 0; z < NZ; ++z) e = fmaf(attrs[(size_t)n*NZ+z], ae[z], e);
    e0n[n] = e;
  }
}

// ================= LDS-staged prefix scan =================
__global__ __launch_bounds__(256) void k_csr_scan(
    int* __restrict__ cntr, int* __restrict__ cnts,
    int* __restrict__ offr, int* __restrict__ offs_){
  __shared__ int lds[NN];
  __shared__ int part[256];
  for (int q = 0; q < 2; ++q){
    int* c   = q ? cnts  : cntr;
    int* off = q ? offs_ : offr;
    for (int i = threadIdx.x; i < NN; i += 256) lds[i] = c[i];
    __syncthreads();
    const int chunk = (NN + 255)/256;
    int lo = threadIdx.x*chunk, hi = lo+chunk; if (hi > NN) hi = NN; if (lo > NN) lo = NN;
    int s = 0;
    for (int i = lo; i < hi; ++i) s += lds[i];
    part[threadIdx.x] = s;
    __syncthreads();
    for (int o = 1; o < 256; o <<= 1){
      int v = (threadIdx.x >= o) ? part[threadIdx.x-o] : 0;
      __syncthreads();
      part[threadIdx.x] += v;
      __syncthreads();
    }
    int run = (threadIdx.x == 0) ? 0 : part[threadIdx.x-1];
    for (int i = lo; i < hi; ++i){
      int ci = lds[i];
      off[i] = run; c[i] = run;
      run += ci;
    }
    if (threadIdx.x == 255) off[NN] = run;
    __syncthreads();
  }
}

// ---------- fill: live edges only ----------
__global__ void k_csr_fill(const int* __restrict__ ei, const float* __restrict__ uvl,
                           int* __restrict__ curr, int* __restrict__ curs,
                           int* __restrict__ listr, int* __restrict__ lists){
  int e = blockIdx.x*256 + threadIdx.x;
  if (e >= NE) return;
  if (uvl[(size_t)e*4+3] >= 5.f) return;
  int pr = atomicAdd(&curr[ei[NE+e]], 1); listr[pr] = e;
  int ps = atomicAdd(&curs[ei[e]], 1);    lists[ps] = e;
}

// ================= aggregation via live receiver CSR (plane-major out) =================
__global__ __launch_bounds__(256) void k_agg(
    const float* __restrict__ TW, const float* __restrict__ uvl,
    const float* __restrict__ h0, const int* __restrict__ ei,
    const int* __restrict__ offr, const int* __restrict__ listr,
    float* __restrict__ agg){
  int lane = threadIdx.x & 63;
  int wid = blockIdx.x*4 + (threadIdx.x >> 6);
  int nw  = gridDim.x*4;
  for (int n = wid; n < NN; n += nw){
    int lo = offr[n], hi = offr[n+1];
    float acc0=0.f, acc1=0.f, acc2=0.f, acc3=0.f;
    for (int i = lo; i < hi; ++i){
      int e = __builtin_amdgcn_readfirstlane(listr[i]);
      int s = __builtin_amdgcn_readfirstlane(ei[e]);
      float ux = uvl[(size_t)e*4], uy = uvl[(size_t)e*4+1], uz = uvl[(size_t)e*4+2];
      float L  = uvl[(size_t)e*4+3];
      float pos = L*(NB/5.f);
      int bi = (int)pos;
      float f = pos - (float)bi;
      const float* T = TW + (size_t)bi*64 + lane;
      float w = fmaf(T[64]-T[0], f, T[0]);
      float wh = w * h0[(size_t)s*64 + lane];     // plane-0 slab, L2-resident
      acc0 += wh;
      acc1 = fmaf(wh, S3*ux, acc1);
      acc2 = fmaf(wh, S3*uy, acc2);
      acc3 = fmaf(wh, S3*uz, acc3);
    }
    size_t ob = (size_t)n*64 + lane;
    agg[ob]        = acc0*(1.f/16.f);
    agg[ob+PL]     = acc1*(1.f/16.f);
    agg[ob+2*PL]   = acc2*(1.f/16.f);
    agg[ob+3*PL]   = acc3*(1.f/16.f);
  }
}

// ================= per-l linear (mix), plane-major =================
__global__ __launch_bounds__(256) void k_lin2(
    const float* __restrict__ in, const float* __restrict__ W3, float* __restrict__ out){
  int k = blockIdx.y;
  int l = (k==0) ? 0 : 1;
  const float* W = W3 + (size_t)l*4096;
  int lane = threadIdx.x & 63;
  float wcol[64];
  #pragma unroll
  for (int j = 0; j < 64; ++j) wcol[j] = W[j*64 + lane];
  int wid = blockIdx.x*4 + (threadIdx.x >> 6);
  int nw  = gridDim.x*4;
  const float* inp = in + (size_t)k*PL;
  float* outp = out + (size_t)k*PL;
  for (int n = wid; n < NN; n += nw){
    float x = inp[(size_t)n*64 + lane];
    float a0 = 0.f, a1 = 0.f, a2 = 0.f, a3 = 0.f;
    #pragma unroll
    for (int j = 0; j < 64; j += 4){
      a0 = fmaf(rlane(x, j  ), wcol[j  ], a0);
      a1 = fmaf(rlane(x, j+1), wcol[j+1], a1);
      a2 = fmaf(rlane(x, j+2), wcol[j+2], a2);
      a3 = fmaf(rlane(x, j+3), wcol[j+3], a3);
    }
    outp[(size_t)n*64 + lane] = (a0+a1) + (a2+a3);
  }
}

// ================= fused layer tail (plane-major; optional nf_out write) =================
__global__ __launch_bounds__(256) void k_tail(
    const float* __restrict__ nf_in, const float* __restrict__ msg,
    const float* __restrict__ Wsc, const float* __restrict__ Wprod, const float* __restrict__ wp,
    const float* __restrict__ we, const float* __restrict__ wd,
    float* __restrict__ nf_out, float* __restrict__ en, float* __restrict__ adp, int write_nf){
  int lane = threadIdx.x & 63;
  int k = threadIdx.x >> 6;
  int l = (k==0) ? 0 : 1;
  float wcs[64], wcp[64];
  #pragma unroll
  for (int j = 0; j < 64; ++j){
    wcs[j] = Wsc[(size_t)l*4096 + j*64 + lane];
    wcp[j] = Wprod[(size_t)l*4096 + j*64 + lane];
  }
  float p0 = wp[lane*3], p1 = wp[lane*3+1], p2 = wp[lane*3+2];
  float rw = (k==0) ? we[lane] : wd[lane];
  const float* msgk = msg + (size_t)k*PL;
  const float* nfk  = nf_in + (size_t)k*PL;
  float* outk = nf_out + (size_t)k*PL;
  for (int n = blockIdx.x; n < NN; n += gridDim.x){
    size_t base = (size_t)n*64 + lane;
    float s0 = msg[base];
    float xm = (k==0) ? s0 : msgk[base];
    float xg = xm * fmaf(fmaf(p2, s0, p1), s0, p0);
    float xs = nfk[base];
    float a0=0.f, a1=0.f, b0=0.f, b1=0.f;
    #pragma unroll
    for (int j = 0; j < 64; j += 2){
      a0 = fmaf(rlane(xs, j  ), wcs[j  ], a0);
      a1 = fmaf(rlane(xs, j+1), wcs[j+1], a1);
      b0 = fmaf(rlane(xg, j  ), wcp[j  ], b0);
      b1 = fmaf(rlane(xg, j+1), wcp[j+1], b1);
    }
    float out = (a0+a1) + (b0+b1);
    if (write_nf) outk[base] = out;
    float red = out * rw;
    #pragma unroll
    for (int o = 32; o; o >>= 1) red += __shfl_xor(red, o, 64);
    if (lane == 0){
      if (k == 0) en[n] = red;
      else        adp[n*3 + (k-1)] += red;
    }
  }
}

// ================= backward head =================
__global__ void k_bwd_head(const float* __restrict__ WPRODT1, const float* __restrict__ WSCT1,
                           const float* __restrict__ we1, const float* __restrict__ we0,
                           float* __restrict__ gvp, float* __restrict__ gnfc){
  int d = threadIdx.x;
  float a = 0.f, b = 0.f;
  #pragma unroll
  for (int c = 0; c < 64; ++c){
    float w = we1[c];
    a = fmaf(w, WPRODT1[c*64+d], a);
    b = fmaf(w, WSCT1[c*64+d], b);
  }
  gvp[d] = a;
  gnfc[d] = b + we0[d];
}

// ================= t=1 backward chain =================
__global__ __launch_bounds__(256) void k_gback1(
    const float* __restrict__ gvp, const float* __restrict__ msg1, const float* __restrict__ wp,
    const float* __restrict__ WMIXT1, float* __restrict__ out){
  int lane = threadIdx.x & 63;
  float wcol[64];
  #pragma unroll
  for (int j = 0; j < 64; ++j) wcol[j] = WMIXT1[j*64 + lane];
  float g = gvp[lane];
  float p0 = wp[lane*3], p1 = wp[lane*3+1], p2 = wp[lane*3+2];
  int wid = blockIdx.x*4 + (threadIdx.x >> 6);
  int nw  = gridDim.x*4;
  for (int n = wid; n < NN; n += nw){
    float s0 = msg1[(size_t)n*64 + lane];       // plane 0
    float poly = fmaf(fmaf(p2, s0, p1), s0, p0);
    float dp   = fmaf(2.f*p2, s0, p1);
    float gb = g*fmaf(s0, dp, poly);
    float a0=0.f, a1=0.f, a2=0.f, a3=0.f;
    #pragma unroll
    for (int j = 0; j < 64; j += 4){
      a0 = fmaf(rlane(gb, j  ), wcol[j  ], a0);
      a1 = fmaf(rlane(gb, j+1), wcol[j+1], a1);
      a2 = fmaf(rlane(gb, j+2), wcol[j+2], a2);
      a3 = fmaf(rlane(gb, j+3), wcol[j+3], a3);
    }
    out[(size_t)n*64 + lane] = (a0+a1) + (a2+a3);
  }
}

// ================= t=0 backward chain =================
__global__ __launch_bounds__(256) void k_gback0(
    const float* __restrict__ gnf0, const float* __restrict__ msg0, const float* __restrict__ wp,
    const float* __restrict__ WPRODT0, const float* __restrict__ WMIXT0,
    float* __restrict__ out){
  int lane = threadIdx.x & 63;
  float wcp[64], wcm[64];
  #pragma unroll
  for (int j = 0; j < 64; ++j){
    wcp[j] = WPRODT0[j*64 + lane];
    wcm[j] = WMIXT0[j*64 + lane];
  }
  float p0 = wp[lane*3], p1 = wp[lane*3+1], p2 = wp[lane*3+2];
  int wid = blockIdx.x*4 + (threadIdx.x >> 6);
  int nw  = gridDim.x*4;
  for (int n = wid; n < NN; n += nw){
    float x = gnf0[(size_t)n*64 + lane];
    float a0=0.f, a1=0.f;
    #pragma unroll
    for (int j = 0; j < 64; j += 2){
      a0 = fmaf(rlane(x, j  ), wcp[j  ], a0);
      a1 = fmaf(rlane(x, j+1), wcp[j+1], a1);
    }
    float gmp = a0+a1;
    float s0 = msg0[(size_t)n*64 + lane];       // plane 0
    float poly = fmaf(fmaf(p2, s0, p1), s0, p0);
    float dp   = fmaf(2.f*p2, s0, p1);
    float gb = gmp*fmaf(s0, dp, poly);
    float b0=0.f, b1=0.f;
    #pragma unroll
    for (int j = 0; j < 64; j += 2){
      b0 = fmaf(rlane(gb, j  ), wcm[j  ], b0);
      b1 = fmaf(rlane(gb, j+1), wcm[j+1], b1);
    }
    out[(size_t)n*64 + lane] = b0+b1;
  }
}

// ================= fused both-layer edge backward over LIVE list =================
__global__ __launch_bounds__(256) void k_bwdE2(
    const float* __restrict__ TQ, const float* __restrict__ uvl,
    const float* __restrict__ h0, const float* __restrict__ h1,
    const float* __restrict__ ga0, const float* __restrict__ ga1,
    const int* __restrict__ ei, const int* __restrict__ lists,
    const int* __restrict__ nlive_ptr, float* __restrict__ gvec){
  int lane = threadIdx.x & 63;
  int wid = blockIdx.x*4 + (threadIdx.x >> 6);
  int nw  = gridDim.x*4;
  int nlive = nlive_ptr[0];
  for (int i = wid; i < nlive; i += nw){
    int e = __builtin_amdgcn_readfirstlane(lists[i]);
    int s = __builtin_amdgcn_readfirstlane(ei[e]);
    int r = __builtin_amdgcn_readfirstlane(ei[NE+e]);
    float L  = uvl[(size_t)e*4+3];
    float pos = L*(NB/5.f);
    int bi = (int)pos;
    float f = pos - (float)bi;
    const float* T0 = TQ + (size_t)bi*64 + lane;
    const float* T1 = T0 + (size_t)NB1*64;
    float Q0 = fmaf(T0[64]-T0[0], f, T0[0]);
    float Q1 = fmaf(T1[64]-T1[0], f, T1[0]);
    float rr = Q0*h0[(size_t)s*64 + lane]*ga0[(size_t)r*64 + lane]
             + Q1*h1[(size_t)s*64 + lane]*ga1[(size_t)r*64 + lane];
    rr *= (1.f/16.f);
    #pragma unroll
    for (int o = 32; o; o >>= 1) rr += __shfl_xor(rr, o, 64);
    if (lane < 3) gvec[(size_t)e*3 + lane] = rr*uvl[(size_t)e*4 + lane];
  }
}

// ================= gh gather via live sender CSR =================
__global__ __launch_bounds__(256) void k_ghgather0(
    const float* __restrict__ TW, const float* __restrict__ uvl, const float* __restrict__ gagg0,
    const int* __restrict__ ei, const int* __restrict__ offs_, const int* __restrict__ lists,
    const float* __restrict__ gnfc, float* __restrict__ out){
  int lane = threadIdx.x & 63;
  int wid = blockIdx.x*4 + (threadIdx.x >> 6);
  int nw  = gridDim.x*4;
  for (int n = wid; n < NN; n += nw){
    int lo = offs_[n], hi = offs_[n+1];
    float acc = 0.f;
    for (int i = lo; i < hi; ++i){
      int e = __builtin_amdgcn_readfirstlane(lists[i]);
      int r = __builtin_amdgcn_readfirstlane(ei[NE+e]);
      float L = uvl[(size_t)e*4+3];
      float pos = L*(NB/5.f);
      int bi = (int)pos;
      float f = pos - (float)bi;
      const float* T = TW + (size_t)bi*64 + lane;
      float w = fmaf(T[64]-T[0], f, T[0]);
      acc = fmaf(w, gagg0[(size_t)r*64 + lane], acc);
    }
    out[(size_t)n*64 + lane] = gnfc[lane] + acc*(1.f/16.f);
  }
}

// ================= force assembly: wave per node =================
__global__ __launch_bounds__(256) void k_gposW(
    const float* __restrict__ gvec,
    const int* __restrict__ offr, const int* __restrict__ listr,
    const int* __restrict__ offs_, const int* __restrict__ lists,
    float* __restrict__ gpos){
  int lane = threadIdx.x & 63;
  int n = blockIdx.x*4 + (threadIdx.x >> 6);
  if (n >= NN) return;
  int lor = offr[n], nr = offr[n+1] - lor;
  int los = offs_[n], ns = offs_[n+1] - los;
  int tot = nr + ns;
  float ax = 0.f, ay = 0.f, az = 0.f;
  for (int i = lane; i < tot; i += 64){
    int e; float sgn;
    if (i < ns){ e = lists[los + i]; sgn = 1.f; }
    else       { e = listr[lor + i - ns]; sgn = -1.f; }
    ax = fmaf(sgn, gvec[(size_t)e*3],   ax);
    ay = fmaf(sgn, gvec[(size_t)e*3+1], ay);
    az = fmaf(sgn, gvec[(size_t)e*3+2], az);
  }
  #pragma unroll
  for (int o = 32; o; o >>= 1){
    ax += __shfl_xor(ax, o, 64); ay += __shfl_xor(ay, o, 64); az += __shfl_xor(az, o, 64);
  }
  if (lane == 0){
    gpos[n*3+0] = ax; gpos[n*3+1] = ay; gpos[n*3+2] = az;
  }
}

// ================= segmented final reduction =================
__global__ void k_reduce(const float* __restrict__ e0n, const float* __restrict__ en0,
                         const float* __restrict__ en1, const float* __restrict__ adp,
                         const float* __restrict__ q, const float* __restrict__ pos,
                         const int* __restrict__ batch, float* __restrict__ e0g,
                         float* __restrict__ Etg, float* __restrict__ td){
  int n = blockIdx.x*256 + threadIdx.x;
  int lane = threadIdx.x & 63;
  bool valid = (n < NN);
  int g = valid ? batch[n] : -1;
  float v0=0.f, v1=0.f, v2=0.f, tx=0.f, ty=0.f, tz=0.f;
  if (valid){
    v0 = e0n[n]; v1 = en0[n]; v2 = en1[n];
    float qq = q[n];
    tx = adp[n*3+0] + qq*pos[n*3+0];
    ty = adp[n*3+1] + qq*pos[n*3+1];
    tz = adp[n*3+2] + qq*pos[n*3+2];
  }
  int g0 = __shfl(g, 0, 64), g63 = __shfl(g, 63, 64);
  if (g0 == g63 && g0 >= 0){
    #pragma unroll
    for (int o = 32; o; o >>= 1){
      v0 += __shfl_xor(v0, o, 64); v1 += __shfl_xor(v1, o, 64); v2 += __shfl_xor(v2, o, 64);
      tx += __shfl_xor(tx, o, 64); ty += __shfl_xor(ty, o, 64); tz += __shfl_xor(tz, o, 64);
    }
    if (lane == 0){
      atomicAdd(&e0g[g0], v0); atomicAdd(&Etg[g0], v1); atomicAdd(&Etg[16+g0], v2);
      atomicAdd(&td[g0*3+0], tx); atomicAdd(&td[g0*3+1], ty); atomicAdd(&td[g0*3+2], tz);
    }
  } else if (valid){
    atomicAdd(&e0g[g], v0); atomicAdd(&Etg[g], v1); atomicAdd(&Etg[16+g], v2);
    atomicAdd(&td[g*3+0], tx); atomicAdd(&td[g*3+1], ty); atomicAdd(&td[g*3+2], tz);
  }
}

__global__ void k_writeout(const float* __restrict__ e0g, const float* __restrict__ Etg,
                           const float* __restrict__ td, const float* __restrict__ adp,
                           const float* __restrict__ gpos, void* __restrict__ outv,
                           const int* __restrict__ flag){
  int i = blockIdx.x*256 + threadIdx.x;
  const int total = NG + NG*3 + NN*3 + NG*3 + NN*3; // 60112
  if (i >= total) return;
  float v;
  if (i < 16){
    v = e0g[i] + Etg[i] + Etg[16+i];
  } else if (i < 64){
    int j = i - 16; int g = j/3, t = j - g*3;
    v = (t == 0) ? e0g[g] : Etg[(t-1)*16 + g];
  } else if (i < 64 + NN*3){
    v = -gpos[i-64];
  } else if (i < 64 + NN*3 + 48){
    v = td[i - (64 + NN*3)];
  } else {
    v = adp[i - (64 + NN*3 + 48)];
  }
  if (flag[0]) ((__hip_bfloat16*)outv)[i] = __float2bfloat16(v);
  else         ((float*)outv)[i] = v;
}

extern "C" void kernel_launch(void* const* d_in, const int* in_sizes, int n_in,
                              void* d_out, int out_size, void* d_ws, size_t ws_size,
                              hipStream_t stream) {
  if (ws_size < WS_FLOATS*sizeof(float)) return; // ~66 MB
  const int* ei    = (const int*)d_in[14];
  const int* batch = (const int*)d_in[15];
  float* ws = (float*)d_ws;
  int* flag = (int*)(ws + O_FLAG);

  int* offr  = (int*)(ws + O_OFFR);
  int* offs_ = (int*)(ws + O_OFFS);
  int* curr  = (int*)(ws + O_CURR);
  int* curs  = (int*)(ws + O_CURS);
  int* listr = (int*)(ws + O_LISTR);
  int* lists = (int*)(ws + O_LISTS);

  hipMemsetAsync(ws + OFF_ACC, 0, ACC_FLOATS*sizeof(float), stream);
  hipMemsetAsync(curr, 0, 2*NN*sizeof(int), stream);
  k_detect<<<1, 256, 0, stream>>>((const unsigned*)d_in[1], flag);
  k_load_all<<<(LD_TOTAL+255)/256, 256, 0, stream>>>(
      d_in[0], d_in[1], d_in[2], d_in[3], d_in[4], d_in[5], d_in[6], d_in[7],
      d_in[8], d_in[9], d_in[10], d_in[11], d_in[12], d_in[13], ws, flag);
  k_transpose_all<<<288, 256, 0, stream>>>(ws);

  k_geom<<<(NE+255)/256, 256, 0, stream>>>(ws+OFF_PIN, ws+OFF_SHF, ei, ws+OFF_UVL, curr, curs);
  k_tables<<<(2*NB1+3)/4, 256, 0, stream>>>(ws+O_R1, ws+O_R2, ws+O_TW, ws+O_TQ);
  k_init_nodes<<<(NN+3)/4, 256, 0, stream>>>(ws+OFF_ATT, ws+O_WEMB, ws+O_AE, ws+OFF_NF0, ws+O_E0N);

  k_csr_scan<<<1, 256, 0, stream>>>(curr, curs, offr, offs_);
  k_csr_fill<<<(NE+255)/256, 256, 0, stream>>>(ei, ws+OFF_UVL, curr, curs, listr, lists);

  const size_t NF[2]  = {OFF_NF0, OFF_NF1};
  const size_t MSG[2] = {OFF_MSG0, OFF_MSG1};
  dim3 ling(256, 4);
  float* GA1 = ws + OFF_AGG;                        // t=1 gagg (kept)
  float* GB0 = ws + OFF_AGG + PL;                   // gnf t=0
  float* GA0 = ws + OFF_AGG + 2*PL;                 // t=0 gagg

  // ---------- forward ----------
  for (int t = 0; t < NT; ++t){
    k_agg<<<1024, 256, 0, stream>>>(ws+O_TW + (size_t)t*NB1*64, ws+OFF_UVL,
                                    ws+NF[t], ei, offr, listr, ws+OFF_AGG);
    k_lin2<<<ling, 256, 0, stream>>>(ws+OFF_AGG, ws+O_WMIX + (size_t)t*12288, ws+MSG[t]);
    k_tail<<<1024, 256, 0, stream>>>(ws+NF[t], ws+MSG[t],
                                     ws+O_WSC + (size_t)t*12288, ws+O_WPROD + (size_t)t*12288,
                                     ws+O_WPOLY + (size_t)t*192, ws+O_WE + (size_t)t*64,
                                     ws+O_WD + (size_t)t*64,
                                     ws+NF[(t+1)&1] /*unused when write_nf=0*/,
                                     ws + (t ? O_EN1 : O_EN0), ws+O_ADP, t == 0 ? 1 : 0);
  }

  // ---------- backward (k=0 plane only) ----------
  k_bwd_head<<<1, 64, 0, stream>>>(ws+O_WPRODT+12288, ws+O_WSCT+12288, ws+O_WE+64, ws+O_WE,
                                   ws+O_GVP, ws+O_GNFC);
  k_gback1<<<1024, 256, 0, stream>>>(ws+O_GVP, ws+MSG[1], ws+O_WPOLY+192,
                                     ws+O_WMIXT+12288, GA1);
  k_ghgather0<<<1024, 256, 0, stream>>>(ws+O_TW + (size_t)NB1*64, ws+OFF_UVL, GA1, ei,
                                        offs_, lists, ws+O_GNFC, GB0);
  k_gback0<<<1024, 256, 0, stream>>>(GB0, ws+MSG[0], ws+O_WPOLY,
                                     ws+O_WPRODT, ws+O_WMIXT, GA0);
  k_bwdE2<<<2048, 256, 0, stream>>>(ws+O_TQ, ws+OFF_UVL,
                                    ws+OFF_NF0, ws+OFF_NF1, GA0, GA1,
                                    ei, lists, offs_ + NN, ws+O_GVEC);

  k_gposW<<<(NN+3)/4, 256, 0, stream>>>(ws+O_GVEC, offr, listr, offs_, lists, ws+O_GPOS);
  k_reduce<<<(NN+255)/256, 256, 0, stream>>>(ws+O_E0N, ws+O_EN0, ws+O_EN1, ws+O_ADP,
                                             ws+OFF_CHG, ws+OFF_PIN, batch,
                                             ws+O_E0G, ws+O_ETG, ws+O_TD);
  k_writeout<<<(60112+255)/256, 256, 0, stream>>>(ws+O_E0G, ws+O_ETG, ws+O_TD, ws+O_ADP, ws+O_GPOS, d_out, flag);
}